// Round 2
// baseline (9671.326 us; speedup 1.0000x reference)
//
#include <hip/hip_runtime.h>
#include <math.h>

#define FFUNC 1000

// ---------------- device helpers ----------------
__device__ __forceinline__ float sigf(float x){ return 1.0f/(1.0f+expf(-x)); }
__device__ __forceinline__ float geluf(float x){
  return 0.5f*x*(1.0f + tanhf(0.7978845608028654f*(x + 0.044715f*x*x*x)));
}
// order-preserving float<->uint key (monotone: bigger float => bigger key)
__device__ __forceinline__ unsigned fkey(float f){
  unsigned u = __float_as_uint(f);
  return (u & 0x80000000u) ? ~u : (u | 0x80000000u);
}
__device__ __forceinline__ float funkey(unsigned k){
  unsigned u = (k & 0x80000000u) ? (k ^ 0x80000000u) : ~k;
  return __uint_as_float(u);
}
__device__ __forceinline__ void atomAddF(float* p, float v){ unsafeAtomicAdd(p, v); }

// ---------------- GEMM: out[N,128] = f(A[N,128] @ W[128,128] + b) ----------------
// mode: 0 plain, 1 tanh, 2 skip: s*acc+(1-s)*xin, 3 skip+combine: relu(0.5*o1+0.5*skip)
// pregelu: apply gelu to A elements before matmul
__global__ __launch_bounds__(256) void gemm128_k(
    const float* __restrict__ A, int N,
    const float* __restrict__ W, const float* __restrict__ bias,
    float* __restrict__ out, int mode, int pregelu,
    const float* __restrict__ xin, const float* __restrict__ o1p,
    const float* __restrict__ skp)
{
  __shared__ __align__(16) float Ws[32][128];
  __shared__ __align__(16) float xT[32][64];
  int t = threadIdx.x;
  int c = t & 31, g = t >> 5;
  int r0 = blockIdx.x * 64;
  float acc[8][4];
  float b0=0,b1=0,b2=0,b3=0;
  if (bias){ b0=bias[c*4]; b1=bias[c*4+1]; b2=bias[c*4+2]; b3=bias[c*4+3]; }
  #pragma unroll
  for (int i=0;i<8;i++){ acc[i][0]=b0; acc[i][1]=b1; acc[i][2]=b2; acc[i][3]=b3; }

  for (int kt=0; kt<4; ++kt){
    #pragma unroll
    for (int u=0;u<4;u++){
      int lin = (u*256 + t)*4;
      int kk = lin >> 7, j = lin & 127;
      *(float4*)(&Ws[kk][j]) = *(const float4*)(W + (size_t)(kt*32+kk)*128 + j);
    }
    #pragma unroll
    for (int u=0;u<2;u++){
      int lin = (u*256 + t)*4;          // 0..2047 : r*32 + kk
      int r = lin >> 5, kk = lin & 31;
      float4 x4 = make_float4(0.f,0.f,0.f,0.f);
      if (r0 + r < N) x4 = *(const float4*)(A + (size_t)(r0+r)*128 + kt*32 + kk);
      if (pregelu){ x4.x=geluf(x4.x); x4.y=geluf(x4.y); x4.z=geluf(x4.z); x4.w=geluf(x4.w); }
      xT[kk  ][r] = x4.x;
      xT[kk+1][r] = x4.y;
      xT[kk+2][r] = x4.z;
      xT[kk+3][r] = x4.w;
    }
    __syncthreads();
    #pragma unroll 8
    for (int k=0;k<32;k++){
      float4 w4 = *(const float4*)(&Ws[k][c*4]);
      float4 xa = *(const float4*)(&xT[k][g*8]);
      float4 xb = *(const float4*)(&xT[k][g*8+4]);
      float xr[8] = {xa.x,xa.y,xa.z,xa.w,xb.x,xb.y,xb.z,xb.w};
      #pragma unroll
      for (int i=0;i<8;i++){
        acc[i][0] += xr[i]*w4.x; acc[i][1] += xr[i]*w4.y;
        acc[i][2] += xr[i]*w4.z; acc[i][3] += xr[i]*w4.w;
      }
    }
    __syncthreads();
  }

  float s=0.f, s1=0.f;
  if (mode >= 2){ s = sigf(skp[0]); s1 = 1.0f - s; }
  #pragma unroll
  for (int i=0;i<8;i++){
    int r = r0 + g*8 + i;
    if (r >= N) continue;
    size_t base = (size_t)r*128 + c*4;
    float o0=acc[i][0], o1v=acc[i][1], o2=acc[i][2], o3=acc[i][3];
    if (mode == 1){
      o0=tanhf(o0); o1v=tanhf(o1v); o2=tanhf(o2); o3=tanhf(o3);
    } else if (mode >= 2){
      float4 xi4 = *(const float4*)(xin + base);
      o0 = s*o0 + s1*xi4.x; o1v = s*o1v + s1*xi4.y;
      o2 = s*o2 + s1*xi4.z; o3 = s*o3 + s1*xi4.w;
      if (mode == 3){
        float4 a4 = *(const float4*)(o1p + base);
        o0 = fmaxf(0.5f*a4.x + 0.5f*o0, 0.f);
        o1v= fmaxf(0.5f*a4.y + 0.5f*o1v,0.f);
        o2 = fmaxf(0.5f*a4.z + 0.5f*o2, 0.f);
        o3 = fmaxf(0.5f*a4.w + 0.5f*o3, 0.f);
      }
    }
    *(float4*)(out + base) = make_float4(o0,o1v,o2,o3);
  }
}

// ---------------- per-head transform: out[n][h*32+f] = sum_d X[n][h*32+d]*Amat[h][d][f] ----------------
__global__ __launch_bounds__(256) void xform_k(
    const float* __restrict__ X, int N,
    const float* __restrict__ Amat, float* __restrict__ out)
{
  __shared__ __align__(16) float As[4][32][32];
  __shared__ __align__(16) float xT[128][64];
  int t = threadIdx.x;
  int cc = t & 7, h = (t>>3)&3, g = t>>5;
  int n0 = blockIdx.x*64;
  #pragma unroll
  for (int u=0;u<4;u++){
    int lin = (u*256+t)*4;
    *(float4*)(((float*)As) + lin) = *(const float4*)(Amat + lin);
  }
  #pragma unroll
  for (int u=0;u<8;u++){
    int lin = (u*256+t)*4;           // r*128 + k
    int r = lin >> 7, k = lin & 127;
    float4 x4 = make_float4(0.f,0.f,0.f,0.f);
    if (n0+r < N) x4 = *(const float4*)(X + (size_t)(n0+r)*128 + k);
    xT[k  ][r]=x4.x; xT[k+1][r]=x4.y; xT[k+2][r]=x4.z; xT[k+3][r]=x4.w;
  }
  __syncthreads();
  float acc[8][4];
  #pragma unroll
  for (int i=0;i<8;i++){ acc[i][0]=0;acc[i][1]=0;acc[i][2]=0;acc[i][3]=0; }
  #pragma unroll 4
  for (int d=0; d<32; d++){
    float4 a4 = *(const float4*)(&As[h][d][cc*4]);
    float4 xa = *(const float4*)(&xT[h*32+d][g*8]);
    float4 xb = *(const float4*)(&xT[h*32+d][g*8+4]);
    float xr[8] = {xa.x,xa.y,xa.z,xa.w,xb.x,xb.y,xb.z,xb.w};
    #pragma unroll
    for (int i=0;i<8;i++){
      acc[i][0] += xr[i]*a4.x; acc[i][1] += xr[i]*a4.y;
      acc[i][2] += xr[i]*a4.z; acc[i][3] += xr[i]*a4.w;
    }
  }
  #pragma unroll
  for (int i=0;i<8;i++){
    int n = n0 + g*8 + i;
    if (n < N)
      *(float4*)(out + (size_t)n*128 + h*32 + cc*4) =
          make_float4(acc[i][0],acc[i][1],acc[i][2],acc[i][3]);
  }
}

// ---------------- E1: logits + segment max ----------------
__global__ __launch_bounds__(256) void e1_k(
    const float* __restrict__ kr, const float* __restrict__ q,
    const int* __restrict__ srcp, const int* __restrict__ dstp, int E,
    const float* __restrict__ prp, float* __restrict__ logits,
    unsigned* __restrict__ nmax)
{
  int t = threadIdx.x;
  int gid = t >> 3, j = t & 7;
  long pair = (long)blockIdx.x*32 + gid;
  int e = (int)(pair >> 2), h = (int)(pair & 3);
  if (e >= E) return;
  int s = srcp[e], d = dstp[e];
  float4 a = *(const float4*)(kr + (size_t)s*128 + h*32 + j*4);
  float4 b = *(const float4*)(q  + (size_t)d*128 + h*32 + j*4);
  float p = a.x*b.x + a.y*b.y + a.z*b.z + a.w*b.w;
  p += __shfl_xor(p, 1, 8);
  p += __shfl_xor(p, 2, 8);
  p += __shfl_xor(p, 4, 8);
  if (j == 0){
    float lg = p * (prp[h] * 0.17677669529663687f);  // 1/sqrt(32)
    logits[(size_t)e*4 + h] = lg;
    atomicMax(&nmax[(size_t)d*4 + h], fkey(lg));
  }
}

// ---------------- E1b: exp + segment denom (all 4 relations in one launch) ----------------
struct Seg4 {
  int blk0[5];
  int E[4];
  int eoff[4];
  const int* dst[4];
  int dtyp[4];
};
__global__ __launch_bounds__(256) void e1b_k(
    Seg4 sg, float* __restrict__ logits,
    const unsigned* __restrict__ nmax_d, const unsigned* __restrict__ nmax_i,
    float* __restrict__ den_d, float* __restrict__ den_i)
{
  int b = blockIdx.x;
  int r = (b >= sg.blk0[1]) + (b >= sg.blk0[2]) + (b >= sg.blk0[3]);
  int pair = (b - sg.blk0[r])*256 + threadIdx.x;
  int e = pair >> 2, h = pair & 3;
  if (e >= sg.E[r]) return;
  int d = sg.dst[r][e];
  size_t li = ((size_t)sg.eoff[r] + e)*4 + h;
  const unsigned* nm = sg.dtyp[r] ? nmax_i : nmax_d;
  float* dn = sg.dtyp[r] ? den_i : den_d;
  float ev = expf(logits[li] - funkey(nm[(size_t)d*4+h]));
  logits[li] = ev;
  atomAddF(&dn[(size_t)d*4+h], ev);
}

// ---------------- E2: weighted scatter-aggregate ----------------
__global__ __launch_bounds__(256) void e2_k(
    const float* __restrict__ vr, const float* __restrict__ evs,
    const float* __restrict__ den, const int* __restrict__ srcp,
    const int* __restrict__ dstp, int E, float* __restrict__ agg)
{
  int t = threadIdx.x;
  int gid = t >> 3, j = t & 7;
  long pair = (long)blockIdx.x*32 + gid;
  int e = (int)(pair >> 2), h = (int)(pair & 3);
  if (e >= E) return;
  int s = srcp[e], d = dstp[e];
  float w = evs[(size_t)e*4+h] / fmaxf(den[(size_t)d*4+h], 1e-16f);
  float4 v4 = *(const float4*)(vr + (size_t)s*128 + h*32 + j*4);
  float* ap = agg + (size_t)d*128 + h*32 + j*4;
  atomAddF(ap+0, w*v4.x); atomAddF(ap+1, w*v4.y);
  atomAddF(ap+2, w*v4.z); atomAddF(ap+3, w*v4.w);
}

// ---------------- func pool: sums + counts ----------------
__global__ void f1_k(const float* __restrict__ xd, const float* __restrict__ xi,
                     const int* __restrict__ fd, const int* __restrict__ fi,
                     int Nd, int Ni, float* __restrict__ fsum, float* __restrict__ fcnt)
{
  int t = threadIdx.x; int j = t & 31; int gl = t >> 5;
  long Nt = (long)Nd + Ni;
  for (long n = (long)blockIdx.x*8 + gl; n < Nt; n += (long)gridDim.x*8){
    const float* x; int f;
    if (n < Nd){ x = xd + n*128; f = fd[n]; }
    else       { x = xi + (n-Nd)*128; f = fi[n-Nd]; }
    float4 v = *(const float4*)(x + j*4);
    float* p = fsum + (size_t)f*128 + j*4;
    atomAddF(p, v.x); atomAddF(p+1, v.y); atomAddF(p+2, v.z); atomAddF(p+3, v.w);
    if (j == 0) atomAddF(fcnt + f, 1.0f);
  }
}

// ---------------- attention-pool context: colsum(fsum)/Nt @ W_att -> tanh ----------------
__global__ void attc_k(const float* __restrict__ fsum, float Ninv,
                       const float* __restrict__ Watt, float* __restrict__ attc)
{
  __shared__ float mean[128];
  int j = threadIdx.x;
  float a = 0;
  for (int f=0; f<FFUNC; f++) a += fsum[(size_t)f*128 + j];
  mean[j] = a * Ninv;
  __syncthreads();
  float c = 0;
  for (int k=0;k<128;k++) c += mean[k]*Watt[(size_t)k*128 + j];
  attc[j] = tanhf(c);
}

__global__ void rowmean_k(float* __restrict__ fsum, const float* __restrict__ fcnt){
  int idx = blockIdx.x*256 + threadIdx.x;
  if (idx < FFUNC*128) fsum[idx] /= fmaxf(fcnt[idx>>7], 1.0f);
}

// ---------------- func pool: gated sum ----------------
__global__ void f3_k(const float* __restrict__ xd, const float* __restrict__ xi,
                     const int* __restrict__ fd, const int* __restrict__ fi,
                     int Nd, int Ni, const float* __restrict__ cf, float* __restrict__ femb)
{
  int t = threadIdx.x; int j = t & 31; int gl = t >> 5;
  long Nt = (long)Nd + Ni;
  for (long n = (long)blockIdx.x*8 + gl; n < Nt; n += (long)gridDim.x*8){
    const float* x; int f;
    if (n < Nd){ x = xd + n*128; f = fd[n]; }
    else       { x = xi + (n-Nd)*128; f = fi[n-Nd]; }
    float4 v = *(const float4*)(x + j*4);
    float4 c4 = *(const float4*)(cf + (size_t)f*128 + j*4);
    float p = v.x*c4.x + v.y*c4.y + v.z*c4.z + v.w*c4.w;
    p += __shfl_xor(p,1,32); p += __shfl_xor(p,2,32); p += __shfl_xor(p,4,32);
    p += __shfl_xor(p,8,32); p += __shfl_xor(p,16,32);
    float sg = sigf(p);
    float* fp = femb + (size_t)f*128 + j*4;
    atomAddF(fp, v.x*sg); atomAddF(fp+1, v.y*sg);
    atomAddF(fp+2, v.z*sg); atomAddF(fp+3, v.w*sg);
  }
}

// ---------------- attention pool: gated global sum ----------------
__global__ void a3_k(const float* __restrict__ xd, const float* __restrict__ xi,
                     int Nd, int Ni, const float* __restrict__ attc, float* __restrict__ pooled)
{
  __shared__ __align__(16) float cs[128];
  __shared__ __align__(16) float red[8][128];
  int t = threadIdx.x;
  if (t < 128) cs[t] = attc[t];
  __syncthreads();
  int j = t & 31, gl = t >> 5;
  float4 acc = make_float4(0.f,0.f,0.f,0.f);
  long Nt = (long)Nd + Ni;
  for (long n = (long)blockIdx.x*8 + gl; n < Nt; n += (long)gridDim.x*8){
    const float* x = (n < Nd) ? (xd + n*128) : (xi + (n-Nd)*128);
    float4 v = *(const float4*)(x + j*4);
    float4 c4 = *(const float4*)(&cs[j*4]);
    float p = v.x*c4.x + v.y*c4.y + v.z*c4.z + v.w*c4.w;
    p += __shfl_xor(p,1,32); p += __shfl_xor(p,2,32); p += __shfl_xor(p,4,32);
    p += __shfl_xor(p,8,32); p += __shfl_xor(p,16,32);
    float sg = sigf(p);
    acc.x += v.x*sg; acc.y += v.y*sg; acc.z += v.z*sg; acc.w += v.w*sg;
  }
  *(float4*)(&red[gl][j*4]) = acc;
  __syncthreads();
  if (t < 128){
    float a = 0;
    for (int g2=0; g2<8; g2++) a += red[g2][t];
    atomAddF(pooled + t, a);
  }
}

// ---------------- histogram: sc = f1@f2^T, track min/max ----------------
__global__ __launch_bounds__(256) void gemmnt_k(const float* __restrict__ fa,
                                                const float* __restrict__ fb,
                                                float* __restrict__ sc,
                                                unsigned* __restrict__ mmk)
{
  int t = threadIdx.x;
  int tx = t & 15, ty = t >> 4;
  int i = blockIdx.y*16 + ty, j = blockIdx.x*16 + tx;
  float mn = INFINITY, mx = -INFINITY;
  if (i < FFUNC && j < FFUNC){
    float a = 0;
    for (int k=0;k<128;k+=4){
      float4 A = *(const float4*)(fa + (size_t)i*128 + k);
      float4 B = *(const float4*)(fb + (size_t)j*128 + k);
      a += A.x*B.x + A.y*B.y + A.z*B.z + A.w*B.w;
    }
    sc[(size_t)i*FFUNC + j] = a;
    mn = a; mx = a;
  }
  __shared__ float smn[256], smx[256];
  smn[t]=mn; smx[t]=mx; __syncthreads();
  for (int o=128;o>0;o>>=1){
    if (t<o){ smn[t]=fminf(smn[t],smn[t+o]); smx[t]=fmaxf(smx[t],smx[t+o]); }
    __syncthreads();
  }
  if (t==0){ atomicMin(&mmk[0], fkey(smn[0])); atomicMax(&mmk[1], fkey(smx[0])); }
}

__global__ void hist_init_k(unsigned* mmk, unsigned* hist){
  int t = threadIdx.x;
  if (t==0){ mmk[0]=0xFFFFFFFFu; mmk[1]=0u; }
  if (t<16) hist[t]=0u;
}

__global__ void hist_k(const float* __restrict__ sc, const unsigned* __restrict__ mmk,
                       unsigned* __restrict__ hist)
{
  __shared__ unsigned hl[16];
  int t = threadIdx.x;
  if (t < 16) hl[t] = 0;
  __syncthreads();
  float mn = funkey(mmk[0]), mx = funkey(mmk[1]);
  float rng = fmaxf(mx - mn, 1e-12f);
  const long total = (long)FFUNC*FFUNC;
  for (long idx = (long)blockIdx.x*256 + t; idx < total; idx += (long)gridDim.x*256){
    float v = sc[idx];
    int b = (int)floorf((v - mn)/rng * 16.0f);
    b = min(max(b,0),15);
    atomicAdd(&hl[b], 1u);
  }
  __syncthreads();
  if (t < 16) atomicAdd(&hist[t], hl[t]);
}

// ---------------- final head ----------------
__global__ __launch_bounds__(256) void final_k(
    const float* __restrict__ p1, const float* __restrict__ p2,
    const float* __restrict__ Wtn, const float* __restrict__ Vtn,
    const float* __restrict__ btn, const unsigned* __restrict__ hist,
    const float* __restrict__ Wfc1, const float* __restrict__ bfc1,
    const float* __restrict__ Wsc, const float* __restrict__ bsc,
    float* __restrict__ outp)
{
  __shared__ float P1[128], P2[128], part[256], feats[32], hv[16];
  int t = threadIdx.x;
  if (t < 128){ P1[t] = p1[t]; P2[t] = p2[t]; }
  __syncthreads();
  int k = t & 15, pr_ = t >> 4;
  float acc = 0;
  for (int i = pr_*8; i < pr_*8+8; ++i){
    float pi = P1[i];
    const float* wrow = Wtn + ((size_t)i*128)*16 + k;
    float a2 = 0;
    for (int j=0;j<128;++j) a2 += P2[j]*wrow[(size_t)j*16];
    acc += pi*a2;
  }
  part[t] = acc;
  __syncthreads();
  if (t < 16){
    float sc_ = 0;
    for (int p=0;p<16;p++) sc_ += part[p*16 + t];
    float bl = btn[t];
    for (int j=0;j<256;j++) bl += Vtn[(size_t)t*256 + j] * (j<128 ? P1[j] : P2[j-128]);
    float tv = sc_ + bl;
    feats[t] = tv > 0.f ? tv : 0.f;
    feats[16+t] = (float)hist[t] * (1.0f/((float)FFUNC*(float)FFUNC));
  }
  __syncthreads();
  if (t < 16){
    float a2 = bfc1[t];
    for (int q2=0;q2<32;q2++) a2 += feats[q2]*Wfc1[q2*16 + t];
    hv[t] = a2 > 0.f ? a2 : 0.f;
  }
  __syncthreads();
  if (t == 0){
    float z = bsc[0];
    for (int m=0;m<16;m++) z += hv[m]*Wsc[m];
    outp[0] = sigf(z);
  }
}

// ---------------- host ----------------
extern "C" void kernel_launch(void* const* d_in, const int* in_sizes, int n_in,
                              void* d_out, int out_size, void* d_ws, size_t ws_size,
                              hipStream_t stream)
{
  (void)n_in; (void)out_size; (void)ws_size;
  const float* Wk = (const float*)d_in[16];
  const float* bk = (const float*)d_in[17];
  const float* Wq = (const float*)d_in[18];
  const float* bq = (const float*)d_in[19];
  const float* Wv = (const float*)d_in[20];
  const float* bv = (const float*)d_in[21];
  const float* Wa = (const float*)d_in[22];
  const float* ba = (const float*)d_in[23];
  const float* SKp = (const float*)d_in[24];
  const float* AR = (const float*)d_in[25];
  const float* MRm = (const float*)d_in[26];
  const float* PRp = (const float*)d_in[27];
  const float* WATT = (const float*)d_in[28];
  const float* WTN = (const float*)d_in[29];
  const float* VTN = (const float*)d_in[30];
  const float* BTN = (const float*)d_in[31];
  const float* WFC1 = (const float*)d_in[32];
  const float* BFC1 = (const float*)d_in[33];
  const float* WSC = (const float*)d_in[34];
  const float* BSC = (const float*)d_in[35];

  int NdA[2] = { in_sizes[0]/128, in_sizes[8]/128 };
  int NiA[2] = { in_sizes[1]/128, in_sizes[9]/128 };
  int EA[2][4];
  for (int g=0; g<2; g++)
    for (int r=0; r<4; r++) EA[g][r] = in_sizes[g*8+2+r]/2;

  int NdM = NdA[0] > NdA[1] ? NdA[0] : NdA[1];
  int NiM = NiA[0] > NiA[1] ? NiA[0] : NiA[1];
  long EtotM = 0;
  for (int g=0; g<2; g++){
    long et = 0; for (int r=0;r<4;r++) et += EA[g][r];
    if (et > EtotM) EtotM = et;
  }

  char* wp = (char*)d_ws;
  auto alloc = [&](size_t bytes)->void*{
    void* p = (void*)wp;
    wp += (bytes + 255) & ~(size_t)255;
    return p;
  };
  size_t nrows = (size_t)NdM + (size_t)NiM;
  // Workspace budget note: QA slab serves as Qb during the K/Q/logits phase
  // and is re-purposed (memset) as the AGG accumulator for the V/aggregate
  // phase (Qb is dead after e1). Total ws use ~220 MiB.
  float*    X    = (float*)alloc(nrows*128*4);
  float*    Kb   = (float*)alloc(nrows*128*4);
  float*    QA   = (float*)alloc(nrows*128*4);   // Qb then AGG
  unsigned* NMAX = (unsigned*)alloc(nrows*4*4);  // NMAX/DEN contiguous (256B multiples)
  float*    DEN  = (float*)alloc(nrows*4*4);
  float*    O1b  = (float*)alloc(nrows*128*4);
  float*    KR   = (float*)alloc((size_t)NiM*128*4);
  float*    LOGb = (float*)alloc((size_t)EtotM*4*4);
  float*    GS[2];
  GS[0] = (float*)alloc((size_t)385280*4);
  GS[1] = (float*)alloc((size_t)385280*4);
  unsigned* MM   = (unsigned*)alloc(2*4);
  unsigned* HIST = (unsigned*)alloc(16*4);
  float*    SCb  = (float*)alloc((size_t)FFUNC*FFUNC*4);

  const size_t OF_FSUM=0, OF_FCNT=128000, OF_CF=129024, OF_ATTC=257024, OF_FEMB=257152, OF_POOL=385152;
  const int stf[4] = {1,0,1,1};   // forward src types (0=data,1=inst)
  const int dtf[4] = {1,1,0,1};   // forward dst types

  for (int g=0; g<2; ++g){
    int nd = NdA[g], ni = NiA[g];
    int E[4] = {EA[g][0],EA[g][1],EA[g][2],EA[g][3]};
    int eoff[4]; eoff[0]=0;
    for (int r=1;r<4;r++) eoff[r] = eoff[r-1] + E[r-1];
    const int* ei[4] = {(const int*)d_in[g*8+2], (const int*)d_in[g*8+3],
                        (const int*)d_in[g*8+4], (const int*)d_in[g*8+5]};
    const int* fdp = (const int*)d_in[g*8+6];
    const int* fip = (const int*)d_in[g*8+7];
    const float* x0d = (const float*)d_in[g*8+0];
    const float* x0i = (const float*)d_in[g*8+1];
    int gbd = (nd+63)/64, gbi = (ni+63)/64;

    for (int l=0; l<2; ++l){
      const float* xd = (l==0) ? x0d : X;
      const float* xi = (l==0) ? x0i : X + (size_t)nd*128;
      for (int c=0; c<2; ++c){
        int pc = l*2 + c;
        // zero segment-max keys + denominators (contiguous region)
        hipMemsetAsync(NMAX, 0, nrows*4*4*2, stream);
        // k, q projections (QA used as Q buffer here)
        gemm128_k<<<gbd,256,0,stream>>>(xd, nd, Wk+(size_t)(pc*2+0)*16384, bk+(size_t)(pc*2+0)*128, Kb, 0,0,nullptr,nullptr,nullptr);
        gemm128_k<<<gbi,256,0,stream>>>(xi, ni, Wk+(size_t)(pc*2+1)*16384, bk+(size_t)(pc*2+1)*128, Kb+(size_t)nd*128, 0,0,nullptr,nullptr,nullptr);
        gemm128_k<<<gbd,256,0,stream>>>(xd, nd, Wq+(size_t)(pc*2+0)*16384, bq+(size_t)(pc*2+0)*128, QA, 0,0,nullptr,nullptr,nullptr);
        gemm128_k<<<gbi,256,0,stream>>>(xi, ni, Wq+(size_t)(pc*2+1)*16384, bq+(size_t)(pc*2+1)*128, QA+(size_t)nd*128, 0,0,nullptr,nullptr,nullptr);
        // per-relation: kr transform + logits/max
        for (int r=0; r<4; r++){
          const int* sp = (c==0) ? ei[r] : ei[r]+E[r];
          const int* dp = (c==0) ? ei[r]+E[r] : ei[r];
          int st = (c==0) ? stf[r] : dtf[r];
          int dt = (c==0) ? dtf[r] : stf[r];
          int Ns = st ? ni : nd;
          xform_k<<<(Ns+63)/64,256,0,stream>>>(Kb + (st?(size_t)nd*128:0), Ns,
                                               AR + (size_t)(pc*4+r)*4096, KR);
          int blks = (E[r]*4 + 31)/32;
          e1_k<<<blks,256,0,stream>>>(KR, QA + (dt?(size_t)nd*128:0), sp, dp, E[r],
                                      PRp + (size_t)(pc*4+r)*4,
                                      LOGb + (size_t)eoff[r]*4,
                                      NMAX + (dt?(size_t)nd*4:0));
        }
        // E1b (exp + denom), all relations
        Seg4 sg; int tb = 0;
        for (int r=0;r<4;r++){
          sg.blk0[r] = tb;
          sg.E[r] = E[r];
          sg.eoff[r] = eoff[r];
          sg.dst[r] = (c==0) ? ei[r]+E[r] : ei[r];
          sg.dtyp[r] = (c==0) ? dtf[r] : stf[r];
          tb += (E[r]*4 + 255)/256;
        }
        sg.blk0[4] = tb;
        e1b_k<<<tb,256,0,stream>>>(sg, LOGb, NMAX, NMAX+(size_t)nd*4, DEN, DEN+(size_t)nd*4);
        // Q is dead now: re-purpose QA as AGG accumulator
        hipMemsetAsync(QA, 0, nrows*128*4, stream);
        // v projections (overwrite K slab, k no longer needed)
        gemm128_k<<<gbd,256,0,stream>>>(xd, nd, Wv+(size_t)(pc*2+0)*16384, bv+(size_t)(pc*2+0)*128, Kb, 0,0,nullptr,nullptr,nullptr);
        gemm128_k<<<gbi,256,0,stream>>>(xi, ni, Wv+(size_t)(pc*2+1)*16384, bv+(size_t)(pc*2+1)*128, Kb+(size_t)nd*128, 0,0,nullptr,nullptr,nullptr);
        // per-relation: vr transform + aggregate
        for (int r=0; r<4; r++){
          const int* sp = (c==0) ? ei[r] : ei[r]+E[r];
          const int* dp = (c==0) ? ei[r]+E[r] : ei[r];
          int st = (c==0) ? stf[r] : dtf[r];
          int dt = (c==0) ? dtf[r] : stf[r];
          int Ns = st ? ni : nd;
          xform_k<<<(Ns+63)/64,256,0,stream>>>(Kb + (st?(size_t)nd*128:0), Ns,
                                               MRm + (size_t)(pc*4+r)*4096, KR);
          int blks = (E[r]*4 + 31)/32;
          e2_k<<<blks,256,0,stream>>>(KR, LOGb + (size_t)eoff[r]*4,
                                      DEN + (dt?(size_t)nd*4:0), sp, dp, E[r],
                                      QA + (dt?(size_t)nd*128:0));
        }
        // epilogue: out = s*(gelu(agg)@Wa + ba) + (1-s)*x  [+ layer combine for c==1]
        const float* sk0 = SKp + pc*2 + 0;
        const float* sk1 = SKp + pc*2 + 1;
        if (c == 0){
          gemm128_k<<<gbd,256,0,stream>>>(QA, nd, Wa+(size_t)(pc*2+0)*16384, ba+(size_t)(pc*2+0)*128, O1b, 2,1, xd, nullptr, sk0);
          gemm128_k<<<gbi,256,0,stream>>>(QA+(size_t)nd*128, ni, Wa+(size_t)(pc*2+1)*16384, ba+(size_t)(pc*2+1)*128, O1b+(size_t)nd*128, 2,1, xi, nullptr, sk1);
        } else {
          gemm128_k<<<gbd,256,0,stream>>>(QA, nd, Wa+(size_t)(pc*2+0)*16384, ba+(size_t)(pc*2+0)*128, X, 3,1, xd, O1b, sk0);
          gemm128_k<<<gbi,256,0,stream>>>(QA+(size_t)nd*128, ni, Wa+(size_t)(pc*2+1)*16384, ba+(size_t)(pc*2+1)*128, X+(size_t)nd*128, 3,1, xi, O1b+(size_t)nd*128, sk1);
        }
      }
    }
    // pooling for this graph
    float* fsum = GS[g]+OF_FSUM;  float* fcnt = GS[g]+OF_FCNT;
    float* cf   = GS[g]+OF_CF;    float* attc = GS[g]+OF_ATTC;
    float* femb = GS[g]+OF_FEMB;  float* pool = GS[g]+OF_POOL;
    hipMemsetAsync(GS[g], 0, (size_t)385280*4, stream);
    int nt8 = (nd + ni + 7)/8;
    f1_k<<<nt8,256,0,stream>>>(X, X+(size_t)nd*128, fdp, fip, nd, ni, fsum, fcnt);
    attc_k<<<1,128,0,stream>>>(fsum, 1.0f/(float)(nd+ni), WATT, attc);
    rowmean_k<<<(FFUNC*128+255)/256,256,0,stream>>>(fsum, fcnt);
    gemm128_k<<<(FFUNC+63)/64,256,0,stream>>>(fsum, FFUNC, WATT, nullptr, cf, 1,0,nullptr,nullptr,nullptr);
    f3_k<<<nt8,256,0,stream>>>(X, X+(size_t)nd*128, fdp, fip, nd, ni, cf, femb);
    a3_k<<<512,256,0,stream>>>(X, X+(size_t)nd*128, nd, ni, attc, pool);
  }
  // similarity histogram + final head
  hist_init_k<<<1,32,0,stream>>>(MM, HIST);
  dim3 gnt((FFUNC+15)/16, (FFUNC+15)/16);
  gemmnt_k<<<gnt,256,0,stream>>>(GS[0]+OF_FEMB, GS[1]+OF_FEMB, SCb, MM);
  hist_k<<<512,256,0,stream>>>(SCb, MM, HIST);
  final_k<<<1,256,0,stream>>>(GS[0]+OF_POOL, GS[1]+OF_POOL, WTN, VTN, BTN, HIST,
                              WFC1, BFC1, WSC, BSC, (float*)d_out);
}

// Round 3
// 5986.814 us; speedup vs baseline: 1.6154x; 1.6154x over previous
//
#include <hip/hip_runtime.h>
#include <math.h>

#define FFUNC 1000

// ---------------- device helpers ----------------
__device__ __forceinline__ float sigf(float x){ return 1.0f/(1.0f+expf(-x)); }
__device__ __forceinline__ float geluf(float x){
  return 0.5f*x*(1.0f + tanhf(0.7978845608028654f*(x + 0.044715f*x*x*x)));
}
// order-preserving float<->uint key (monotone: bigger float => bigger key)
__device__ __forceinline__ unsigned fkey(float f){
  unsigned u = __float_as_uint(f);
  return (u & 0x80000000u) ? ~u : (u | 0x80000000u);
}
__device__ __forceinline__ float funkey(unsigned k){
  unsigned u = (k & 0x80000000u) ? (k ^ 0x80000000u) : ~k;
  return __uint_as_float(u);
}
__device__ __forceinline__ void atomAddF(float* p, float v){ unsafeAtomicAdd(p, v); }

// ---------------- GEMM: out[N,128] = f(A[N,128] @ W[128,128] + b) ----------------
// mode: 0 plain, 1 tanh, 2 skip: s*acc+(1-s)*xin, 3 skip+combine: relu(0.5*o1+0.5*skip)
// pregelu: apply gelu to A elements before matmul
__global__ __launch_bounds__(256) void gemm128_k(
    const float* __restrict__ A, int N,
    const float* __restrict__ W, const float* __restrict__ bias,
    float* __restrict__ out, int mode, int pregelu,
    const float* __restrict__ xin, const float* __restrict__ o1p,
    const float* __restrict__ skp)
{
  __shared__ __align__(16) float Ws[32][128];
  __shared__ __align__(16) float xT[32][64];
  int t = threadIdx.x;
  int c = t & 31, g = t >> 5;
  int r0 = blockIdx.x * 64;
  float acc[8][4];
  float b0=0,b1=0,b2=0,b3=0;
  if (bias){ b0=bias[c*4]; b1=bias[c*4+1]; b2=bias[c*4+2]; b3=bias[c*4+3]; }
  #pragma unroll
  for (int i=0;i<8;i++){ acc[i][0]=b0; acc[i][1]=b1; acc[i][2]=b2; acc[i][3]=b3; }

  for (int kt=0; kt<4; ++kt){
    #pragma unroll
    for (int u=0;u<4;u++){
      int lin = (u*256 + t)*4;
      int kk = lin >> 7, j = lin & 127;
      *(float4*)(&Ws[kk][j]) = *(const float4*)(W + (size_t)(kt*32+kk)*128 + j);
    }
    #pragma unroll
    for (int u=0;u<2;u++){
      int lin = (u*256 + t)*4;          // 0..2047 : r*32 + kk
      int r = lin >> 5, kk = lin & 31;
      float4 x4 = make_float4(0.f,0.f,0.f,0.f);
      if (r0 + r < N) x4 = *(const float4*)(A + (size_t)(r0+r)*128 + kt*32 + kk);
      if (pregelu){ x4.x=geluf(x4.x); x4.y=geluf(x4.y); x4.z=geluf(x4.z); x4.w=geluf(x4.w); }
      xT[kk  ][r] = x4.x;
      xT[kk+1][r] = x4.y;
      xT[kk+2][r] = x4.z;
      xT[kk+3][r] = x4.w;
    }
    __syncthreads();
    #pragma unroll 8
    for (int k=0;k<32;k++){
      float4 w4 = *(const float4*)(&Ws[k][c*4]);
      float4 xa = *(const float4*)(&xT[k][g*8]);
      float4 xb = *(const float4*)(&xT[k][g*8+4]);
      float xr[8] = {xa.x,xa.y,xa.z,xa.w,xb.x,xb.y,xb.z,xb.w};
      #pragma unroll
      for (int i=0;i<8;i++){
        acc[i][0] += xr[i]*w4.x; acc[i][1] += xr[i]*w4.y;
        acc[i][2] += xr[i]*w4.z; acc[i][3] += xr[i]*w4.w;
      }
    }
    __syncthreads();
  }

  float s=0.f, s1=0.f;
  if (mode >= 2){ s = sigf(skp[0]); s1 = 1.0f - s; }
  #pragma unroll
  for (int i=0;i<8;i++){
    int r = r0 + g*8 + i;
    if (r >= N) continue;
    size_t base = (size_t)r*128 + c*4;
    float o0=acc[i][0], o1v=acc[i][1], o2=acc[i][2], o3=acc[i][3];
    if (mode == 1){
      o0=tanhf(o0); o1v=tanhf(o1v); o2=tanhf(o2); o3=tanhf(o3);
    } else if (mode >= 2){
      float4 xi4 = *(const float4*)(xin + base);
      o0 = s*o0 + s1*xi4.x; o1v = s*o1v + s1*xi4.y;
      o2 = s*o2 + s1*xi4.z; o3 = s*o3 + s1*xi4.w;
      if (mode == 3){
        float4 a4 = *(const float4*)(o1p + base);
        o0 = fmaxf(0.5f*a4.x + 0.5f*o0, 0.f);
        o1v= fmaxf(0.5f*a4.y + 0.5f*o1v,0.f);
        o2 = fmaxf(0.5f*a4.z + 0.5f*o2, 0.f);
        o3 = fmaxf(0.5f*a4.w + 0.5f*o3, 0.f);
      }
    }
    *(float4*)(out + base) = make_float4(o0,o1v,o2,o3);
  }
}

// ---------------- per-head transform: out[n][h*32+f] = sum_d X[n][h*32+d]*Amat[h][d][f] ----------------
__global__ __launch_bounds__(256) void xform_k(
    const float* __restrict__ X, int N,
    const float* __restrict__ Amat, float* __restrict__ out)
{
  __shared__ __align__(16) float As[4][32][32];
  __shared__ __align__(16) float xT[128][64];
  int t = threadIdx.x;
  int cc = t & 7, h = (t>>3)&3, g = t>>5;
  int n0 = blockIdx.x*64;
  #pragma unroll
  for (int u=0;u<4;u++){
    int lin = (u*256+t)*4;
    *(float4*)(((float*)As) + lin) = *(const float4*)(Amat + lin);
  }
  #pragma unroll
  for (int u=0;u<8;u++){
    int lin = (u*256+t)*4;           // r*128 + k
    int r = lin >> 7, k = lin & 127;
    float4 x4 = make_float4(0.f,0.f,0.f,0.f);
    if (n0+r < N) x4 = *(const float4*)(X + (size_t)(n0+r)*128 + k);
    xT[k  ][r]=x4.x; xT[k+1][r]=x4.y; xT[k+2][r]=x4.z; xT[k+3][r]=x4.w;
  }
  __syncthreads();
  float acc[8][4];
  #pragma unroll
  for (int i=0;i<8;i++){ acc[i][0]=0;acc[i][1]=0;acc[i][2]=0;acc[i][3]=0; }
  #pragma unroll 4
  for (int d=0; d<32; d++){
    float4 a4 = *(const float4*)(&As[h][d][cc*4]);
    float4 xa = *(const float4*)(&xT[h*32+d][g*8]);
    float4 xb = *(const float4*)(&xT[h*32+d][g*8+4]);
    float xr[8] = {xa.x,xa.y,xa.z,xa.w,xb.x,xb.y,xb.z,xb.w};
    #pragma unroll
    for (int i=0;i<8;i++){
      acc[i][0] += xr[i]*a4.x; acc[i][1] += xr[i]*a4.y;
      acc[i][2] += xr[i]*a4.z; acc[i][3] += xr[i]*a4.w;
    }
  }
  #pragma unroll
  for (int i=0;i<8;i++){
    int n = n0 + g*8 + i;
    if (n < N)
      *(float4*)(out + (size_t)n*128 + h*32 + cc*4) =
          make_float4(acc[i][0],acc[i][1],acc[i][2],acc[i][3]);
  }
}

// ---------------- CSR build ----------------
struct ScanDesc { int n[8]; };

__global__ void csr_hist_k(const int* __restrict__ dst, int E, int* __restrict__ cnt){
  for (int e = blockIdx.x*256 + threadIdx.x; e < E; e += gridDim.x*256)
    atomicAdd(&cnt[dst[e]], 1);
}

__global__ void csr_scan_k(ScanDesc sd, int* __restrict__ offs, int* __restrict__ curs, int NO){
  int ent = blockIdx.x;
  int n = sd.n[ent];
  int* o  = offs + (size_t)ent*NO;
  int* cu = curs + (size_t)ent*NO;
  __shared__ int sb[1024];
  int tid = threadIdx.x;
  int run = 0;
  for (int base=0; base<n; base+=1024){
    int i = base + tid;
    int v = (i<n) ? o[i] : 0;
    sb[tid] = v; __syncthreads();
    for (int s=1; s<1024; s<<=1){
      int a = (tid>=s) ? sb[tid-s] : 0;
      __syncthreads();
      sb[tid] += a;
      __syncthreads();
    }
    int excl = run + sb[tid] - v;
    if (i < n){ o[i] = excl; cu[i] = excl; }
    run += sb[1023];
    __syncthreads();
  }
  if (tid == 0) o[n] = run;
}

__global__ void csr_fill_k(const int* __restrict__ dst, const int* __restrict__ src, int E,
                           int* __restrict__ curs, int* __restrict__ perm){
  for (int e = blockIdx.x*256 + threadIdx.x; e < E; e += gridDim.x*256){
    int pos = atomicAdd(&curs[dst[e]], 1);
    perm[pos] = src[e];
  }
}

// ---------------- E1 (dst-major): logits + per-dst max ----------------
__global__ __launch_bounds__(256) void e1_csr_k(
    const float* __restrict__ kr, const float* __restrict__ q,
    const int* __restrict__ offs, const int* __restrict__ psrc, int Ndst,
    const float* __restrict__ prp, float* __restrict__ logits,
    unsigned* __restrict__ nmax)
{
  int gidx = blockIdx.x*256 + threadIdx.x;
  int d = gidx >> 5; if (d >= Ndst) return;
  int sub = gidx & 31, h = sub >> 3, j = sub & 7;
  int o0 = offs[d], o1 = offs[d+1];
  if (o0 == o1) return;
  float4 qv = *(const float4*)(q + (size_t)d*128 + h*32 + j*4);
  float scale = prp[h] * 0.17677669529663687f;  // 1/sqrt(32)
  float mx = -INFINITY;
  for (int i=o0; i<o1; ++i){
    int s = psrc[i];
    float4 a = *(const float4*)(kr + (size_t)s*128 + h*32 + j*4);
    float p = a.x*qv.x + a.y*qv.y + a.z*qv.z + a.w*qv.w;
    p += __shfl_xor(p, 1, 8);
    p += __shfl_xor(p, 2, 8);
    p += __shfl_xor(p, 4, 8);
    float lg = p * scale;
    if (j == 0) logits[(size_t)i*4 + h] = lg;
    mx = fmaxf(mx, lg);
  }
  if (j == 0) atomicMax(&nmax[(size_t)d*4 + h], fkey(mx));
}

// ---------------- E1b (dst-major, all 4 relations): exp + denom ----------------
struct SegB {
  int blk0[5];
  int ndst[4];
  const int* offs[4];
  long eoff[4];
  int dty[4];
};
__global__ __launch_bounds__(256) void e1b_csr_k(SegB sg, float* __restrict__ logits,
    const unsigned* __restrict__ nmax_d, const unsigned* __restrict__ nmax_i,
    float* __restrict__ den_d, float* __restrict__ den_i)
{
  int b = blockIdx.x;
  int r = (b >= sg.blk0[1]) + (b >= sg.blk0[2]) + (b >= sg.blk0[3]);
  int pair = (b - sg.blk0[r])*256 + threadIdx.x;
  int d = pair >> 2, h = pair & 3;
  if (d >= sg.ndst[r]) return;
  const int* off = sg.offs[r];
  int o0 = off[d], o1 = off[d+1];
  if (o0 == o1) return;
  const unsigned* nm = sg.dty[r] ? nmax_i : nmax_d;
  float* dn = sg.dty[r] ? den_i : den_d;
  float mx = funkey(nm[(size_t)d*4 + h]);
  float* lg = logits + sg.eoff[r]*4;
  float acc = 0;
  for (int i=o0; i<o1; ++i){
    float ev = expf(lg[(size_t)i*4 + h] - mx);
    lg[(size_t)i*4 + h] = ev;
    acc += ev;
  }
  atomAddF(&dn[(size_t)d*4 + h], acc);
}

// ---------------- E2 (dst-major): weighted aggregate, no atomics ----------------
__global__ __launch_bounds__(256) void e2_csr_k(
    const float* __restrict__ vr, const float* __restrict__ evs,
    const float* __restrict__ den, const int* __restrict__ offs,
    const int* __restrict__ psrc, int Ndst, float* __restrict__ agg)
{
  int gidx = blockIdx.x*256 + threadIdx.x;
  int d = gidx >> 5; if (d >= Ndst) return;
  int sub = gidx & 31, h = sub >> 3, j = sub & 7;
  int o0 = offs[d], o1 = offs[d+1];
  if (o0 == o1) return;
  float inv = 1.0f / fmaxf(den[(size_t)d*4 + h], 1e-16f);
  float* ap = agg + (size_t)d*128 + h*32 + j*4;
  float4 acc = *(const float4*)ap;
  for (int i=o0; i<o1; ++i){
    int s = psrc[i];
    float w = evs[(size_t)i*4 + h] * inv;
    float4 v = *(const float4*)(vr + (size_t)s*128 + h*32 + j*4);
    acc.x += w*v.x; acc.y += w*v.y; acc.z += w*v.z; acc.w += w*v.w;
  }
  *(float4*)ap = acc;
}

// ---------------- func pool: sums + counts ----------------
__global__ void f1_k(const float* __restrict__ xd, const float* __restrict__ xi,
                     const int* __restrict__ fd, const int* __restrict__ fi,
                     int Nd, int Ni, float* __restrict__ fsum, float* __restrict__ fcnt)
{
  int t = threadIdx.x; int j = t & 31; int gl = t >> 5;
  long Nt = (long)Nd + Ni;
  for (long n = (long)blockIdx.x*8 + gl; n < Nt; n += (long)gridDim.x*8){
    const float* x; int f;
    if (n < Nd){ x = xd + n*128; f = fd[n]; }
    else       { x = xi + (n-Nd)*128; f = fi[n-Nd]; }
    float4 v = *(const float4*)(x + j*4);
    float* p = fsum + (size_t)f*128 + j*4;
    atomAddF(p, v.x); atomAddF(p+1, v.y); atomAddF(p+2, v.z); atomAddF(p+3, v.w);
    if (j == 0) atomAddF(fcnt + f, 1.0f);
  }
}

// ---------------- attention-pool context: colsum(fsum)/Nt @ W_att -> tanh ----------------
__global__ void attc_k(const float* __restrict__ fsum, float Ninv,
                       const float* __restrict__ Watt, float* __restrict__ attc)
{
  __shared__ float mean[128];
  int j = threadIdx.x;
  float a = 0;
  for (int f=0; f<FFUNC; f++) a += fsum[(size_t)f*128 + j];
  mean[j] = a * Ninv;
  __syncthreads();
  float c = 0;
  for (int k=0;k<128;k++) c += mean[k]*Watt[(size_t)k*128 + j];
  attc[j] = tanhf(c);
}

__global__ void rowmean_k(float* __restrict__ fsum, const float* __restrict__ fcnt){
  int idx = blockIdx.x*256 + threadIdx.x;
  if (idx < FFUNC*128) fsum[idx] /= fmaxf(fcnt[idx>>7], 1.0f);
}

// ---------------- func pool: gated sum ----------------
__global__ void f3_k(const float* __restrict__ xd, const float* __restrict__ xi,
                     const int* __restrict__ fd, const int* __restrict__ fi,
                     int Nd, int Ni, const float* __restrict__ cf, float* __restrict__ femb)
{
  int t = threadIdx.x; int j = t & 31; int gl = t >> 5;
  long Nt = (long)Nd + Ni;
  for (long n = (long)blockIdx.x*8 + gl; n < Nt; n += (long)gridDim.x*8){
    const float* x; int f;
    if (n < Nd){ x = xd + n*128; f = fd[n]; }
    else       { x = xi + (n-Nd)*128; f = fi[n-Nd]; }
    float4 v = *(const float4*)(x + j*4);
    float4 c4 = *(const float4*)(cf + (size_t)f*128 + j*4);
    float p = v.x*c4.x + v.y*c4.y + v.z*c4.z + v.w*c4.w;
    p += __shfl_xor(p,1,32); p += __shfl_xor(p,2,32); p += __shfl_xor(p,4,32);
    p += __shfl_xor(p,8,32); p += __shfl_xor(p,16,32);
    float sg = sigf(p);
    float* fp = femb + (size_t)f*128 + j*4;
    atomAddF(fp, v.x*sg); atomAddF(fp+1, v.y*sg);
    atomAddF(fp+2, v.z*sg); atomAddF(fp+3, v.w*sg);
  }
}

// ---------------- attention pool: gated global sum ----------------
__global__ void a3_k(const float* __restrict__ xd, const float* __restrict__ xi,
                     int Nd, int Ni, const float* __restrict__ attc, float* __restrict__ pooled)
{
  __shared__ __align__(16) float cs[128];
  __shared__ __align__(16) float red[8][128];
  int t = threadIdx.x;
  if (t < 128) cs[t] = attc[t];
  __syncthreads();
  int j = t & 31, gl = t >> 5;
  float4 acc = make_float4(0.f,0.f,0.f,0.f);
  long Nt = (long)Nd + Ni;
  for (long n = (long)blockIdx.x*8 + gl; n < Nt; n += (long)gridDim.x*8){
    const float* x = (n < Nd) ? (xd + n*128) : (xi + (n-Nd)*128);
    float4 v = *(const float4*)(x + j*4);
    float4 c4 = *(const float4*)(&cs[j*4]);
    float p = v.x*c4.x + v.y*c4.y + v.z*c4.z + v.w*c4.w;
    p += __shfl_xor(p,1,32); p += __shfl_xor(p,2,32); p += __shfl_xor(p,4,32);
    p += __shfl_xor(p,8,32); p += __shfl_xor(p,16,32);
    float sg = sigf(p);
    acc.x += v.x*sg; acc.y += v.y*sg; acc.z += v.z*sg; acc.w += v.w*sg;
  }
  *(float4*)(&red[gl][j*4]) = acc;
  __syncthreads();
  if (t < 128){
    float a = 0;
    for (int g2=0; g2<8; g2++) a += red[g2][t];
    atomAddF(pooled + t, a);
  }
}

// ---------------- histogram: sc = f1@f2^T, track min/max ----------------
__global__ __launch_bounds__(256) void gemmnt_k(const float* __restrict__ fa,
                                                const float* __restrict__ fb,
                                                float* __restrict__ sc,
                                                unsigned* __restrict__ mmk)
{
  int t = threadIdx.x;
  int tx = t & 15, ty = t >> 4;
  int i = blockIdx.y*16 + ty, j = blockIdx.x*16 + tx;
  float mn = INFINITY, mx = -INFINITY;
  if (i < FFUNC && j < FFUNC){
    float a = 0;
    for (int k=0;k<128;k+=4){
      float4 A = *(const float4*)(fa + (size_t)i*128 + k);
      float4 B = *(const float4*)(fb + (size_t)j*128 + k);
      a += A.x*B.x + A.y*B.y + A.z*B.z + A.w*B.w;
    }
    sc[(size_t)i*FFUNC + j] = a;
    mn = a; mx = a;
  }
  __shared__ float smn[256], smx[256];
  smn[t]=mn; smx[t]=mx; __syncthreads();
  for (int o=128;o>0;o>>=1){
    if (t<o){ smn[t]=fminf(smn[t],smn[t+o]); smx[t]=fmaxf(smx[t],smx[t+o]); }
    __syncthreads();
  }
  if (t==0){ atomicMin(&mmk[0], fkey(smn[0])); atomicMax(&mmk[1], fkey(smx[0])); }
}

__global__ void hist_init_k(unsigned* mmk, unsigned* hist){
  int t = threadIdx.x;
  if (t==0){ mmk[0]=0xFFFFFFFFu; mmk[1]=0u; }
  if (t<16) hist[t]=0u;
}

__global__ void hist_k(const float* __restrict__ sc, const unsigned* __restrict__ mmk,
                       unsigned* __restrict__ hist)
{
  __shared__ unsigned hl[16];
  int t = threadIdx.x;
  if (t < 16) hl[t] = 0;
  __syncthreads();
  float mn = funkey(mmk[0]), mx = funkey(mmk[1]);
  float rng = fmaxf(mx - mn, 1e-12f);
  const long total = (long)FFUNC*FFUNC;
  for (long idx = (long)blockIdx.x*256 + t; idx < total; idx += (long)gridDim.x*256){
    float v = sc[idx];
    int b = (int)floorf((v - mn)/rng * 16.0f);
    b = min(max(b,0),15);
    atomicAdd(&hl[b], 1u);
  }
  __syncthreads();
  if (t < 16) atomicAdd(&hist[t], hl[t]);
}

// ---------------- final head ----------------
__global__ __launch_bounds__(256) void final_k(
    const float* __restrict__ p1, const float* __restrict__ p2,
    const float* __restrict__ Wtn, const float* __restrict__ Vtn,
    const float* __restrict__ btn, const unsigned* __restrict__ hist,
    const float* __restrict__ Wfc1, const float* __restrict__ bfc1,
    const float* __restrict__ Wsc, const float* __restrict__ bsc,
    float* __restrict__ outp)
{
  __shared__ float P1[128], P2[128], part[256], feats[32], hv[16];
  int t = threadIdx.x;
  if (t < 128){ P1[t] = p1[t]; P2[t] = p2[t]; }
  __syncthreads();
  int k = t & 15, pr_ = t >> 4;
  float acc = 0;
  for (int i = pr_*8; i < pr_*8+8; ++i){
    float pi = P1[i];
    const float* wrow = Wtn + ((size_t)i*128)*16 + k;
    float a2 = 0;
    for (int j=0;j<128;++j) a2 += P2[j]*wrow[(size_t)j*16];
    acc += pi*a2;
  }
  part[t] = acc;
  __syncthreads();
  if (t < 16){
    float sc_ = 0;
    for (int p=0;p<16;p++) sc_ += part[p*16 + t];
    float bl = btn[t];
    for (int j=0;j<256;j++) bl += Vtn[(size_t)t*256 + j] * (j<128 ? P1[j] : P2[j-128]);
    float tv = sc_ + bl;
    feats[t] = tv > 0.f ? tv : 0.f;
    feats[16+t] = (float)hist[t] * (1.0f/((float)FFUNC*(float)FFUNC));
  }
  __syncthreads();
  if (t < 16){
    float a2 = bfc1[t];
    for (int q2=0;q2<32;q2++) a2 += feats[q2]*Wfc1[q2*16 + t];
    hv[t] = a2 > 0.f ? a2 : 0.f;
  }
  __syncthreads();
  if (t == 0){
    float z = bsc[0];
    for (int m=0;m<16;m++) z += hv[m]*Wsc[m];
    outp[0] = sigf(z);
  }
}

// ---------------- host ----------------
extern "C" void kernel_launch(void* const* d_in, const int* in_sizes, int n_in,
                              void* d_out, int out_size, void* d_ws, size_t ws_size,
                              hipStream_t stream)
{
  (void)n_in; (void)out_size; (void)ws_size;
  const float* Wk = (const float*)d_in[16];
  const float* bk = (const float*)d_in[17];
  const float* Wq = (const float*)d_in[18];
  const float* bq = (const float*)d_in[19];
  const float* Wv = (const float*)d_in[20];
  const float* bv = (const float*)d_in[21];
  const float* Wa = (const float*)d_in[22];
  const float* ba = (const float*)d_in[23];
  const float* SKp = (const float*)d_in[24];
  const float* AR = (const float*)d_in[25];
  const float* MRm = (const float*)d_in[26];
  const float* PRp = (const float*)d_in[27];
  const float* WATT = (const float*)d_in[28];
  const float* WTN = (const float*)d_in[29];
  const float* VTN = (const float*)d_in[30];
  const float* BTN = (const float*)d_in[31];
  const float* WFC1 = (const float*)d_in[32];
  const float* BFC1 = (const float*)d_in[33];
  const float* WSC = (const float*)d_in[34];
  const float* BSC = (const float*)d_in[35];

  int NdA[2] = { in_sizes[0]/128, in_sizes[8]/128 };
  int NiA[2] = { in_sizes[1]/128, in_sizes[9]/128 };
  int EA[2][4];
  for (int g=0; g<2; g++)
    for (int r=0; r<4; r++) EA[g][r] = in_sizes[g*8+2+r]/2;

  int NdM = NdA[0] > NdA[1] ? NdA[0] : NdA[1];
  int NiM = NiA[0] > NiA[1] ? NiA[0] : NiA[1];
  long EtotM = 0;
  for (int g=0; g<2; g++){
    long et = 0; for (int r=0;r<4;r++) et += EA[g][r];
    if (et > EtotM) EtotM = et;
  }
  int NO = ((NiM + 2 + 63)/64)*64;   // offsets stride per CSR entry (>= Ndst+1)

  char* wp = (char*)d_ws;
  auto alloc = [&](size_t bytes)->void*{
    void* p = (void*)wp;
    wp += (bytes + 255) & ~(size_t)255;
    return p;
  };
  size_t nrows = (size_t)NdM + (size_t)NiM;
  float*    X    = (float*)alloc(nrows*128*4);
  float*    Kb   = (float*)alloc(nrows*128*4);
  float*    QA   = (float*)alloc(nrows*128*4);   // Qb then AGG (disjoint lifetimes)
  unsigned* NMAX = (unsigned*)alloc(nrows*4*4);  // NMAX/DEN contiguous
  float*    DEN  = (float*)alloc(nrows*4*4);
  float*    O1b  = (float*)alloc(nrows*128*4);
  float*    KR   = (float*)alloc((size_t)NiM*128*4);
  float*    LOGb = (float*)alloc((size_t)EtotM*4*4);
  int*      OFFS = (int*)alloc((size_t)8*NO*4);          // 8 CSR entries (this graph)
  int*      PERM = (int*)alloc((size_t)2*EtotM*4);       // 2 directions
  float*    GS[2];
  GS[0] = (float*)alloc((size_t)385280*4);
  GS[1] = (float*)alloc((size_t)385280*4);
  unsigned* MM   = (unsigned*)alloc(2*4);
  unsigned* HIST = (unsigned*)alloc(16*4);
  // CURS (CSR build, start-of-graph) aliases SCb (similarity, end-of-pass): disjoint lifetimes
  size_t uni_bytes = (size_t)FFUNC*FFUNC*4;
  size_t curs_bytes = (size_t)8*NO*4;
  void* UNI = alloc(uni_bytes > curs_bytes ? uni_bytes : curs_bytes);
  int*      CURS = (int*)UNI;
  float*    SCb  = (float*)UNI;

  const size_t OF_FSUM=0, OF_FCNT=128000, OF_CF=129024, OF_ATTC=257024, OF_FEMB=257152, OF_POOL=385152;
  const int stf[4] = {1,0,1,1};   // forward src types (0=data,1=inst)
  const int dtf[4] = {1,1,0,1};   // forward dst types

  for (int g=0; g<2; ++g){
    int nd = NdA[g], ni = NiA[g];
    int E[4] = {EA[g][0],EA[g][1],EA[g][2],EA[g][3]};
    int eoff[4]; eoff[0]=0;
    for (int r=1;r<4;r++) eoff[r] = eoff[r-1] + E[r-1];
    const int* ei[4] = {(const int*)d_in[g*8+2], (const int*)d_in[g*8+3],
                        (const int*)d_in[g*8+4], (const int*)d_in[g*8+5]};
    const int* fdp = (const int*)d_in[g*8+6];
    const int* fip = (const int*)d_in[g*8+7];
    const float* x0d = (const float*)d_in[g*8+0];
    const float* x0i = (const float*)d_in[g*8+1];
    int gbd = (nd+63)/64, gbi = (ni+63)/64;

    // ---- build 8 CSRs for this graph (2 directions x 4 relations) ----
    hipMemsetAsync(OFFS, 0, (size_t)8*NO*4, stream);
    ScanDesc sd;
    for (int c2=0; c2<2; c2++)
      for (int r=0; r<4; r++){
        int ent = c2*4 + r;
        const int* dptr = (c2==0) ? ei[r]+E[r] : ei[r];
        int nds = ((c2==0) ? dtf[r] : stf[r]) ? ni : nd;
        sd.n[ent] = nds;
        int blks = (E[r]+255)/256; if (blks > 1024) blks = 1024;
        csr_hist_k<<<blks,256,0,stream>>>(dptr, E[r], OFFS + (size_t)ent*NO);
      }
    csr_scan_k<<<8,1024,0,stream>>>(sd, OFFS, CURS, NO);
    for (int c2=0; c2<2; c2++)
      for (int r=0; r<4; r++){
        int ent = c2*4 + r;
        const int* dptr = (c2==0) ? ei[r]+E[r] : ei[r];
        const int* sptr = (c2==0) ? ei[r] : ei[r]+E[r];
        int blks = (E[r]+255)/256; if (blks > 1024) blks = 1024;
        csr_fill_k<<<blks,256,0,stream>>>(dptr, sptr, E[r], CURS + (size_t)ent*NO,
                                          PERM + (size_t)c2*EtotM + eoff[r]);
      }

    for (int l=0; l<2; ++l){
      const float* xd = (l==0) ? x0d : X;
      const float* xi = (l==0) ? x0i : X + (size_t)nd*128;
      for (int c=0; c<2; ++c){
        int pc = l*2 + c;
        hipMemsetAsync(NMAX, 0, nrows*4*4*2, stream);
        // k, q projections (QA = Q buffer here)
        gemm128_k<<<gbd,256,0,stream>>>(xd, nd, Wk+(size_t)(pc*2+0)*16384, bk+(size_t)(pc*2+0)*128, Kb, 0,0,nullptr,nullptr,nullptr);
        gemm128_k<<<gbi,256,0,stream>>>(xi, ni, Wk+(size_t)(pc*2+1)*16384, bk+(size_t)(pc*2+1)*128, Kb+(size_t)nd*128, 0,0,nullptr,nullptr,nullptr);
        gemm128_k<<<gbd,256,0,stream>>>(xd, nd, Wq+(size_t)(pc*2+0)*16384, bq+(size_t)(pc*2+0)*128, QA, 0,0,nullptr,nullptr,nullptr);
        gemm128_k<<<gbi,256,0,stream>>>(xi, ni, Wq+(size_t)(pc*2+1)*16384, bq+(size_t)(pc*2+1)*128, QA+(size_t)nd*128, 0,0,nullptr,nullptr,nullptr);
        // per-relation: kr transform + logits/max (dst-major)
        for (int r=0; r<4; r++){
          int st = (c==0) ? stf[r] : dtf[r];
          int dt = (c==0) ? dtf[r] : stf[r];
          int Ns = st ? ni : nd;
          int Ndst = dt ? ni : nd;
          int ent = c*4 + r;
          xform_k<<<(Ns+63)/64,256,0,stream>>>(Kb + (st?(size_t)nd*128:0), Ns,
                                               AR + (size_t)(pc*4+r)*4096, KR);
          e1_csr_k<<<((size_t)Ndst*32+255)/256,256,0,stream>>>(
              KR, QA + (dt?(size_t)nd*128:0),
              OFFS + (size_t)ent*NO, PERM + (size_t)c*EtotM + eoff[r], Ndst,
              PRp + (size_t)(pc*4+r)*4,
              LOGb + (size_t)eoff[r]*4,
              NMAX + (dt?(size_t)nd*4:0));
        }
        // E1b: exp + denom (all relations)
        SegB sg; int tb = 0;
        for (int r=0;r<4;r++){
          int dt = (c==0) ? dtf[r] : stf[r];
          int Ndst = dt ? ni : nd;
          sg.blk0[r] = tb;
          sg.ndst[r] = Ndst;
          sg.offs[r] = OFFS + (size_t)(c*4+r)*NO;
          sg.eoff[r] = eoff[r];
          sg.dty[r]  = dt;
          tb += ((size_t)Ndst*4 + 255)/256;
        }
        sg.blk0[4] = tb;
        e1b_csr_k<<<tb,256,0,stream>>>(sg, LOGb, NMAX, NMAX+(size_t)nd*4, DEN, DEN+(size_t)nd*4);
        // Q dead: QA becomes AGG
        hipMemsetAsync(QA, 0, nrows*128*4, stream);
        // v projections (overwrite Kb)
        gemm128_k<<<gbd,256,0,stream>>>(xd, nd, Wv+(size_t)(pc*2+0)*16384, bv+(size_t)(pc*2+0)*128, Kb, 0,0,nullptr,nullptr,nullptr);
        gemm128_k<<<gbi,256,0,stream>>>(xi, ni, Wv+(size_t)(pc*2+1)*16384, bv+(size_t)(pc*2+1)*128, Kb+(size_t)nd*128, 0,0,nullptr,nullptr,nullptr);
        // per-relation: vr transform + aggregate (dst-major, atomic-free)
        for (int r=0; r<4; r++){
          int st = (c==0) ? stf[r] : dtf[r];
          int dt = (c==0) ? dtf[r] : stf[r];
          int Ns = st ? ni : nd;
          int Ndst = dt ? ni : nd;
          int ent = c*4 + r;
          xform_k<<<(Ns+63)/64,256,0,stream>>>(Kb + (st?(size_t)nd*128:0), Ns,
                                               MRm + (size_t)(pc*4+r)*4096, KR);
          e2_csr_k<<<((size_t)Ndst*32+255)/256,256,0,stream>>>(
              KR, LOGb + (size_t)eoff[r]*4,
              DEN + (dt?(size_t)nd*4:0),
              OFFS + (size_t)ent*NO, PERM + (size_t)c*EtotM + eoff[r], Ndst,
              QA + (dt?(size_t)nd*128:0));
        }
        // epilogue
        const float* sk0 = SKp + pc*2 + 0;
        const float* sk1 = SKp + pc*2 + 1;
        if (c == 0){
          gemm128_k<<<gbd,256,0,stream>>>(QA, nd, Wa+(size_t)(pc*2+0)*16384, ba+(size_t)(pc*2+0)*128, O1b, 2,1, xd, nullptr, sk0);
          gemm128_k<<<gbi,256,0,stream>>>(QA+(size_t)nd*128, ni, Wa+(size_t)(pc*2+1)*16384, ba+(size_t)(pc*2+1)*128, O1b+(size_t)nd*128, 2,1, xi, nullptr, sk1);
        } else {
          gemm128_k<<<gbd,256,0,stream>>>(QA, nd, Wa+(size_t)(pc*2+0)*16384, ba+(size_t)(pc*2+0)*128, X, 3,1, xd, O1b, sk0);
          gemm128_k<<<gbi,256,0,stream>>>(QA+(size_t)nd*128, ni, Wa+(size_t)(pc*2+1)*16384, ba+(size_t)(pc*2+1)*128, X+(size_t)nd*128, 3,1, xi, O1b+(size_t)nd*128, sk1);
        }
      }
    }
    // pooling for this graph
    float* fsum = GS[g]+OF_FSUM;  float* fcnt = GS[g]+OF_FCNT;
    float* cf   = GS[g]+OF_CF;    float* attc = GS[g]+OF_ATTC;
    float* femb = GS[g]+OF_FEMB;  float* pool = GS[g]+OF_POOL;
    hipMemsetAsync(GS[g], 0, (size_t)385280*4, stream);
    int nt8 = (nd + ni + 7)/8;
    f1_k<<<nt8,256,0,stream>>>(X, X+(size_t)nd*128, fdp, fip, nd, ni, fsum, fcnt);
    attc_k<<<1,128,0,stream>>>(fsum, 1.0f/(float)(nd+ni), WATT, attc);
    rowmean_k<<<(FFUNC*128+255)/256,256,0,stream>>>(fsum, fcnt);
    gemm128_k<<<(FFUNC+63)/64,256,0,stream>>>(fsum, FFUNC, WATT, nullptr, cf, 1,0,nullptr,nullptr,nullptr);
    f3_k<<<nt8,256,0,stream>>>(X, X+(size_t)nd*128, fdp, fip, nd, ni, cf, femb);
    a3_k<<<512,256,0,stream>>>(X, X+(size_t)nd*128, nd, ni, attc, pool);
  }
  // similarity histogram + final head
  hist_init_k<<<1,32,0,stream>>>(MM, HIST);
  dim3 gnt((FFUNC+15)/16, (FFUNC+15)/16);
  gemmnt_k<<<gnt,256,0,stream>>>(GS[0]+OF_FEMB, GS[1]+OF_FEMB, SCb, MM);
  hist_k<<<512,256,0,stream>>>(SCb, MM, HIST);
  final_k<<<1,256,0,stream>>>(GS[0]+OF_POOL, GS[1]+OF_POOL, WTN, VTN, BTN, HIST,
                              WFC1, BFC1, WSC, BSC, (float*)d_out);
}

// Round 4
// 4291.065 us; speedup vs baseline: 2.2538x; 1.3952x over previous
//
#include <hip/hip_runtime.h>
#include <math.h>

#define FFUNC 1000

typedef __attribute__((ext_vector_type(8))) short s8v;
typedef __attribute__((ext_vector_type(4))) float f4v;

// ---------------- device helpers ----------------
__device__ __forceinline__ float sigf(float x){ return 1.0f/(1.0f+expf(-x)); }
__device__ __forceinline__ float geluf(float x){
  return 0.5f*x*(1.0f + tanhf(0.7978845608028654f*(x + 0.044715f*x*x*x)));
}
__device__ __forceinline__ unsigned fkey(float f){
  unsigned u = __float_as_uint(f);
  return (u & 0x80000000u) ? ~u : (u | 0x80000000u);
}
__device__ __forceinline__ float funkey(unsigned k){
  unsigned u = (k & 0x80000000u) ? (k ^ 0x80000000u) : ~k;
  return __uint_as_float(u);
}
__device__ __forceinline__ void atomAddF(float* p, float v){ unsafeAtomicAdd(p, v); }
__device__ __forceinline__ unsigned short bfr(float x){   // f32 -> bf16 RNE
  unsigned u = __float_as_uint(x);
  unsigned r = (u + 0x7FFFu + ((u >> 16) & 1u)) >> 16;
  return (unsigned short)r;
}
__device__ __forceinline__ float b2f(unsigned short v){
  return __uint_as_float((unsigned)v << 16);
}

// ---------------- weight prepack: W[128][128] f32 -> B-fragment bf16 ----------------
// packed[((kt*8+nt)*64+l)*8+j] = W[kt*32 + 8*(l>>4)+j][nt*16 + (l&15)]
__global__ void packw_k(const float* __restrict__ W, unsigned short* __restrict__ out){
  int mat = blockIdx.x;
  const float* w = W + (size_t)mat*16384;
  unsigned short* o = out + (size_t)mat*16384;
  for (int u=0; u<64; u++){
    int oi = u*256 + threadIdx.x;
    int j = oi & 7, l = (oi>>3) & 63, nt = (oi>>9) & 7, kt = oi >> 12;
    float v = w[(size_t)(kt*32 + 8*(l>>4) + j)*128 + nt*16 + (l&15)];
    o[oi] = bfr(v);
  }
}

// relation prepack: a[h][32][32] f32 -> packed[((h*2+nt)*64+l)*8+j] = a[h][8*(l>>4)+j][nt*16+(l&15)]
__global__ void packa_k(const float* __restrict__ A, unsigned short* __restrict__ out){
  int ent = blockIdx.x;
  const float* a = A + (size_t)ent*4096;
  unsigned short* o = out + (size_t)ent*4096;
  for (int u=0; u<16; u++){
    int oi = u*256 + threadIdx.x;
    int j = oi & 7, l = (oi>>3) & 63, nt = (oi>>9) & 1, h = oi >> 10;
    float v = a[(size_t)h*1024 + (size_t)(8*(l>>4)+j)*32 + nt*16 + (l&15)];
    o[oi] = bfr(v);
  }
}

// ---------------- MFMA GEMM: out[N,128] = f(A[N,128] @ W + b) ----------------
// mode: 0 plain, 1 tanh, 2 skip, 3 skip+combine;  pregelu on A
__global__ __launch_bounds__(256) void gemmb_k(
    const float* __restrict__ A, int N,
    const unsigned short* __restrict__ Wp, const float* __restrict__ bias,
    float* __restrict__ outf, unsigned short* __restrict__ outb,
    int mode, int pregelu,
    const float* __restrict__ xin, const float* __restrict__ o1p,
    const float* __restrict__ skp)
{
  __shared__ __align__(16) unsigned short Bs[16384];
  int t = threadIdx.x;
  #pragma unroll
  for (int u=0; u<8; u++){
    int i = (u*256 + t)*8;
    *(uint4*)(Bs + i) = *(const uint4*)(Wp + i);
  }
  __syncthreads();
  int l = t & 63, w = t >> 6;
  int b = l >> 4, m = l & 15;
  int arow = blockIdx.x*64 + w*16 + m;
  bool rv = arow < N;
  f4v acc[8];
  #pragma unroll
  for (int nt=0; nt<8; nt++) acc[nt] = (f4v){0.f,0.f,0.f,0.f};

  #pragma unroll
  for (int kt=0; kt<4; kt++){
    s8v af;
    if (rv){
      const float* ap = A + (size_t)arow*128 + kt*32 + b*8;
      float4 x0 = *(const float4*)ap;
      float4 x1 = *(const float4*)(ap + 4);
      if (pregelu){
        x0.x=geluf(x0.x); x0.y=geluf(x0.y); x0.z=geluf(x0.z); x0.w=geluf(x0.w);
        x1.x=geluf(x1.x); x1.y=geluf(x1.y); x1.z=geluf(x1.z); x1.w=geluf(x1.w);
      }
      af[0]=(short)bfr(x0.x); af[1]=(short)bfr(x0.y); af[2]=(short)bfr(x0.z); af[3]=(short)bfr(x0.w);
      af[4]=(short)bfr(x1.x); af[5]=(short)bfr(x1.y); af[6]=(short)bfr(x1.z); af[7]=(short)bfr(x1.w);
    } else {
      af = (s8v){0,0,0,0,0,0,0,0};
    }
    #pragma unroll
    for (int nt=0; nt<8; nt++){
      s8v bf = *(const s8v*)(Bs + ((kt*8 + nt)*64 + l)*8);
      acc[nt] = __builtin_amdgcn_mfma_f32_16x16x32_bf16(af, bf, acc[nt], 0, 0, 0);
    }
  }

  float s=0.f, s1=0.f;
  if (mode >= 2){ s = sigf(skp[0]); s1 = 1.0f - s; }
  #pragma unroll
  for (int r2=0; r2<4; r2++){
    int orow = blockIdx.x*64 + w*16 + 4*b + r2;
    if (orow >= N) continue;
    #pragma unroll
    for (int nt=0; nt<8; nt++){
      int col = nt*16 + m;
      float v = acc[nt][r2];
      if (bias) v += bias[col];
      if (mode == 1) v = tanhf(v);
      else if (mode >= 2){
        float xi = xin[(size_t)orow*128 + col];
        v = s*v + s1*xi;
        if (mode == 3){
          float o1 = o1p[(size_t)orow*128 + col];
          v = fmaxf(0.5f*o1 + 0.5f*v, 0.f);
        }
      }
      if (outf) outf[(size_t)orow*128 + col] = v;
      if (outb) outb[(size_t)orow*128 + col] = bfr(v);
    }
  }
}

// ---------------- MFMA per-head transform: Xb[N,128] bf16 -> KR[N,128] bf16 ----------------
__global__ __launch_bounds__(256) void xformb_k(
    const unsigned short* __restrict__ Xb, int N,
    const unsigned short* __restrict__ Ap, unsigned short* __restrict__ out)
{
  __shared__ __align__(16) unsigned short Bs[4096];
  int t = threadIdx.x;
  #pragma unroll
  for (int u=0; u<2; u++){
    int i = (u*256 + t)*8;
    *(uint4*)(Bs + i) = *(const uint4*)(Ap + i);
  }
  __syncthreads();
  int l = t & 63, w = t >> 6;
  int b = l >> 4, m = l & 15;
  int arow = blockIdx.x*64 + w*16 + m;
  bool rv = arow < N;
  f4v acc[8];
  #pragma unroll
  for (int i=0;i<8;i++) acc[i] = (f4v){0.f,0.f,0.f,0.f};
  #pragma unroll
  for (int h=0; h<4; h++){
    s8v af;
    if (rv) af = *(const s8v*)(Xb + (size_t)arow*128 + h*32 + b*8);
    else af = (s8v){0,0,0,0,0,0,0,0};
    #pragma unroll
    for (int nt=0; nt<2; nt++){
      s8v bf = *(const s8v*)(Bs + ((h*2 + nt)*64 + l)*8);
      acc[h*2+nt] = __builtin_amdgcn_mfma_f32_16x16x32_bf16(af, bf, acc[h*2+nt], 0, 0, 0);
    }
  }
  #pragma unroll
  for (int r2=0; r2<4; r2++){
    int orow = blockIdx.x*64 + w*16 + 4*b + r2;
    if (orow >= N) continue;
    #pragma unroll
    for (int h=0; h<4; h++)
      #pragma unroll
      for (int nt=0; nt<2; nt++)
        out[(size_t)orow*128 + h*32 + nt*16 + m] = bfr(acc[h*2+nt][r2]);
  }
}

// ---------------- CSR build ----------------
struct ScanDesc { int n[8]; };

__global__ void csr_hist_k(const int* __restrict__ dst, int E, int* __restrict__ cnt){
  for (int e = blockIdx.x*256 + threadIdx.x; e < E; e += gridDim.x*256)
    atomicAdd(&cnt[dst[e]], 1);
}

__global__ void csr_scan_k(ScanDesc sd, int* __restrict__ offs, int* __restrict__ curs, int NO){
  int ent = blockIdx.x;
  int n = sd.n[ent];
  int* o  = offs + (size_t)ent*NO;
  int* cu = curs + (size_t)ent*NO;
  __shared__ int sb[1024];
  int tid = threadIdx.x;
  int run = 0;
  for (int base=0; base<n; base+=1024){
    int i = base + tid;
    int v = (i<n) ? o[i] : 0;
    sb[tid] = v; __syncthreads();
    for (int s=1; s<1024; s<<=1){
      int a = (tid>=s) ? sb[tid-s] : 0;
      __syncthreads();
      sb[tid] += a;
      __syncthreads();
    }
    int excl = run + sb[tid] - v;
    if (i < n){ o[i] = excl; cu[i] = excl; }
    run += sb[1023];
    __syncthreads();
  }
  if (tid == 0) o[n] = run;
}

__global__ void csr_fill_k(const int* __restrict__ dst, const int* __restrict__ src, int E,
                           int* __restrict__ curs, int* __restrict__ perm){
  for (int e = blockIdx.x*256 + threadIdx.x; e < E; e += gridDim.x*256){
    int pos = atomicAdd(&curs[dst[e]], 1);
    perm[pos] = src[e];
  }
}

// ---------------- E1 (dst-major): logits + per-dst max (bf16 inputs) ----------------
__global__ __launch_bounds__(256) void e1_csr_k(
    const unsigned short* __restrict__ kr, const unsigned short* __restrict__ q,
    const int* __restrict__ offs, const int* __restrict__ psrc, int Ndst,
    const float* __restrict__ prp, float* __restrict__ logits,
    unsigned* __restrict__ nmax)
{
  int gidx = blockIdx.x*256 + threadIdx.x;
  int d = gidx >> 5; if (d >= Ndst) return;
  int sub = gidx & 31, h = sub >> 3, j = sub & 7;
  int o0 = offs[d], o1 = offs[d+1];
  if (o0 == o1) return;
  ushort4 qa = *(const ushort4*)(q + (size_t)d*128 + h*32 + j*4);
  float q0=b2f(qa.x), q1=b2f(qa.y), q2=b2f(qa.z), q3=b2f(qa.w);
  float scale = prp[h] * 0.17677669529663687f;  // 1/sqrt(32)
  float mx = -INFINITY;
  for (int i=o0; i<o1; ++i){
    int s = psrc[i];
    ushort4 aa = *(const ushort4*)(kr + (size_t)s*128 + h*32 + j*4);
    float p = b2f(aa.x)*q0 + b2f(aa.y)*q1 + b2f(aa.z)*q2 + b2f(aa.w)*q3;
    p += __shfl_xor(p, 1, 8);
    p += __shfl_xor(p, 2, 8);
    p += __shfl_xor(p, 4, 8);
    float lg = p * scale;
    if (j == 0) logits[(size_t)i*4 + h] = lg;
    mx = fmaxf(mx, lg);
  }
  if (j == 0) atomicMax(&nmax[(size_t)d*4 + h], fkey(mx));
}

// ---------------- E1b (dst-major, all 4 relations): exp + denom ----------------
struct SegB {
  int blk0[5];
  int ndst[4];
  const int* offs[4];
  long eoff[4];
  int dty[4];
};
__global__ __launch_bounds__(256) void e1b_csr_k(SegB sg, float* __restrict__ logits,
    const unsigned* __restrict__ nmax_d, const unsigned* __restrict__ nmax_i,
    float* __restrict__ den_d, float* __restrict__ den_i)
{
  int b = blockIdx.x;
  int r = (b >= sg.blk0[1]) + (b >= sg.blk0[2]) + (b >= sg.blk0[3]);
  int pair = (b - sg.blk0[r])*256 + threadIdx.x;
  int d = pair >> 2, h = pair & 3;
  if (d >= sg.ndst[r]) return;
  const int* off = sg.offs[r];
  int o0 = off[d], o1 = off[d+1];
  if (o0 == o1) return;
  const unsigned* nm = sg.dty[r] ? nmax_i : nmax_d;
  float* dn = sg.dty[r] ? den_i : den_d;
  float mx = funkey(nm[(size_t)d*4 + h]);
  float* lg = logits + sg.eoff[r]*4;
  float acc = 0;
  for (int i=o0; i<o1; ++i){
    float ev = expf(lg[(size_t)i*4 + h] - mx);
    lg[(size_t)i*4 + h] = ev;
    acc += ev;
  }
  atomAddF(&dn[(size_t)d*4 + h], acc);
}

// ---------------- E2 (dst-major): weighted aggregate, no atomics (bf16 vr) ----------------
__global__ __launch_bounds__(256) void e2_csr_k(
    const unsigned short* __restrict__ vr, const float* __restrict__ evs,
    const float* __restrict__ den, const int* __restrict__ offs,
    const int* __restrict__ psrc, int Ndst, float* __restrict__ agg)
{
  int gidx = blockIdx.x*256 + threadIdx.x;
  int d = gidx >> 5; if (d >= Ndst) return;
  int sub = gidx & 31, h = sub >> 3, j = sub & 7;
  int o0 = offs[d], o1 = offs[d+1];
  if (o0 == o1) return;
  float inv = 1.0f / fmaxf(den[(size_t)d*4 + h], 1e-16f);
  float* ap = agg + (size_t)d*128 + h*32 + j*4;
  float4 acc = *(const float4*)ap;
  for (int i=o0; i<o1; ++i){
    int s = psrc[i];
    float w = evs[(size_t)i*4 + h] * inv;
    ushort4 v = *(const ushort4*)(vr + (size_t)s*128 + h*32 + j*4);
    acc.x += w*b2f(v.x); acc.y += w*b2f(v.y); acc.z += w*b2f(v.z); acc.w += w*b2f(v.w);
  }
  *(float4*)ap = acc;
}

// ---------------- func pool: sums + counts ----------------
__global__ void f1_k(const float* __restrict__ xd, const float* __restrict__ xi,
                     const int* __restrict__ fd, const int* __restrict__ fi,
                     int Nd, int Ni, float* __restrict__ fsum, float* __restrict__ fcnt)
{
  int t = threadIdx.x; int j = t & 31; int gl = t >> 5;
  long Nt = (long)Nd + Ni;
  for (long n = (long)blockIdx.x*8 + gl; n < Nt; n += (long)gridDim.x*8){
    const float* x; int f;
    if (n < Nd){ x = xd + n*128; f = fd[n]; }
    else       { x = xi + (n-Nd)*128; f = fi[n-Nd]; }
    float4 v = *(const float4*)(x + j*4);
    float* p = fsum + (size_t)f*128 + j*4;
    atomAddF(p, v.x); atomAddF(p+1, v.y); atomAddF(p+2, v.z); atomAddF(p+3, v.w);
    if (j == 0) atomAddF(fcnt + f, 1.0f);
  }
}

// ---------------- attention-pool context ----------------
__global__ void attc_k(const float* __restrict__ fsum, float Ninv,
                       const float* __restrict__ Watt, float* __restrict__ attc)
{
  __shared__ float mean[128];
  int j = threadIdx.x;
  float a = 0;
  for (int f=0; f<FFUNC; f++) a += fsum[(size_t)f*128 + j];
  mean[j] = a * Ninv;
  __syncthreads();
  float c = 0;
  for (int k=0;k<128;k++) c += mean[k]*Watt[(size_t)k*128 + j];
  attc[j] = tanhf(c);
}

__global__ void rowmean_k(float* __restrict__ fsum, const float* __restrict__ fcnt){
  int idx = blockIdx.x*256 + threadIdx.x;
  if (idx < FFUNC*128) fsum[idx] /= fmaxf(fcnt[idx>>7], 1.0f);
}

// ---------------- func pool: gated sum ----------------
__global__ void f3_k(const float* __restrict__ xd, const float* __restrict__ xi,
                     const int* __restrict__ fd, const int* __restrict__ fi,
                     int Nd, int Ni, const float* __restrict__ cf, float* __restrict__ femb)
{
  int t = threadIdx.x; int j = t & 31; int gl = t >> 5;
  long Nt = (long)Nd + Ni;
  for (long n = (long)blockIdx.x*8 + gl; n < Nt; n += (long)gridDim.x*8){
    const float* x; int f;
    if (n < Nd){ x = xd + n*128; f = fd[n]; }
    else       { x = xi + (n-Nd)*128; f = fi[n-Nd]; }
    float4 v = *(const float4*)(x + j*4);
    float4 c4 = *(const float4*)(cf + (size_t)f*128 + j*4);
    float p = v.x*c4.x + v.y*c4.y + v.z*c4.z + v.w*c4.w;
    p += __shfl_xor(p,1,32); p += __shfl_xor(p,2,32); p += __shfl_xor(p,4,32);
    p += __shfl_xor(p,8,32); p += __shfl_xor(p,16,32);
    float sg = sigf(p);
    float* fp = femb + (size_t)f*128 + j*4;
    atomAddF(fp, v.x*sg); atomAddF(fp+1, v.y*sg);
    atomAddF(fp+2, v.z*sg); atomAddF(fp+3, v.w*sg);
  }
}

// ---------------- attention pool: gated global sum ----------------
__global__ void a3_k(const float* __restrict__ xd, const float* __restrict__ xi,
                     int Nd, int Ni, const float* __restrict__ attc, float* __restrict__ pooled)
{
  __shared__ __align__(16) float cs[128];
  __shared__ __align__(16) float red[8][128];
  int t = threadIdx.x;
  if (t < 128) cs[t] = attc[t];
  __syncthreads();
  int j = t & 31, gl = t >> 5;
  float4 acc = make_float4(0.f,0.f,0.f,0.f);
  long Nt = (long)Nd + Ni;
  for (long n = (long)blockIdx.x*8 + gl; n < Nt; n += (long)gridDim.x*8){
    const float* x = (n < Nd) ? (xd + n*128) : (xi + (n-Nd)*128);
    float4 v = *(const float4*)(x + j*4);
    float4 c4 = *(const float4*)(&cs[j*4]);
    float p = v.x*c4.x + v.y*c4.y + v.z*c4.z + v.w*c4.w;
    p += __shfl_xor(p,1,32); p += __shfl_xor(p,2,32); p += __shfl_xor(p,4,32);
    p += __shfl_xor(p,8,32); p += __shfl_xor(p,16,32);
    float sg = sigf(p);
    acc.x += v.x*sg; acc.y += v.y*sg; acc.z += v.z*sg; acc.w += v.w*sg;
  }
  *(float4*)(&red[gl][j*4]) = acc;
  __syncthreads();
  if (t < 128){
    float a = 0;
    for (int g2=0; g2<8; g2++) a += red[g2][t];
    atomAddF(pooled + t, a);
  }
}

// ---------------- histogram: sc = f1@f2^T, track min/max ----------------
__global__ __launch_bounds__(256) void gemmnt_k(const float* __restrict__ fa,
                                                const float* __restrict__ fb,
                                                float* __restrict__ sc,
                                                unsigned* __restrict__ mmk)
{
  int t = threadIdx.x;
  int tx = t & 15, ty = t >> 4;
  int i = blockIdx.y*16 + ty, j = blockIdx.x*16 + tx;
  float mn = INFINITY, mx = -INFINITY;
  if (i < FFUNC && j < FFUNC){
    float a = 0;
    for (int k=0;k<128;k+=4){
      float4 A = *(const float4*)(fa + (size_t)i*128 + k);
      float4 B = *(const float4*)(fb + (size_t)j*128 + k);
      a += A.x*B.x + A.y*B.y + A.z*B.z + A.w*B.w;
    }
    sc[(size_t)i*FFUNC + j] = a;
    mn = a; mx = a;
  }
  __shared__ float smn[256], smx[256];
  smn[t]=mn; smx[t]=mx; __syncthreads();
  for (int o=128;o>0;o>>=1){
    if (t<o){ smn[t]=fminf(smn[t],smn[t+o]); smx[t]=fmaxf(smx[t],smx[t+o]); }
    __syncthreads();
  }
  if (t==0){ atomicMin(&mmk[0], fkey(smn[0])); atomicMax(&mmk[1], fkey(smx[0])); }
}

__global__ void hist_init_k(unsigned* mmk, unsigned* hist){
  int t = threadIdx.x;
  if (t==0){ mmk[0]=0xFFFFFFFFu; mmk[1]=0u; }
  if (t<16) hist[t]=0u;
}

__global__ void hist_k(const float* __restrict__ sc, const unsigned* __restrict__ mmk,
                       unsigned* __restrict__ hist)
{
  __shared__ unsigned hl[16];
  int t = threadIdx.x;
  if (t < 16) hl[t] = 0;
  __syncthreads();
  float mn = funkey(mmk[0]), mx = funkey(mmk[1]);
  float rng = fmaxf(mx - mn, 1e-12f);
  const long total = (long)FFUNC*FFUNC;
  for (long idx = (long)blockIdx.x*256 + t; idx < total; idx += (long)gridDim.x*256){
    float v = sc[idx];
    int b = (int)floorf((v - mn)/rng * 16.0f);
    b = min(max(b,0),15);
    atomicAdd(&hl[b], 1u);
  }
  __syncthreads();
  if (t < 16) atomicAdd(&hist[t], hl[t]);
}

// ---------------- final head ----------------
__global__ __launch_bounds__(256) void final_k(
    const float* __restrict__ p1, const float* __restrict__ p2,
    const float* __restrict__ Wtn, const float* __restrict__ Vtn,
    const float* __restrict__ btn, const unsigned* __restrict__ hist,
    const float* __restrict__ Wfc1, const float* __restrict__ bfc1,
    const float* __restrict__ Wsc, const float* __restrict__ bsc,
    float* __restrict__ outp)
{
  __shared__ float P1[128], P2[128], part[256], feats[32], hv[16];
  int t = threadIdx.x;
  if (t < 128){ P1[t] = p1[t]; P2[t] = p2[t]; }
  __syncthreads();
  int k = t & 15, pr_ = t >> 4;
  float acc = 0;
  for (int i = pr_*8; i < pr_*8+8; ++i){
    float pi = P1[i];
    const float* wrow = Wtn + ((size_t)i*128)*16 + k;
    float a2 = 0;
    for (int j=0;j<128;++j) a2 += P2[j]*wrow[(size_t)j*16];
    acc += pi*a2;
  }
  part[t] = acc;
  __syncthreads();
  if (t < 16){
    float sc_ = 0;
    for (int p=0;p<16;p++) sc_ += part[p*16 + t];
    float bl = btn[t];
    for (int j=0;j<256;j++) bl += Vtn[(size_t)t*256 + j] * (j<128 ? P1[j] : P2[j-128]);
    float tv = sc_ + bl;
    feats[t] = tv > 0.f ? tv : 0.f;
    feats[16+t] = (float)hist[t] * (1.0f/((float)FFUNC*(float)FFUNC));
  }
  __syncthreads();
  if (t < 16){
    float a2 = bfc1[t];
    for (int q2=0;q2<32;q2++) a2 += feats[q2]*Wfc1[q2*16 + t];
    hv[t] = a2 > 0.f ? a2 : 0.f;
  }
  __syncthreads();
  if (t == 0){
    float z = bsc[0];
    for (int m=0;m<16;m++) z += hv[m]*Wsc[m];
    outp[0] = sigf(z);
  }
}

// ---------------- host ----------------
extern "C" void kernel_launch(void* const* d_in, const int* in_sizes, int n_in,
                              void* d_out, int out_size, void* d_ws, size_t ws_size,
                              hipStream_t stream)
{
  (void)n_in; (void)out_size; (void)ws_size;
  const float* Wk = (const float*)d_in[16];
  const float* bk = (const float*)d_in[17];
  const float* Wq = (const float*)d_in[18];
  const float* bq = (const float*)d_in[19];
  const float* Wv = (const float*)d_in[20];
  const float* bv = (const float*)d_in[21];
  const float* Wa = (const float*)d_in[22];
  const float* ba = (const float*)d_in[23];
  const float* SKp = (const float*)d_in[24];
  const float* AR = (const float*)d_in[25];
  const float* MRm = (const float*)d_in[26];
  const float* PRp = (const float*)d_in[27];
  const float* WATT = (const float*)d_in[28];
  const float* WTN = (const float*)d_in[29];
  const float* VTN = (const float*)d_in[30];
  const float* BTN = (const float*)d_in[31];
  const float* WFC1 = (const float*)d_in[32];
  const float* BFC1 = (const float*)d_in[33];
  const float* WSC = (const float*)d_in[34];
  const float* BSC = (const float*)d_in[35];

  int NdA[2] = { in_sizes[0]/128, in_sizes[8]/128 };
  int NiA[2] = { in_sizes[1]/128, in_sizes[9]/128 };
  int EA[2][4];
  for (int g=0; g<2; g++)
    for (int r=0; r<4; r++) EA[g][r] = in_sizes[g*8+2+r]/2;

  int NdM = NdA[0] > NdA[1] ? NdA[0] : NdA[1];
  int NiM = NiA[0] > NiA[1] ? NiA[0] : NiA[1];
  long EtotM = 0;
  for (int g=0; g<2; g++){
    long et = 0; for (int r=0;r<4;r++) et += EA[g][r];
    if (et > EtotM) EtotM = et;
  }
  int NO = ((NiM + 2 + 63)/64)*64;

  char* wp = (char*)d_ws;
  auto alloc = [&](size_t bytes)->void*{
    void* p = (void*)wp;
    wp += (bytes + 255) & ~(size_t)255;
    return p;
  };
  size_t nrows = (size_t)NdM + (size_t)NiM;
  float*          X    = (float*)alloc(nrows*128*4);
  float*          AGG  = (float*)alloc(nrows*128*4);
  float*          O1b  = (float*)alloc(nrows*128*4);
  unsigned short* Kb   = (unsigned short*)alloc(nrows*128*2);
  unsigned short* Qb   = (unsigned short*)alloc(nrows*128*2);
  unsigned short* KR   = (unsigned short*)alloc((size_t)NiM*128*2);
  unsigned*       NMAX = (unsigned*)alloc(nrows*4*4);  // NMAX/DEN contiguous
  float*          DEN  = (float*)alloc(nrows*4*4);
  float*          LOGb = (float*)alloc((size_t)EtotM*4*4);
  int*            OFFS = (int*)alloc((size_t)8*NO*4);
  int*            PERM = (int*)alloc((size_t)2*EtotM*4);
  float*          GS[2];
  GS[0] = (float*)alloc((size_t)385280*4);
  GS[1] = (float*)alloc((size_t)385280*4);
  unsigned*       MM   = (unsigned*)alloc(2*4);
  unsigned*       HIST = (unsigned*)alloc(16*4);
  // packed weights (bf16 fragment order)
  unsigned short* WKP  = (unsigned short*)alloc((size_t)8*16384*2);
  unsigned short* WQP  = (unsigned short*)alloc((size_t)8*16384*2);
  unsigned short* WVP  = (unsigned short*)alloc((size_t)8*16384*2);
  unsigned short* WAP  = (unsigned short*)alloc((size_t)8*16384*2);
  unsigned short* WATTP= (unsigned short*)alloc((size_t)16384*2);
  unsigned short* ARP  = (unsigned short*)alloc((size_t)16*4096*2);
  unsigned short* MRP  = (unsigned short*)alloc((size_t)16*4096*2);
  // CURS aliases SCb (disjoint lifetimes)
  size_t uni_bytes = (size_t)FFUNC*FFUNC*4;
  size_t curs_bytes = (size_t)8*NO*4;
  void* UNI = alloc(uni_bytes > curs_bytes ? uni_bytes : curs_bytes);
  int*   CURS = (int*)UNI;
  float* SCb  = (float*)UNI;

  // ---- prepack all weights ----
  packw_k<<<8,256,0,stream>>>(Wk, WKP);
  packw_k<<<8,256,0,stream>>>(Wq, WQP);
  packw_k<<<8,256,0,stream>>>(Wv, WVP);
  packw_k<<<8,256,0,stream>>>(Wa, WAP);
  packw_k<<<1,256,0,stream>>>(WATT, WATTP);
  packa_k<<<16,256,0,stream>>>(AR, ARP);
  packa_k<<<16,256,0,stream>>>(MRm, MRP);

  const size_t OF_FSUM=0, OF_FCNT=128000, OF_CF=129024, OF_ATTC=257024, OF_FEMB=257152, OF_POOL=385152;
  const int stf[4] = {1,0,1,1};
  const int dtf[4] = {1,1,0,1};

  for (int g=0; g<2; ++g){
    int nd = NdA[g], ni = NiA[g];
    int E[4] = {EA[g][0],EA[g][1],EA[g][2],EA[g][3]};
    int eoff[4]; eoff[0]=0;
    for (int r=1;r<4;r++) eoff[r] = eoff[r-1] + E[r-1];
    const int* ei[4] = {(const int*)d_in[g*8+2], (const int*)d_in[g*8+3],
                        (const int*)d_in[g*8+4], (const int*)d_in[g*8+5]};
    const int* fdp = (const int*)d_in[g*8+6];
    const int* fip = (const int*)d_in[g*8+7];
    const float* x0d = (const float*)d_in[g*8+0];
    const float* x0i = (const float*)d_in[g*8+1];
    int gbd = (nd+63)/64, gbi = (ni+63)/64;

    // ---- build 8 CSRs ----
    hipMemsetAsync(OFFS, 0, (size_t)8*NO*4, stream);
    ScanDesc sd;
    for (int c2=0; c2<2; c2++)
      for (int r=0; r<4; r++){
        int ent = c2*4 + r;
        const int* dptr = (c2==0) ? ei[r]+E[r] : ei[r];
        int nds = ((c2==0) ? dtf[r] : stf[r]) ? ni : nd;
        sd.n[ent] = nds;
        int blks = (E[r]+255)/256; if (blks > 1024) blks = 1024;
        csr_hist_k<<<blks,256,0,stream>>>(dptr, E[r], OFFS + (size_t)ent*NO);
      }
    csr_scan_k<<<8,1024,0,stream>>>(sd, OFFS, CURS, NO);
    for (int c2=0; c2<2; c2++)
      for (int r=0; r<4; r++){
        int ent = c2*4 + r;
        const int* dptr = (c2==0) ? ei[r]+E[r] : ei[r];
        const int* sptr = (c2==0) ? ei[r] : ei[r]+E[r];
        int blks = (E[r]+255)/256; if (blks > 1024) blks = 1024;
        csr_fill_k<<<blks,256,0,stream>>>(dptr, sptr, E[r], CURS + (size_t)ent*NO,
                                          PERM + (size_t)c2*EtotM + eoff[r]);
      }

    for (int l=0; l<2; ++l){
      const float* xd = (l==0) ? x0d : X;
      const float* xi = (l==0) ? x0i : X + (size_t)nd*128;
      for (int c=0; c<2; ++c){
        int pc = l*2 + c;
        hipMemsetAsync(NMAX, 0, nrows*4*4*2, stream);
        hipMemsetAsync(AGG, 0, nrows*128*4, stream);
        // k, q projections -> bf16
        gemmb_k<<<gbd,256,0,stream>>>(xd, nd, WKP+(size_t)(pc*2+0)*16384, bk+(size_t)(pc*2+0)*128, nullptr, Kb, 0,0,nullptr,nullptr,nullptr);
        gemmb_k<<<gbi,256,0,stream>>>(xi, ni, WKP+(size_t)(pc*2+1)*16384, bk+(size_t)(pc*2+1)*128, nullptr, Kb+(size_t)nd*128, 0,0,nullptr,nullptr,nullptr);
        gemmb_k<<<gbd,256,0,stream>>>(xd, nd, WQP+(size_t)(pc*2+0)*16384, bq+(size_t)(pc*2+0)*128, nullptr, Qb, 0,0,nullptr,nullptr,nullptr);
        gemmb_k<<<gbi,256,0,stream>>>(xi, ni, WQP+(size_t)(pc*2+1)*16384, bq+(size_t)(pc*2+1)*128, nullptr, Qb+(size_t)nd*128, 0,0,nullptr,nullptr,nullptr);
        // per-relation: kr transform + logits/max
        for (int r=0; r<4; r++){
          int st = (c==0) ? stf[r] : dtf[r];
          int dt = (c==0) ? dtf[r] : stf[r];
          int Ns = st ? ni : nd;
          int Ndst = dt ? ni : nd;
          int ent = c*4 + r;
          xformb_k<<<(Ns+63)/64,256,0,stream>>>(Kb + (st?(size_t)nd*128:0), Ns,
                                                ARP + (size_t)(pc*4+r)*4096, KR);
          e1_csr_k<<<((size_t)Ndst*32+255)/256,256,0,stream>>>(
              KR, Qb + (dt?(size_t)nd*128:0),
              OFFS + (size_t)ent*NO, PERM + (size_t)c*EtotM + eoff[r], Ndst,
              PRp + (size_t)(pc*4+r)*4,
              LOGb + (size_t)eoff[r]*4,
              NMAX + (dt?(size_t)nd*4:0));
        }
        // E1b: exp + denom
        SegB sg; int tb = 0;
        for (int r=0;r<4;r++){
          int dt = (c==0) ? dtf[r] : stf[r];
          int Ndst = dt ? ni : nd;
          sg.blk0[r] = tb;
          sg.ndst[r] = Ndst;
          sg.offs[r] = OFFS + (size_t)(c*4+r)*NO;
          sg.eoff[r] = eoff[r];
          sg.dty[r]  = dt;
          tb += ((size_t)Ndst*4 + 255)/256;
        }
        sg.blk0[4] = tb;
        e1b_csr_k<<<tb,256,0,stream>>>(sg, LOGb, NMAX, NMAX+(size_t)nd*4, DEN, DEN+(size_t)nd*4);
        // v projections -> bf16 (reuse Kb slab)
        gemmb_k<<<gbd,256,0,stream>>>(xd, nd, WVP+(size_t)(pc*2+0)*16384, bv+(size_t)(pc*2+0)*128, nullptr, Kb, 0,0,nullptr,nullptr,nullptr);
        gemmb_k<<<gbi,256,0,stream>>>(xi, ni, WVP+(size_t)(pc*2+1)*16384, bv+(size_t)(pc*2+1)*128, nullptr, Kb+(size_t)nd*128, 0,0,nullptr,nullptr,nullptr);
        // per-relation: vr transform + aggregate
        for (int r=0; r<4; r++){
          int st = (c==0) ? stf[r] : dtf[r];
          int dt = (c==0) ? dtf[r] : stf[r];
          int Ns = st ? ni : nd;
          int Ndst = dt ? ni : nd;
          int ent = c*4 + r;
          xformb_k<<<(Ns+63)/64,256,0,stream>>>(Kb + (st?(size_t)nd*128:0), Ns,
                                                MRP + (size_t)(pc*4+r)*4096, KR);
          e2_csr_k<<<((size_t)Ndst*32+255)/256,256,0,stream>>>(
              KR, LOGb + (size_t)eoff[r]*4,
              DEN + (dt?(size_t)nd*4:0),
              OFFS + (size_t)ent*NO, PERM + (size_t)c*EtotM + eoff[r], Ndst,
              AGG + (dt?(size_t)nd*128:0));
        }
        // epilogue
        const float* sk0 = SKp + pc*2 + 0;
        const float* sk1 = SKp + pc*2 + 1;
        if (c == 0){
          gemmb_k<<<gbd,256,0,stream>>>(AGG, nd, WAP+(size_t)(pc*2+0)*16384, ba+(size_t)(pc*2+0)*128, O1b, nullptr, 2,1, xd, nullptr, sk0);
          gemmb_k<<<gbi,256,0,stream>>>(AGG+(size_t)nd*128, ni, WAP+(size_t)(pc*2+1)*16384, ba+(size_t)(pc*2+1)*128, O1b+(size_t)nd*128, nullptr, 2,1, xi, nullptr, sk1);
        } else {
          gemmb_k<<<gbd,256,0,stream>>>(AGG, nd, WAP+(size_t)(pc*2+0)*16384, ba+(size_t)(pc*2+0)*128, X, nullptr, 3,1, xd, O1b, sk0);
          gemmb_k<<<gbi,256,0,stream>>>(AGG+(size_t)nd*128, ni, WAP+(size_t)(pc*2+1)*16384, ba+(size_t)(pc*2+1)*128, X+(size_t)nd*128, nullptr, 3,1, xi, O1b+(size_t)nd*128, sk1);
        }
      }
    }
    // pooling for this graph
    float* fsum = GS[g]+OF_FSUM;  float* fcnt = GS[g]+OF_FCNT;
    float* cf   = GS[g]+OF_CF;    float* attc = GS[g]+OF_ATTC;
    float* femb = GS[g]+OF_FEMB;  float* pool = GS[g]+OF_POOL;
    hipMemsetAsync(GS[g], 0, (size_t)385280*4, stream);
    int nt8 = (nd + ni + 7)/8;
    f1_k<<<nt8,256,0,stream>>>(X, X+(size_t)nd*128, fdp, fip, nd, ni, fsum, fcnt);
    attc_k<<<1,128,0,stream>>>(fsum, 1.0f/(float)(nd+ni), WATT, attc);
    rowmean_k<<<(FFUNC*128+255)/256,256,0,stream>>>(fsum, fcnt);
    gemmb_k<<<(FFUNC+63)/64,256,0,stream>>>(fsum, FFUNC, WATTP, nullptr, cf, nullptr, 1,0,nullptr,nullptr,nullptr);
    f3_k<<<nt8,256,0,stream>>>(X, X+(size_t)nd*128, fdp, fip, nd, ni, cf, femb);
    a3_k<<<512,256,0,stream>>>(X, X+(size_t)nd*128, nd, ni, attc, pool);
  }
  // similarity histogram + final head
  hist_init_k<<<1,32,0,stream>>>(MM, HIST);
  dim3 gnt((FFUNC+15)/16, (FFUNC+15)/16);
  gemmnt_k<<<gnt,256,0,stream>>>(GS[0]+OF_FEMB, GS[1]+OF_FEMB, SCb, MM);
  hist_k<<<512,256,0,stream>>>(SCb, MM, HIST);
  final_k<<<1,256,0,stream>>>(GS[0]+OF_POOL, GS[1]+OF_POOL, WTN, VTN, BTN, HIST,
                              WFC1, BFC1, WSC, BSC, (float*)d_out);
}

// Round 5
// 4014.458 us; speedup vs baseline: 2.4091x; 1.0689x over previous
//
#include <hip/hip_runtime.h>
#include <math.h>

#define FFUNC 1000

typedef __attribute__((ext_vector_type(8))) short s8v;
typedef __attribute__((ext_vector_type(4))) float f4v;

// ---------------- device helpers ----------------
__device__ __forceinline__ float sigf(float x){ return 1.0f/(1.0f+expf(-x)); }
__device__ __forceinline__ float geluf(float x){
  return 0.5f*x*(1.0f + tanhf(0.7978845608028654f*(x + 0.044715f*x*x*x)));
}
__device__ __forceinline__ unsigned fkey(float f){
  unsigned u = __float_as_uint(f);
  return (u & 0x80000000u) ? ~u : (u | 0x80000000u);
}
__device__ __forceinline__ float funkey(unsigned k){
  unsigned u = (k & 0x80000000u) ? (k ^ 0x80000000u) : ~k;
  return __uint_as_float(u);
}
__device__ __forceinline__ void atomAddF(float* p, float v){ unsafeAtomicAdd(p, v); }
__device__ __forceinline__ unsigned short bfr(float x){   // f32 -> bf16 RNE
  unsigned u = __float_as_uint(x);
  unsigned r = (u + 0x7FFFu + ((u >> 16) & 1u)) >> 16;
  return (unsigned short)r;
}
__device__ __forceinline__ float b2f(unsigned short v){
  return __uint_as_float((unsigned)v << 16);
}

// ---------------- weight prepack: W[128][128] f32 -> B-fragment bf16 ----------------
__global__ void packw_k(const float* __restrict__ W, unsigned short* __restrict__ out){
  int mat = blockIdx.x;
  const float* w = W + (size_t)mat*16384;
  unsigned short* o = out + (size_t)mat*16384;
  for (int u=0; u<64; u++){
    int oi = u*256 + threadIdx.x;
    int j = oi & 7, l = (oi>>3) & 63, nt = (oi>>9) & 7, kt = oi >> 12;
    float v = w[(size_t)(kt*32 + 8*(l>>4) + j)*128 + nt*16 + (l&15)];
    o[oi] = bfr(v);
  }
}

// relation prepack: a[h][32][32] f32 -> packed[((h*2+nt)*64+l)*8+j]
__global__ void packa_k(const float* __restrict__ A, unsigned short* __restrict__ out){
  int ent = blockIdx.x;
  const float* a = A + (size_t)ent*4096;
  unsigned short* o = out + (size_t)ent*4096;
  for (int u=0; u<16; u++){
    int oi = u*256 + threadIdx.x;
    int j = oi & 7, l = (oi>>3) & 63, nt = (oi>>9) & 1, h = oi >> 10;
    float v = a[(size_t)h*1024 + (size_t)(8*(l>>4)+j)*32 + nt*16 + (l&15)];
    o[oi] = bfr(v);
  }
}

// ---------------- fused K/Q/V projection, both node types ----------------
__global__ __launch_bounds__(256) void gemm_kqv_k(
    const float* __restrict__ xd, const float* __restrict__ xi, int nd, int ni, int gbd,
    const unsigned short* __restrict__ WK, const unsigned short* __restrict__ WQ,
    const unsigned short* __restrict__ WV,
    const float* __restrict__ bK, const float* __restrict__ bQ, const float* __restrict__ bV,
    unsigned short* __restrict__ Kb, unsigned short* __restrict__ Qb,
    unsigned short* __restrict__ Vb)
{
  int blk = blockIdx.x;
  int ty = (blk >= gbd);
  const float* A = ty ? xi : xd;
  int N = ty ? ni : nd;
  int rbase = (ty ? (blk - gbd) : blk) * 64;
  size_t obase = ty ? (size_t)nd*128 : 0;
  const unsigned short* wk = WK + (ty ? 16384 : 0);
  const unsigned short* wq = WQ + (ty ? 16384 : 0);
  const unsigned short* wv = WV + (ty ? 16384 : 0);
  const float* bk2 = bK + (ty ? 128 : 0);
  const float* bq2 = bQ + (ty ? 128 : 0);
  const float* bv2 = bV + (ty ? 128 : 0);

  int t = threadIdx.x;
  int l = t & 63, w = t >> 6, b = l >> 4, m = l & 15;
  int arow = rbase + w*16 + m;
  bool rv = arow < N;
  f4v ak[8], aq[8], av[8];
  #pragma unroll
  for (int nt=0; nt<8; nt++){ ak[nt]=(f4v){0,0,0,0}; aq[nt]=(f4v){0,0,0,0}; av[nt]=(f4v){0,0,0,0}; }

  #pragma unroll
  for (int kt=0; kt<4; kt++){
    s8v af;
    if (rv){
      const float* ap = A + (size_t)arow*128 + kt*32 + b*8;
      float4 x0 = *(const float4*)ap;
      float4 x1 = *(const float4*)(ap + 4);
      af[0]=(short)bfr(x0.x); af[1]=(short)bfr(x0.y); af[2]=(short)bfr(x0.z); af[3]=(short)bfr(x0.w);
      af[4]=(short)bfr(x1.x); af[5]=(short)bfr(x1.y); af[6]=(short)bfr(x1.z); af[7]=(short)bfr(x1.w);
    } else af = (s8v){0,0,0,0,0,0,0,0};
    #pragma unroll
    for (int nt=0; nt<8; nt++){
      int fo = ((kt*8 + nt)*64 + l)*8;
      s8v bk_ = *(const s8v*)(wk + fo);
      s8v bq_ = *(const s8v*)(wq + fo);
      s8v bv_ = *(const s8v*)(wv + fo);
      ak[nt] = __builtin_amdgcn_mfma_f32_16x16x32_bf16(af, bk_, ak[nt], 0, 0, 0);
      aq[nt] = __builtin_amdgcn_mfma_f32_16x16x32_bf16(af, bq_, aq[nt], 0, 0, 0);
      av[nt] = __builtin_amdgcn_mfma_f32_16x16x32_bf16(af, bv_, av[nt], 0, 0, 0);
    }
  }
  float bkr[8], bqr[8], bvr[8];
  #pragma unroll
  for (int nt=0; nt<8; nt++){ int col=nt*16+m; bkr[nt]=bk2[col]; bqr[nt]=bq2[col]; bvr[nt]=bv2[col]; }
  #pragma unroll
  for (int r2=0; r2<4; r2++){
    int orow = rbase + w*16 + 4*b + r2;
    if (orow >= N) continue;
    size_t ob = obase + (size_t)orow*128 + m;
    #pragma unroll
    for (int nt=0; nt<8; nt++){
      Kb[ob + nt*16] = bfr(ak[nt][r2] + bkr[nt]);
      Qb[ob + nt*16] = bfr(aq[nt][r2] + bqr[nt]);
      Vb[ob + nt*16] = bfr(av[nt][r2] + bvr[nt]);
    }
  }
}

// ---------------- fused epilogue GEMM, both node types ----------------
// A = gelu(AGG/den); out = s*(A@Wa + ba) + (1-s)*xin;  mode3: relu(0.5*o1 + 0.5*that)
__global__ __launch_bounds__(256) void gemm_epi_k(
    const float* __restrict__ AGG, const float* __restrict__ DENb,
    int nd, int ni, int gbd,
    const unsigned short* __restrict__ WA, const float* __restrict__ bA,
    const float* __restrict__ xin_d, const float* __restrict__ xin_i,
    const float* __restrict__ o1p, float* __restrict__ out,
    const float* __restrict__ skp, int mode)
{
  int blk = blockIdx.x;
  int ty = (blk >= gbd);
  int N = ty ? ni : nd;
  int rbase = (ty ? (blk - gbd) : blk) * 64;
  int goff = ty ? nd : 0;
  const unsigned short* wa = WA + (ty ? 16384 : 0);
  const float* ba2 = bA + (ty ? 128 : 0);
  const float* xin = ty ? xin_i : xin_d;
  float s = sigf(skp[ty]), s1 = 1.0f - s;

  int t = threadIdx.x;
  int l = t & 63, w = t >> 6, b = l >> 4, m = l & 15;
  int arow = rbase + w*16 + m;
  bool rv = arow < N;
  f4v acc[8];
  #pragma unroll
  for (int nt=0; nt<8; nt++) acc[nt] = (f4v){0,0,0,0};

  #pragma unroll
  for (int kt=0; kt<4; kt++){
    s8v af;
    if (rv){
      size_t grow = (size_t)(goff + arow);
      float dv = 1.0f / fmaxf(DENb[grow*4 + kt], 1e-16f);
      const float* ap = AGG + grow*128 + kt*32 + b*8;
      float4 x0 = *(const float4*)ap;
      float4 x1 = *(const float4*)(ap + 4);
      x0.x=geluf(x0.x*dv); x0.y=geluf(x0.y*dv); x0.z=geluf(x0.z*dv); x0.w=geluf(x0.w*dv);
      x1.x=geluf(x1.x*dv); x1.y=geluf(x1.y*dv); x1.z=geluf(x1.z*dv); x1.w=geluf(x1.w*dv);
      af[0]=(short)bfr(x0.x); af[1]=(short)bfr(x0.y); af[2]=(short)bfr(x0.z); af[3]=(short)bfr(x0.w);
      af[4]=(short)bfr(x1.x); af[5]=(short)bfr(x1.y); af[6]=(short)bfr(x1.z); af[7]=(short)bfr(x1.w);
    } else af = (s8v){0,0,0,0,0,0,0,0};
    #pragma unroll
    for (int nt=0; nt<8; nt++){
      s8v bf = *(const s8v*)(wa + ((kt*8 + nt)*64 + l)*8);
      acc[nt] = __builtin_amdgcn_mfma_f32_16x16x32_bf16(af, bf, acc[nt], 0, 0, 0);
    }
  }
  #pragma unroll
  for (int r2=0; r2<4; r2++){
    int orow = rbase + w*16 + 4*b + r2;
    if (orow >= N) continue;
    size_t grow = (size_t)(goff + orow);
    #pragma unroll
    for (int nt=0; nt<8; nt++){
      int col = nt*16 + m;
      float v = acc[nt][r2] + ba2[col];
      float xv = xin[(size_t)orow*128 + col];
      v = s*v + s1*xv;
      if (mode == 3){
        float o1 = o1p[grow*128 + col];
        v = fmaxf(0.5f*o1 + 0.5f*v, 0.f);
      }
      out[grow*128 + col] = v;
    }
  }
}

// ---------------- MFMA per-head transform (no LDS) ----------------
__global__ __launch_bounds__(256) void xformb_k(
    const unsigned short* __restrict__ Xb, int N,
    const unsigned short* __restrict__ Ap, unsigned short* __restrict__ out)
{
  int t = threadIdx.x;
  int l = t & 63, w = t >> 6, b = l >> 4, m = l & 15;
  int arow = blockIdx.x*64 + w*16 + m;
  bool rv = arow < N;
  f4v acc[8];
  #pragma unroll
  for (int i=0;i<8;i++) acc[i] = (f4v){0,0,0,0};
  #pragma unroll
  for (int h=0; h<4; h++){
    s8v af;
    if (rv) af = *(const s8v*)(Xb + (size_t)arow*128 + h*32 + b*8);
    else af = (s8v){0,0,0,0,0,0,0,0};
    #pragma unroll
    for (int nt=0; nt<2; nt++){
      s8v bf = *(const s8v*)(Ap + ((h*2 + nt)*64 + l)*8);
      acc[h*2+nt] = __builtin_amdgcn_mfma_f32_16x16x32_bf16(af, bf, acc[h*2+nt], 0, 0, 0);
    }
  }
  #pragma unroll
  for (int r2=0; r2<4; r2++){
    int orow = blockIdx.x*64 + w*16 + 4*b + r2;
    if (orow >= N) continue;
    #pragma unroll
    for (int h=0; h<4; h++)
      #pragma unroll
      for (int nt=0; nt<2; nt++)
        out[(size_t)orow*128 + h*32 + nt*16 + m] = bfr(acc[h*2+nt][r2]);
  }
}

// ---------------- CSR build ----------------
struct ScanDesc { int n[8]; };

__global__ void csr_hist_k(const int* __restrict__ dst, int E, int* __restrict__ cnt){
  for (int e = blockIdx.x*256 + threadIdx.x; e < E; e += gridDim.x*256)
    atomicAdd(&cnt[dst[e]], 1);
}

__global__ void csr_scan_k(ScanDesc sd, int* __restrict__ offs, int* __restrict__ curs, int NO){
  int ent = blockIdx.x;
  int n = sd.n[ent];
  int* o  = offs + (size_t)ent*NO;
  int* cu = curs + (size_t)ent*NO;
  __shared__ int sb[1024];
  int tid = threadIdx.x;
  int run = 0;
  for (int base=0; base<n; base+=1024){
    int i = base + tid;
    int v = (i<n) ? o[i] : 0;
    sb[tid] = v; __syncthreads();
    for (int s=1; s<1024; s<<=1){
      int a = (tid>=s) ? sb[tid-s] : 0;
      __syncthreads();
      sb[tid] += a;
      __syncthreads();
    }
    int excl = run + sb[tid] - v;
    if (i < n){ o[i] = excl; cu[i] = excl; }
    run += sb[1023];
    __syncthreads();
  }
  if (tid == 0) o[n] = run;
}

__global__ void csr_fill_k(const int* __restrict__ dst, const int* __restrict__ src, int E,
                           int* __restrict__ curs, int* __restrict__ perm){
  for (int e = blockIdx.x*256 + threadIdx.x; e < E; e += gridDim.x*256){
    int pos = atomicAdd(&curs[dst[e]], 1);
    perm[pos] = src[e];
  }
}

// ---------------- E1 (dst-major): logits + per-dst max ----------------
__global__ __launch_bounds__(256) void e1_csr_k(
    const unsigned short* __restrict__ kr, const unsigned short* __restrict__ q,
    const int* __restrict__ offs, const int* __restrict__ psrc, int Ndst,
    const float* __restrict__ prp, float* __restrict__ logits,
    unsigned* __restrict__ nmax)
{
  int gidx = blockIdx.x*256 + threadIdx.x;
  int d = gidx >> 5; if (d >= Ndst) return;
  int sub = gidx & 31, h = sub >> 3, j = sub & 7;
  int o0 = offs[d], o1 = offs[d+1];
  if (o0 == o1) return;
  ushort4 qa = *(const ushort4*)(q + (size_t)d*128 + h*32 + j*4);
  float q0=b2f(qa.x), q1=b2f(qa.y), q2=b2f(qa.z), q3=b2f(qa.w);
  float scale = prp[h] * 0.17677669529663687f;  // 1/sqrt(32)
  float mx = -INFINITY;
  for (int i=o0; i<o1; ++i){
    int s = psrc[i];
    ushort4 aa = *(const ushort4*)(kr + (size_t)s*128 + h*32 + j*4);
    float p = b2f(aa.x)*q0 + b2f(aa.y)*q1 + b2f(aa.z)*q2 + b2f(aa.w)*q3;
    p += __shfl_xor(p, 1, 8);
    p += __shfl_xor(p, 2, 8);
    p += __shfl_xor(p, 4, 8);
    float lg = p * scale;
    if (j == 0) logits[(size_t)i*4 + h] = lg;
    mx = fmaxf(mx, lg);
  }
  if (j == 0) atomicMax(&nmax[(size_t)d*4 + h], fkey(mx));
}

// ---------------- E2 (dst-major): exp + unnormalized aggregate + denom ----------------
__global__ __launch_bounds__(256) void e2n_k(
    const unsigned short* __restrict__ vr, const float* __restrict__ logits,
    const unsigned* __restrict__ nmax, const int* __restrict__ offs,
    const int* __restrict__ psrc, int Ndst,
    float* __restrict__ agg, float* __restrict__ den)
{
  int gidx = blockIdx.x*256 + threadIdx.x;
  int d = gidx >> 5; if (d >= Ndst) return;
  int sub = gidx & 31, h = sub >> 3, j = sub & 7;
  int o0 = offs[d], o1 = offs[d+1];
  if (o0 == o1) return;
  float mx = funkey(nmax[(size_t)d*4 + h]);
  float4 acc = make_float4(0.f,0.f,0.f,0.f);
  float ds = 0.f;
  for (int i=o0; i<o1; ++i){
    int s = psrc[i];
    float ev = __expf(logits[(size_t)i*4 + h] - mx);
    ushort4 v = *(const ushort4*)(vr + (size_t)s*128 + h*32 + j*4);
    acc.x += ev*b2f(v.x); acc.y += ev*b2f(v.y); acc.z += ev*b2f(v.z); acc.w += ev*b2f(v.w);
    ds += ev;
  }
  float* ap = agg + (size_t)d*128 + h*32 + j*4;
  float4 old = *(const float4*)ap;
  old.x += acc.x; old.y += acc.y; old.z += acc.z; old.w += acc.w;
  *(float4*)ap = old;
  if (j == 0) den[(size_t)d*4 + h] += ds;
}

// ---------------- legacy LDS GEMM (used for cf only) ----------------
__global__ __launch_bounds__(256) void gemmb_k(
    const float* __restrict__ A, int N,
    const unsigned short* __restrict__ Wp, const float* __restrict__ bias,
    float* __restrict__ outf, unsigned short* __restrict__ outb,
    int mode, int pregelu,
    const float* __restrict__ xin, const float* __restrict__ o1p,
    const float* __restrict__ skp)
{
  int t = threadIdx.x;
  int l = t & 63, w = t >> 6, b = l >> 4, m = l & 15;
  int arow = blockIdx.x*64 + w*16 + m;
  bool rv = arow < N;
  f4v acc[8];
  #pragma unroll
  for (int nt=0; nt<8; nt++) acc[nt] = (f4v){0,0,0,0};
  #pragma unroll
  for (int kt=0; kt<4; kt++){
    s8v af;
    if (rv){
      const float* ap = A + (size_t)arow*128 + kt*32 + b*8;
      float4 x0 = *(const float4*)ap;
      float4 x1 = *(const float4*)(ap + 4);
      if (pregelu){
        x0.x=geluf(x0.x); x0.y=geluf(x0.y); x0.z=geluf(x0.z); x0.w=geluf(x0.w);
        x1.x=geluf(x1.x); x1.y=geluf(x1.y); x1.z=geluf(x1.z); x1.w=geluf(x1.w);
      }
      af[0]=(short)bfr(x0.x); af[1]=(short)bfr(x0.y); af[2]=(short)bfr(x0.z); af[3]=(short)bfr(x0.w);
      af[4]=(short)bfr(x1.x); af[5]=(short)bfr(x1.y); af[6]=(short)bfr(x1.z); af[7]=(short)bfr(x1.w);
    } else af = (s8v){0,0,0,0,0,0,0,0};
    #pragma unroll
    for (int nt=0; nt<8; nt++){
      s8v bf = *(const s8v*)(Wp + ((kt*8 + nt)*64 + l)*8);
      acc[nt] = __builtin_amdgcn_mfma_f32_16x16x32_bf16(af, bf, acc[nt], 0, 0, 0);
    }
  }
  float s=0.f, s1=0.f;
  if (mode >= 2){ s = sigf(skp[0]); s1 = 1.0f - s; }
  #pragma unroll
  for (int r2=0; r2<4; r2++){
    int orow = blockIdx.x*64 + w*16 + 4*b + r2;
    if (orow >= N) continue;
    #pragma unroll
    for (int nt=0; nt<8; nt++){
      int col = nt*16 + m;
      float v = acc[nt][r2];
      if (bias) v += bias[col];
      if (mode == 1) v = tanhf(v);
      else if (mode >= 2){
        float xi = xin[(size_t)orow*128 + col];
        v = s*v + s1*xi;
        if (mode == 3){
          float o1 = o1p[(size_t)orow*128 + col];
          v = fmaxf(0.5f*o1 + 0.5f*v, 0.f);
        }
      }
      if (outf) outf[(size_t)orow*128 + col] = v;
      if (outb) outb[(size_t)orow*128 + col] = bfr(v);
    }
  }
}

// ---------------- func pool: sums + counts ----------------
__global__ void f1_k(const float* __restrict__ xd, const float* __restrict__ xi,
                     const int* __restrict__ fd, const int* __restrict__ fi,
                     int Nd, int Ni, float* __restrict__ fsum, float* __restrict__ fcnt)
{
  int t = threadIdx.x; int j = t & 31; int gl = t >> 5;
  long Nt = (long)Nd + Ni;
  for (long n = (long)blockIdx.x*8 + gl; n < Nt; n += (long)gridDim.x*8){
    const float* x; int f;
    if (n < Nd){ x = xd + n*128; f = fd[n]; }
    else       { x = xi + (n-Nd)*128; f = fi[n-Nd]; }
    float4 v = *(const float4*)(x + j*4);
    float* p = fsum + (size_t)f*128 + j*4;
    atomAddF(p, v.x); atomAddF(p+1, v.y); atomAddF(p+2, v.z); atomAddF(p+3, v.w);
    if (j == 0) atomAddF(fcnt + f, 1.0f);
  }
}

// ---------------- attention-pool context ----------------
__global__ void attc_k(const float* __restrict__ fsum, float Ninv,
                       const float* __restrict__ Watt, float* __restrict__ attc)
{
  __shared__ float mean[128];
  int j = threadIdx.x;
  float a = 0;
  for (int f=0; f<FFUNC; f++) a += fsum[(size_t)f*128 + j];
  mean[j] = a * Ninv;
  __syncthreads();
  float c = 0;
  for (int k=0;k<128;k++) c += mean[k]*Watt[(size_t)k*128 + j];
  attc[j] = tanhf(c);
}

__global__ void rowmean_k(float* __restrict__ fsum, const float* __restrict__ fcnt){
  int idx = blockIdx.x*256 + threadIdx.x;
  if (idx < FFUNC*128) fsum[idx] /= fmaxf(fcnt[idx>>7], 1.0f);
}

// ---------------- func pool: gated sum ----------------
__global__ void f3_k(const float* __restrict__ xd, const float* __restrict__ xi,
                     const int* __restrict__ fd, const int* __restrict__ fi,
                     int Nd, int Ni, const float* __restrict__ cf, float* __restrict__ femb)
{
  int t = threadIdx.x; int j = t & 31; int gl = t >> 5;
  long Nt = (long)Nd + Ni;
  for (long n = (long)blockIdx.x*8 + gl; n < Nt; n += (long)gridDim.x*8){
    const float* x; int f;
    if (n < Nd){ x = xd + n*128; f = fd[n]; }
    else       { x = xi + (n-Nd)*128; f = fi[n-Nd]; }
    float4 v = *(const float4*)(x + j*4);
    float4 c4 = *(const float4*)(cf + (size_t)f*128 + j*4);
    float p = v.x*c4.x + v.y*c4.y + v.z*c4.z + v.w*c4.w;
    p += __shfl_xor(p,1,32); p += __shfl_xor(p,2,32); p += __shfl_xor(p,4,32);
    p += __shfl_xor(p,8,32); p += __shfl_xor(p,16,32);
    float sg = sigf(p);
    float* fp = femb + (size_t)f*128 + j*4;
    atomAddF(fp, v.x*sg); atomAddF(fp+1, v.y*sg);
    atomAddF(fp+2, v.z*sg); atomAddF(fp+3, v.w*sg);
  }
}

// ---------------- attention pool: gated global sum ----------------
__global__ void a3_k(const float* __restrict__ xd, const float* __restrict__ xi,
                     int Nd, int Ni, const float* __restrict__ attc, float* __restrict__ pooled)
{
  __shared__ __align__(16) float cs[128];
  __shared__ __align__(16) float red[8][128];
  int t = threadIdx.x;
  if (t < 128) cs[t] = attc[t];
  __syncthreads();
  int j = t & 31, gl = t >> 5;
  float4 acc = make_float4(0.f,0.f,0.f,0.f);
  long Nt = (long)Nd + Ni;
  for (long n = (long)blockIdx.x*8 + gl; n < Nt; n += (long)gridDim.x*8){
    const float* x = (n < Nd) ? (xd + n*128) : (xi + (n-Nd)*128);
    float4 v = *(const float4*)(x + j*4);
    float4 c4 = *(const float4*)(&cs[j*4]);
    float p = v.x*c4.x + v.y*c4.y + v.z*c4.z + v.w*c4.w;
    p += __shfl_xor(p,1,32); p += __shfl_xor(p,2,32); p += __shfl_xor(p,4,32);
    p += __shfl_xor(p,8,32); p += __shfl_xor(p,16,32);
    float sg = sigf(p);
    acc.x += v.x*sg; acc.y += v.y*sg; acc.z += v.z*sg; acc.w += v.w*sg;
  }
  *(float4*)(&red[gl][j*4]) = acc;
  __syncthreads();
  if (t < 128){
    float a = 0;
    for (int g2=0; g2<8; g2++) a += red[g2][t];
    atomAddF(pooled + t, a);
  }
}

// ---------------- histogram: sc = f1@f2^T, track min/max ----------------
__global__ __launch_bounds__(256) void gemmnt_k(const float* __restrict__ fa,
                                                const float* __restrict__ fb,
                                                float* __restrict__ sc,
                                                unsigned* __restrict__ mmk)
{
  int t = threadIdx.x;
  int tx = t & 15, ty = t >> 4;
  int i = blockIdx.y*16 + ty, j = blockIdx.x*16 + tx;
  float mn = INFINITY, mx = -INFINITY;
  if (i < FFUNC && j < FFUNC){
    float a = 0;
    for (int k=0;k<128;k+=4){
      float4 A = *(const float4*)(fa + (size_t)i*128 + k);
      float4 B = *(const float4*)(fb + (size_t)j*128 + k);
      a += A.x*B.x + A.y*B.y + A.z*B.z + A.w*B.w;
    }
    sc[(size_t)i*FFUNC + j] = a;
    mn = a; mx = a;
  }
  __shared__ float smn[256], smx[256];
  smn[t]=mn; smx[t]=mx; __syncthreads();
  for (int o=128;o>0;o>>=1){
    if (t<o){ smn[t]=fminf(smn[t],smn[t+o]); smx[t]=fmaxf(smx[t],smx[t+o]); }
    __syncthreads();
  }
  if (t==0){ atomicMin(&mmk[0], fkey(smn[0])); atomicMax(&mmk[1], fkey(smx[0])); }
}

__global__ void hist_init_k(unsigned* mmk, unsigned* hist){
  int t = threadIdx.x;
  if (t==0){ mmk[0]=0xFFFFFFFFu; mmk[1]=0u; }
  if (t<16) hist[t]=0u;
}

__global__ void hist_k(const float* __restrict__ sc, const unsigned* __restrict__ mmk,
                       unsigned* __restrict__ hist)
{
  __shared__ unsigned hl[16];
  int t = threadIdx.x;
  if (t < 16) hl[t] = 0;
  __syncthreads();
  float mn = funkey(mmk[0]), mx = funkey(mmk[1]);
  float rng = fmaxf(mx - mn, 1e-12f);
  const long total = (long)FFUNC*FFUNC;
  for (long idx = (long)blockIdx.x*256 + t; idx < total; idx += (long)gridDim.x*256){
    float v = sc[idx];
    int b = (int)floorf((v - mn)/rng * 16.0f);
    b = min(max(b,0),15);
    atomicAdd(&hl[b], 1u);
  }
  __syncthreads();
  if (t < 16) atomicAdd(&hist[t], hl[t]);
}

// ---------------- final head ----------------
__global__ __launch_bounds__(256) void final_k(
    const float* __restrict__ p1, const float* __restrict__ p2,
    const float* __restrict__ Wtn, const float* __restrict__ Vtn,
    const float* __restrict__ btn, const unsigned* __restrict__ hist,
    const float* __restrict__ Wfc1, const float* __restrict__ bfc1,
    const float* __restrict__ Wsc, const float* __restrict__ bsc,
    float* __restrict__ outp)
{
  __shared__ float P1[128], P2[128], part[256], feats[32], hv[16];
  int t = threadIdx.x;
  if (t < 128){ P1[t] = p1[t]; P2[t] = p2[t]; }
  __syncthreads();
  int k = t & 15, pr_ = t >> 4;
  float acc = 0;
  for (int i = pr_*8; i < pr_*8+8; ++i){
    float pi = P1[i];
    const float* wrow = Wtn + ((size_t)i*128)*16 + k;
    float a2 = 0;
    for (int j=0;j<128;++j) a2 += P2[j]*wrow[(size_t)j*16];
    acc += pi*a2;
  }
  part[t] = acc;
  __syncthreads();
  if (t < 16){
    float sc_ = 0;
    for (int p=0;p<16;p++) sc_ += part[p*16 + t];
    float bl = btn[t];
    for (int j=0;j<256;j++) bl += Vtn[(size_t)t*256 + j] * (j<128 ? P1[j] : P2[j-128]);
    float tv = sc_ + bl;
    feats[t] = tv > 0.f ? tv : 0.f;
    feats[16+t] = (float)hist[t] * (1.0f/((float)FFUNC*(float)FFUNC));
  }
  __syncthreads();
  if (t < 16){
    float a2 = bfc1[t];
    for (int q2=0;q2<32;q2++) a2 += feats[q2]*Wfc1[q2*16 + t];
    hv[t] = a2 > 0.f ? a2 : 0.f;
  }
  __syncthreads();
  if (t == 0){
    float z = bsc[0];
    for (int m=0;m<16;m++) z += hv[m]*Wsc[m];
    outp[0] = sigf(z);
  }
}

// ---------------- host ----------------
extern "C" void kernel_launch(void* const* d_in, const int* in_sizes, int n_in,
                              void* d_out, int out_size, void* d_ws, size_t ws_size,
                              hipStream_t stream)
{
  (void)n_in; (void)out_size; (void)ws_size;
  const float* Wk = (const float*)d_in[16];
  const float* bk = (const float*)d_in[17];
  const float* Wq = (const float*)d_in[18];
  const float* bq = (const float*)d_in[19];
  const float* Wv = (const float*)d_in[20];
  const float* bv = (const float*)d_in[21];
  const float* Wa = (const float*)d_in[22];
  const float* ba = (const float*)d_in[23];
  const float* SKp = (const float*)d_in[24];
  const float* AR = (const float*)d_in[25];
  const float* MRm = (const float*)d_in[26];
  const float* PRp = (const float*)d_in[27];
  const float* WATT = (const float*)d_in[28];
  const float* WTN = (const float*)d_in[29];
  const float* VTN = (const float*)d_in[30];
  const float* BTN = (const float*)d_in[31];
  const float* WFC1 = (const float*)d_in[32];
  const float* BFC1 = (const float*)d_in[33];
  const float* WSC = (const float*)d_in[34];
  const float* BSC = (const float*)d_in[35];

  int NdA[2] = { in_sizes[0]/128, in_sizes[8]/128 };
  int NiA[2] = { in_sizes[1]/128, in_sizes[9]/128 };
  int EA[2][4];
  for (int g=0; g<2; g++)
    for (int r=0; r<4; r++) EA[g][r] = in_sizes[g*8+2+r]/2;

  int NdM = NdA[0] > NdA[1] ? NdA[0] : NdA[1];
  int NiM = NiA[0] > NiA[1] ? NiA[0] : NiA[1];
  long EtotM = 0;
  for (int g=0; g<2; g++){
    long et = 0; for (int r=0;r<4;r++) et += EA[g][r];
    if (et > EtotM) EtotM = et;
  }
  int NO = ((NiM + 2 + 63)/64)*64;

  char* wp = (char*)d_ws;
  auto alloc = [&](size_t bytes)->void*{
    void* p = (void*)wp;
    wp += (bytes + 255) & ~(size_t)255;
    return p;
  };
  size_t nrows = (size_t)NdM + (size_t)NiM;
  float*          X    = (float*)alloc(nrows*128*4);
  // AGG / NMAX / DEN contiguous -> single memset per pass
  float*          AGG  = (float*)alloc(nrows*128*4);
  unsigned*       NMAX = (unsigned*)alloc(nrows*4*4);
  float*          DEN  = (float*)alloc(nrows*4*4);
  float*          O1b  = (float*)alloc(nrows*128*4);
  unsigned short* Kb   = (unsigned short*)alloc(nrows*128*2);
  unsigned short* Qb   = (unsigned short*)alloc(nrows*128*2);
  unsigned short* Vb   = (unsigned short*)alloc(nrows*128*2);
  unsigned short* KR   = (unsigned short*)alloc((size_t)NiM*128*2);
  float*          LOGb = (float*)alloc((size_t)EtotM*4*4);
  int*            OFFS = (int*)alloc((size_t)8*NO*4);
  int*            PERM = (int*)alloc((size_t)2*EtotM*4);
  float*          GS[2];
  GS[0] = (float*)alloc((size_t)385280*4);
  GS[1] = (float*)alloc((size_t)385280*4);
  unsigned*       MM   = (unsigned*)alloc(2*4);
  unsigned*       HIST = (unsigned*)alloc(16*4);
  unsigned short* WKP  = (unsigned short*)alloc((size_t)8*16384*2);
  unsigned short* WQP  = (unsigned short*)alloc((size_t)8*16384*2);
  unsigned short* WVP  = (unsigned short*)alloc((size_t)8*16384*2);
  unsigned short* WAP  = (unsigned short*)alloc((size_t)8*16384*2);
  unsigned short* WATTP= (unsigned short*)alloc((size_t)16384*2);
  unsigned short* ARP  = (unsigned short*)alloc((size_t)16*4096*2);
  unsigned short* MRP  = (unsigned short*)alloc((size_t)16*4096*2);
  size_t uni_bytes = (size_t)FFUNC*FFUNC*4;
  size_t curs_bytes = (size_t)8*NO*4;
  void* UNI = alloc(uni_bytes > curs_bytes ? uni_bytes : curs_bytes);
  int*   CURS = (int*)UNI;
  float* SCb  = (float*)UNI;

  packw_k<<<8,256,0,stream>>>(Wk, WKP);
  packw_k<<<8,256,0,stream>>>(Wq, WQP);
  packw_k<<<8,256,0,stream>>>(Wv, WVP);
  packw_k<<<8,256,0,stream>>>(Wa, WAP);
  packw_k<<<1,256,0,stream>>>(WATT, WATTP);
  packa_k<<<16,256,0,stream>>>(AR, ARP);
  packa_k<<<16,256,0,stream>>>(MRm, MRP);

  const size_t OF_FSUM=0, OF_FCNT=128000, OF_CF=129024, OF_ATTC=257024, OF_FEMB=257152, OF_POOL=385152;
  const int stf[4] = {1,0,1,1};
  const int dtf[4] = {1,1,0,1};

  for (int g=0; g<2; ++g){
    int nd = NdA[g], ni = NiA[g];
    int E[4] = {EA[g][0],EA[g][1],EA[g][2],EA[g][3]};
    int eoff[4]; eoff[0]=0;
    for (int r=1;r<4;r++) eoff[r] = eoff[r-1] + E[r-1];
    const int* ei[4] = {(const int*)d_in[g*8+2], (const int*)d_in[g*8+3],
                        (const int*)d_in[g*8+4], (const int*)d_in[g*8+5]};
    const int* fdp = (const int*)d_in[g*8+6];
    const int* fip = (const int*)d_in[g*8+7];
    const float* x0d = (const float*)d_in[g*8+0];
    const float* x0i = (const float*)d_in[g*8+1];
    int gbd = (nd+63)/64, gbi = (ni+63)/64;

    // ---- build 8 CSRs ----
    hipMemsetAsync(OFFS, 0, (size_t)8*NO*4, stream);
    ScanDesc sd;
    for (int c2=0; c2<2; c2++)
      for (int r=0; r<4; r++){
        int ent = c2*4 + r;
        const int* dptr = (c2==0) ? ei[r]+E[r] : ei[r];
        int nds = ((c2==0) ? dtf[r] : stf[r]) ? ni : nd;
        sd.n[ent] = nds;
        int blks = (E[r]+255)/256; if (blks > 1024) blks = 1024;
        csr_hist_k<<<blks,256,0,stream>>>(dptr, E[r], OFFS + (size_t)ent*NO);
      }
    csr_scan_k<<<8,1024,0,stream>>>(sd, OFFS, CURS, NO);
    for (int c2=0; c2<2; c2++)
      for (int r=0; r<4; r++){
        int ent = c2*4 + r;
        const int* dptr = (c2==0) ? ei[r]+E[r] : ei[r];
        const int* sptr = (c2==0) ? ei[r] : ei[r]+E[r];
        int blks = (E[r]+255)/256; if (blks > 1024) blks = 1024;
        csr_fill_k<<<blks,256,0,stream>>>(dptr, sptr, E[r], CURS + (size_t)ent*NO,
                                          PERM + (size_t)c2*EtotM + eoff[r]);
      }

    for (int l=0; l<2; ++l){
      const float* xd = (l==0) ? x0d : X;
      const float* xi = (l==0) ? x0i : X + (size_t)nd*128;
      for (int c=0; c<2; ++c){
        int pc = l*2 + c;
        // zero AGG + NMAX + DEN in one shot (contiguous)
        hipMemsetAsync(AGG, 0, nrows*128*4 + nrows*4*4*2, stream);
        // fused K/Q/V projection (both types, one launch)
        gemm_kqv_k<<<gbd+gbi,256,0,stream>>>(
            xd, xi, nd, ni, gbd,
            WKP+(size_t)pc*2*16384, WQP+(size_t)pc*2*16384, WVP+(size_t)pc*2*16384,
            bk+(size_t)pc*2*128, bq+(size_t)pc*2*128, bv+(size_t)pc*2*128,
            Kb, Qb, Vb);
        // per-relation: kr transform + logits/max
        for (int r=0; r<4; r++){
          int st = (c==0) ? stf[r] : dtf[r];
          int dt = (c==0) ? dtf[r] : stf[r];
          int Ns = st ? ni : nd;
          int Ndst = dt ? ni : nd;
          int ent = c*4 + r;
          xformb_k<<<(Ns+63)/64,256,0,stream>>>(Kb + (st?(size_t)nd*128:0), Ns,
                                                ARP + (size_t)(pc*4+r)*4096, KR);
          e1_csr_k<<<((size_t)Ndst*32+255)/256,256,0,stream>>>(
              KR, Qb + (dt?(size_t)nd*128:0),
              OFFS + (size_t)ent*NO, PERM + (size_t)c*EtotM + eoff[r], Ndst,
              PRp + (size_t)(pc*4+r)*4,
              LOGb + (size_t)eoff[r]*4,
              NMAX + (dt?(size_t)nd*4:0));
        }
        // per-relation: vr transform + exp/aggregate/denominator
        for (int r=0; r<4; r++){
          int st = (c==0) ? stf[r] : dtf[r];
          int dt = (c==0) ? dtf[r] : stf[r];
          int Ns = st ? ni : nd;
          int Ndst = dt ? ni : nd;
          int ent = c*4 + r;
          xformb_k<<<(Ns+63)/64,256,0,stream>>>(Vb + (st?(size_t)nd*128:0), Ns,
                                                MRP + (size_t)(pc*4+r)*4096, KR);
          e2n_k<<<((size_t)Ndst*32+255)/256,256,0,stream>>>(
              KR, LOGb + (size_t)eoff[r]*4,
              NMAX + (dt?(size_t)nd*4:0),
              OFFS + (size_t)ent*NO, PERM + (size_t)c*EtotM + eoff[r], Ndst,
              AGG + (dt?(size_t)nd*128:0), DEN + (dt?(size_t)nd*4:0));
        }
        // fused epilogue (both types, one launch); divide-by-den folded in
        gemm_epi_k<<<gbd+gbi,256,0,stream>>>(
            AGG, DEN, nd, ni, gbd,
            WAP+(size_t)pc*2*16384, ba+(size_t)pc*2*128,
            xd, xi,
            (c==1) ? O1b : nullptr,
            (c==0) ? O1b : X,
            SKp + (size_t)pc*2, (c==0) ? 2 : 3);
      }
    }
    // pooling for this graph
    float* fsum = GS[g]+OF_FSUM;  float* fcnt = GS[g]+OF_FCNT;
    float* cf   = GS[g]+OF_CF;    float* attc = GS[g]+OF_ATTC;
    float* femb = GS[g]+OF_FEMB;  float* pool = GS[g]+OF_POOL;
    hipMemsetAsync(GS[g], 0, (size_t)385280*4, stream);
    int nt8 = (nd + ni + 7)/8;
    f1_k<<<nt8,256,0,stream>>>(X, X+(size_t)nd*128, fdp, fip, nd, ni, fsum, fcnt);
    attc_k<<<1,128,0,stream>>>(fsum, 1.0f/(float)(nd+ni), WATT, attc);
    rowmean_k<<<(FFUNC*128+255)/256,256,0,stream>>>(fsum, fcnt);
    gemmb_k<<<(FFUNC+63)/64,256,0,stream>>>(fsum, FFUNC, WATTP, nullptr, cf, nullptr, 1,0,nullptr,nullptr,nullptr);
    f3_k<<<nt8,256,0,stream>>>(X, X+(size_t)nd*128, fdp, fip, nd, ni, cf, femb);
    a3_k<<<512,256,0,stream>>>(X, X+(size_t)nd*128, nd, ni, attc, pool);
  }
  // similarity histogram + final head
  hist_init_k<<<1,32,0,stream>>>(MM, HIST);
  dim3 gnt((FFUNC+15)/16, (FFUNC+15)/16);
  gemmnt_k<<<gnt,256,0,stream>>>(GS[0]+OF_FEMB, GS[1]+OF_FEMB, SCb, MM);
  hist_k<<<512,256,0,stream>>>(SCb, MM, HIST);
  final_k<<<1,256,0,stream>>>(GS[0]+OF_POOL, GS[1]+OF_POOL, WTN, VTN, BTN, HIST,
                              WFC1, BFC1, WSC, BSC, (float*)d_out);
}

// Round 6
// 3521.260 us; speedup vs baseline: 2.7466x; 1.1401x over previous
//
#include <hip/hip_runtime.h>
#include <math.h>

#define FFUNC 1000

typedef __attribute__((ext_vector_type(8))) short s8v;
typedef __attribute__((ext_vector_type(4))) float f4v;

// ---------------- device helpers ----------------
__device__ __forceinline__ float sigf(float x){ return 1.0f/(1.0f+expf(-x)); }
__device__ __forceinline__ float geluf(float x){
  return 0.5f*x*(1.0f + tanhf(0.7978845608028654f*(x + 0.044715f*x*x*x)));
}
__device__ __forceinline__ unsigned fkey(float f){
  unsigned u = __float_as_uint(f);
  return (u & 0x80000000u) ? ~u : (u | 0x80000000u);
}
__device__ __forceinline__ float funkey(unsigned k){
  unsigned u = (k & 0x80000000u) ? (k ^ 0x80000000u) : ~k;
  return __uint_as_float(u);
}
__device__ __forceinline__ void atomAddF(float* p, float v){ unsafeAtomicAdd(p, v); }
__device__ __forceinline__ unsigned short bfr(float x){   // f32 -> bf16 RNE
  unsigned u = __float_as_uint(x);
  unsigned r = (u + 0x7FFFu + ((u >> 16) & 1u)) >> 16;
  return (unsigned short)r;
}
__device__ __forceinline__ float b2f(unsigned short v){
  return __uint_as_float((unsigned)v << 16);
}

// ---------------- weight prepack: W[128][128] f32 -> B-fragment bf16 ----------------
__global__ void packw_k(const float* __restrict__ W, unsigned short* __restrict__ out){
  int mat = blockIdx.x;
  const float* w = W + (size_t)mat*16384;
  unsigned short* o = out + (size_t)mat*16384;
  for (int u=0; u<64; u++){
    int oi = u*256 + threadIdx.x;
    int j = oi & 7, l = (oi>>3) & 63, nt = (oi>>9) & 7, kt = oi >> 12;
    float v = w[(size_t)(kt*32 + 8*(l>>4) + j)*128 + nt*16 + (l&15)];
    o[oi] = bfr(v);
  }
}

// relation prepack
__global__ void packa_k(const float* __restrict__ A, unsigned short* __restrict__ out){
  int ent = blockIdx.x;
  const float* a = A + (size_t)ent*4096;
  unsigned short* o = out + (size_t)ent*4096;
  for (int u=0; u<16; u++){
    int oi = u*256 + threadIdx.x;
    int j = oi & 7, l = (oi>>3) & 63, nt = (oi>>9) & 1, h = oi >> 10;
    float v = a[(size_t)h*1024 + (size_t)(8*(l>>4)+j)*32 + nt*16 + (l&15)];
    o[oi] = bfr(v);
  }
}

// ---------------- fused K/Q/V projection, both node types ----------------
__global__ __launch_bounds__(256) void gemm_kqv_k(
    const float* __restrict__ xd, const float* __restrict__ xi, int nd, int ni, int gbd,
    const unsigned short* __restrict__ WK, const unsigned short* __restrict__ WQ,
    const unsigned short* __restrict__ WV,
    const float* __restrict__ bK, const float* __restrict__ bQ, const float* __restrict__ bV,
    unsigned short* __restrict__ Kb, unsigned short* __restrict__ Qb,
    unsigned short* __restrict__ Vb)
{
  int blk = blockIdx.x;
  int ty = (blk >= gbd);
  const float* A = ty ? xi : xd;
  int N = ty ? ni : nd;
  int rbase = (ty ? (blk - gbd) : blk) * 64;
  size_t obase = ty ? (size_t)nd*128 : 0;
  const unsigned short* wk = WK + (ty ? 16384 : 0);
  const unsigned short* wq = WQ + (ty ? 16384 : 0);
  const unsigned short* wv = WV + (ty ? 16384 : 0);
  const float* bk2 = bK + (ty ? 128 : 0);
  const float* bq2 = bQ + (ty ? 128 : 0);
  const float* bv2 = bV + (ty ? 128 : 0);

  int t = threadIdx.x;
  int l = t & 63, w = t >> 6, b = l >> 4, m = l & 15;
  int arow = rbase + w*16 + m;
  bool rv = arow < N;
  f4v ak[8], aq[8], av[8];
  #pragma unroll
  for (int nt=0; nt<8; nt++){ ak[nt]=(f4v){0,0,0,0}; aq[nt]=(f4v){0,0,0,0}; av[nt]=(f4v){0,0,0,0}; }

  #pragma unroll
  for (int kt=0; kt<4; kt++){
    s8v af;
    if (rv){
      const float* ap = A + (size_t)arow*128 + kt*32 + b*8;
      float4 x0 = *(const float4*)ap;
      float4 x1 = *(const float4*)(ap + 4);
      af[0]=(short)bfr(x0.x); af[1]=(short)bfr(x0.y); af[2]=(short)bfr(x0.z); af[3]=(short)bfr(x0.w);
      af[4]=(short)bfr(x1.x); af[5]=(short)bfr(x1.y); af[6]=(short)bfr(x1.z); af[7]=(short)bfr(x1.w);
    } else af = (s8v){0,0,0,0,0,0,0,0};
    #pragma unroll
    for (int nt=0; nt<8; nt++){
      int fo = ((kt*8 + nt)*64 + l)*8;
      s8v bk_ = *(const s8v*)(wk + fo);
      s8v bq_ = *(const s8v*)(wq + fo);
      s8v bv_ = *(const s8v*)(wv + fo);
      ak[nt] = __builtin_amdgcn_mfma_f32_16x16x32_bf16(af, bk_, ak[nt], 0, 0, 0);
      aq[nt] = __builtin_amdgcn_mfma_f32_16x16x32_bf16(af, bq_, aq[nt], 0, 0, 0);
      av[nt] = __builtin_amdgcn_mfma_f32_16x16x32_bf16(af, bv_, av[nt], 0, 0, 0);
    }
  }
  float bkr[8], bqr[8], bvr[8];
  #pragma unroll
  for (int nt=0; nt<8; nt++){ int col=nt*16+m; bkr[nt]=bk2[col]; bqr[nt]=bq2[col]; bvr[nt]=bv2[col]; }
  #pragma unroll
  for (int r2=0; r2<4; r2++){
    int orow = rbase + w*16 + 4*b + r2;
    if (orow >= N) continue;
    size_t ob = obase + (size_t)orow*128 + m;
    #pragma unroll
    for (int nt=0; nt<8; nt++){
      Kb[ob + nt*16] = bfr(ak[nt][r2] + bkr[nt]);
      Qb[ob + nt*16] = bfr(aq[nt][r2] + bqr[nt]);
      Vb[ob + nt*16] = bfr(av[nt][r2] + bvr[nt]);
    }
  }
}

// ---------------- fused epilogue GEMM, both node types ----------------
__global__ __launch_bounds__(256) void gemm_epi_k(
    const float* __restrict__ AGG, const float* __restrict__ DENb,
    int nd, int ni, int gbd,
    const unsigned short* __restrict__ WA, const float* __restrict__ bA,
    const float* __restrict__ xin_d, const float* __restrict__ xin_i,
    const float* __restrict__ o1p, float* __restrict__ out,
    const float* __restrict__ skp, int mode)
{
  int blk = blockIdx.x;
  int ty = (blk >= gbd);
  int N = ty ? ni : nd;
  int rbase = (ty ? (blk - gbd) : blk) * 64;
  int goff = ty ? nd : 0;
  const unsigned short* wa = WA + (ty ? 16384 : 0);
  const float* ba2 = bA + (ty ? 128 : 0);
  const float* xin = ty ? xin_i : xin_d;
  float s = sigf(skp[ty]), s1 = 1.0f - s;

  int t = threadIdx.x;
  int l = t & 63, w = t >> 6, b = l >> 4, m = l & 15;
  int arow = rbase + w*16 + m;
  bool rv = arow < N;
  f4v acc[8];
  #pragma unroll
  for (int nt=0; nt<8; nt++) acc[nt] = (f4v){0,0,0,0};

  #pragma unroll
  for (int kt=0; kt<4; kt++){
    s8v af;
    if (rv){
      size_t grow = (size_t)(goff + arow);
      float dv = 1.0f / fmaxf(DENb[grow*4 + kt], 1e-16f);
      const float* ap = AGG + grow*128 + kt*32 + b*8;
      float4 x0 = *(const float4*)ap;
      float4 x1 = *(const float4*)(ap + 4);
      x0.x=geluf(x0.x*dv); x0.y=geluf(x0.y*dv); x0.z=geluf(x0.z*dv); x0.w=geluf(x0.w*dv);
      x1.x=geluf(x1.x*dv); x1.y=geluf(x1.y*dv); x1.z=geluf(x1.z*dv); x1.w=geluf(x1.w*dv);
      af[0]=(short)bfr(x0.x); af[1]=(short)bfr(x0.y); af[2]=(short)bfr(x0.z); af[3]=(short)bfr(x0.w);
      af[4]=(short)bfr(x1.x); af[5]=(short)bfr(x1.y); af[6]=(short)bfr(x1.z); af[7]=(short)bfr(x1.w);
    } else af = (s8v){0,0,0,0,0,0,0,0};
    #pragma unroll
    for (int nt=0; nt<8; nt++){
      s8v bf = *(const s8v*)(wa + ((kt*8 + nt)*64 + l)*8);
      acc[nt] = __builtin_amdgcn_mfma_f32_16x16x32_bf16(af, bf, acc[nt], 0, 0, 0);
    }
  }
  #pragma unroll
  for (int r2=0; r2<4; r2++){
    int orow = rbase + w*16 + 4*b + r2;
    if (orow >= N) continue;
    size_t grow = (size_t)(goff + orow);
    #pragma unroll
    for (int nt=0; nt<8; nt++){
      int col = nt*16 + m;
      float v = acc[nt][r2] + ba2[col];
      float xv = xin[(size_t)orow*128 + col];
      v = s*v + s1*xv;
      if (mode == 3){
        float o1 = o1p[grow*128 + col];
        v = fmaxf(0.5f*o1 + 0.5f*v, 0.f);
      }
      out[grow*128 + col] = v;
    }
  }
}

// ---------------- MFMA per-head transform (no LDS) ----------------
__global__ __launch_bounds__(256) void xformb_k(
    const unsigned short* __restrict__ Xb, int N,
    const unsigned short* __restrict__ Ap, unsigned short* __restrict__ out)
{
  int t = threadIdx.x;
  int l = t & 63, w = t >> 6, b = l >> 4, m = l & 15;
  int arow = blockIdx.x*64 + w*16 + m;
  bool rv = arow < N;
  f4v acc[8];
  #pragma unroll
  for (int i=0;i<8;i++) acc[i] = (f4v){0,0,0,0};
  #pragma unroll
  for (int h=0; h<4; h++){
    s8v af;
    if (rv) af = *(const s8v*)(Xb + (size_t)arow*128 + h*32 + b*8);
    else af = (s8v){0,0,0,0,0,0,0,0};
    #pragma unroll
    for (int nt=0; nt<2; nt++){
      s8v bf = *(const s8v*)(Ap + ((h*2 + nt)*64 + l)*8);
      acc[h*2+nt] = __builtin_amdgcn_mfma_f32_16x16x32_bf16(af, bf, acc[h*2+nt], 0, 0, 0);
    }
  }
  #pragma unroll
  for (int r2=0; r2<4; r2++){
    int orow = blockIdx.x*64 + w*16 + 4*b + r2;
    if (orow >= N) continue;
    #pragma unroll
    for (int h=0; h<4; h++)
      #pragma unroll
      for (int nt=0; nt<2; nt++)
        out[(size_t)orow*128 + h*32 + nt*16 + m] = bfr(acc[h*2+nt][r2]);
  }
}

// ---------------- CSR build ----------------
struct ScanDesc { int n[8]; };

__global__ void csr_hist_k(const int* __restrict__ dst, int E, int* __restrict__ cnt){
  for (int e = blockIdx.x*256 + threadIdx.x; e < E; e += gridDim.x*256)
    atomicAdd(&cnt[dst[e]], 1);
}

__global__ void csr_scan_k(ScanDesc sd, int* __restrict__ offs, int* __restrict__ curs, int NO){
  int ent = blockIdx.x;
  int n = sd.n[ent];
  int* o  = offs + (size_t)ent*NO;
  int* cu = curs + (size_t)ent*NO;
  __shared__ int sb[1024];
  int tid = threadIdx.x;
  int run = 0;
  for (int base=0; base<n; base+=1024){
    int i = base + tid;
    int v = (i<n) ? o[i] : 0;
    sb[tid] = v; __syncthreads();
    for (int s=1; s<1024; s<<=1){
      int a = (tid>=s) ? sb[tid-s] : 0;
      __syncthreads();
      sb[tid] += a;
      __syncthreads();
    }
    int excl = run + sb[tid] - v;
    if (i < n){ o[i] = excl; cu[i] = excl; }
    run += sb[1023];
    __syncthreads();
  }
  if (tid == 0) o[n] = run;
}

__global__ void csr_fill_k(const int* __restrict__ dst, const int* __restrict__ src, int E,
                           int* __restrict__ curs, int* __restrict__ perm){
  for (int e = blockIdx.x*256 + threadIdx.x; e < E; e += gridDim.x*256){
    int pos = atomicAdd(&curs[dst[e]], 1);
    perm[pos] = src[e];
  }
}

// ---------------- function-CSR build ----------------
__global__ void fhist_k(const int* __restrict__ fd, const int* __restrict__ fi,
                        int Nd, int Ni, int* __restrict__ cnt){
  int nt = Nd + Ni;
  for (int n = blockIdx.x*256 + threadIdx.x; n < nt; n += gridDim.x*256){
    int f = (n < Nd) ? fd[n] : fi[n-Nd];
    atomicAdd(&cnt[f], 1);
  }
}

__global__ void ffill_k(const int* __restrict__ fd, const int* __restrict__ fi,
                        int Nd, int Ni, int* __restrict__ curs, int* __restrict__ perm){
  int nt = Nd + Ni;
  for (int n = blockIdx.x*256 + threadIdx.x; n < nt; n += gridDim.x*256){
    int f = (n < Nd) ? fd[n] : fi[n-Nd];
    int pos = atomicAdd(&curs[f], 1);
    perm[pos] = n;
  }
}

// ---------------- E1 (dst-major): logits + per-dst max ----------------
__global__ __launch_bounds__(256) void e1_csr_k(
    const unsigned short* __restrict__ kr, const unsigned short* __restrict__ q,
    const int* __restrict__ offs, const int* __restrict__ psrc, int Ndst,
    const float* __restrict__ prp, float* __restrict__ logits,
    unsigned* __restrict__ nmax)
{
  int gidx = blockIdx.x*256 + threadIdx.x;
  int d = gidx >> 5; if (d >= Ndst) return;
  int sub = gidx & 31, h = sub >> 3, j = sub & 7;
  int o0 = offs[d], o1 = offs[d+1];
  if (o0 == o1) return;
  ushort4 qa = *(const ushort4*)(q + (size_t)d*128 + h*32 + j*4);
  float q0=b2f(qa.x), q1=b2f(qa.y), q2=b2f(qa.z), q3=b2f(qa.w);
  float scale = prp[h] * 0.17677669529663687f;  // 1/sqrt(32)
  float mx = -INFINITY;
  for (int i=o0; i<o1; ++i){
    int s = psrc[i];
    ushort4 aa = *(const ushort4*)(kr + (size_t)s*128 + h*32 + j*4);
    float p = b2f(aa.x)*q0 + b2f(aa.y)*q1 + b2f(aa.z)*q2 + b2f(aa.w)*q3;
    p += __shfl_xor(p, 1, 8);
    p += __shfl_xor(p, 2, 8);
    p += __shfl_xor(p, 4, 8);
    float lg = p * scale;
    if (j == 0) logits[(size_t)i*4 + h] = lg;
    mx = fmaxf(mx, lg);
  }
  if (j == 0) atomicMax(&nmax[(size_t)d*4 + h], fkey(mx));
}

// ---------------- E2 (dst-major): exp + unnormalized aggregate + denom ----------------
__global__ __launch_bounds__(256) void e2n_k(
    const unsigned short* __restrict__ vr, const float* __restrict__ logits,
    const unsigned* __restrict__ nmax, const int* __restrict__ offs,
    const int* __restrict__ psrc, int Ndst,
    float* __restrict__ agg, float* __restrict__ den)
{
  int gidx = blockIdx.x*256 + threadIdx.x;
  int d = gidx >> 5; if (d >= Ndst) return;
  int sub = gidx & 31, h = sub >> 3, j = sub & 7;
  int o0 = offs[d], o1 = offs[d+1];
  if (o0 == o1) return;
  float mx = funkey(nmax[(size_t)d*4 + h]);
  float4 acc = make_float4(0.f,0.f,0.f,0.f);
  float ds = 0.f;
  for (int i=o0; i<o1; ++i){
    int s = psrc[i];
    float ev = __expf(logits[(size_t)i*4 + h] - mx);
    ushort4 v = *(const ushort4*)(vr + (size_t)s*128 + h*32 + j*4);
    acc.x += ev*b2f(v.x); acc.y += ev*b2f(v.y); acc.z += ev*b2f(v.z); acc.w += ev*b2f(v.w);
    ds += ev;
  }
  float* ap = agg + (size_t)d*128 + h*32 + j*4;
  float4 old = *(const float4*)ap;
  old.x += acc.x; old.y += acc.y; old.z += acc.z; old.w += acc.w;
  *(float4*)ap = old;
  if (j == 0) den[(size_t)d*4 + h] += ds;
}

// ---------------- plain MFMA GEMM (cf only) ----------------
__global__ __launch_bounds__(256) void gemmb_k(
    const float* __restrict__ A, int N,
    const unsigned short* __restrict__ Wp, const float* __restrict__ bias,
    float* __restrict__ outf, unsigned short* __restrict__ outb,
    int mode, int pregelu,
    const float* __restrict__ xin, const float* __restrict__ o1p,
    const float* __restrict__ skp)
{
  int t = threadIdx.x;
  int l = t & 63, w = t >> 6, b = l >> 4, m = l & 15;
  int arow = blockIdx.x*64 + w*16 + m;
  bool rv = arow < N;
  f4v acc[8];
  #pragma unroll
  for (int nt=0; nt<8; nt++) acc[nt] = (f4v){0,0,0,0};
  #pragma unroll
  for (int kt=0; kt<4; kt++){
    s8v af;
    if (rv){
      const float* ap = A + (size_t)arow*128 + kt*32 + b*8;
      float4 x0 = *(const float4*)ap;
      float4 x1 = *(const float4*)(ap + 4);
      if (pregelu){
        x0.x=geluf(x0.x); x0.y=geluf(x0.y); x0.z=geluf(x0.z); x0.w=geluf(x0.w);
        x1.x=geluf(x1.x); x1.y=geluf(x1.y); x1.z=geluf(x1.z); x1.w=geluf(x1.w);
      }
      af[0]=(short)bfr(x0.x); af[1]=(short)bfr(x0.y); af[2]=(short)bfr(x0.z); af[3]=(short)bfr(x0.w);
      af[4]=(short)bfr(x1.x); af[5]=(short)bfr(x1.y); af[6]=(short)bfr(x1.z); af[7]=(short)bfr(x1.w);
    } else af = (s8v){0,0,0,0,0,0,0,0};
    #pragma unroll
    for (int nt=0; nt<8; nt++){
      s8v bf = *(const s8v*)(Wp + ((kt*8 + nt)*64 + l)*8);
      acc[nt] = __builtin_amdgcn_mfma_f32_16x16x32_bf16(af, bf, acc[nt], 0, 0, 0);
    }
  }
  float s=0.f, s1=0.f;
  if (mode >= 2){ s = sigf(skp[0]); s1 = 1.0f - s; }
  #pragma unroll
  for (int r2=0; r2<4; r2++){
    int orow = blockIdx.x*64 + w*16 + 4*b + r2;
    if (orow >= N) continue;
    #pragma unroll
    for (int nt=0; nt<8; nt++){
      int col = nt*16 + m;
      float v = acc[nt][r2];
      if (bias) v += bias[col];
      if (mode == 1) v = tanhf(v);
      else if (mode >= 2){
        float xi = xin[(size_t)orow*128 + col];
        v = s*v + s1*xi;
        if (mode == 3){
          float o1 = o1p[(size_t)orow*128 + col];
          v = fmaxf(0.5f*o1 + 0.5f*v, 0.f);
        }
      }
      if (outf) outf[(size_t)orow*128 + col] = v;
      if (outb) outb[(size_t)orow*128 + col] = bfr(v);
    }
  }
}

// ---------------- func pool (CSR): sums + counts, atomic-free ----------------
__global__ __launch_bounds__(256) void f1c_k(const float* __restrict__ X,
    const int* __restrict__ foffs, const int* __restrict__ fperm,
    float* __restrict__ fsum, float* __restrict__ fcnt)
{
  __shared__ __align__(16) float red[4][128];
  int t = threadIdx.x, wv = t >> 6, lane = t & 63;
  int f = blockIdx.x;
  int o0 = foffs[f], o1 = foffs[f+1];
  float a0 = 0, a1 = 0;
  for (int i = o0 + wv; i < o1; i += 4){
    const float* x = X + (size_t)fperm[i]*128 + lane*2;
    a0 += x[0]; a1 += x[1];
  }
  red[wv][lane*2] = a0; red[wv][lane*2+1] = a1;
  __syncthreads();
  if (t < 128)
    fsum[(size_t)f*128 + t] = red[0][t] + red[1][t] + red[2][t] + red[3][t];
  if (t == 0) fcnt[f] = (float)(o1 - o0);
}

// ---------------- func pool (CSR): femb + global attention pool fused ----------------
__global__ __launch_bounds__(256) void f23c_k(const float* __restrict__ X,
    const int* __restrict__ foffs, const int* __restrict__ fperm,
    const float* __restrict__ cf, const float* __restrict__ attc,
    float* __restrict__ femb, float* __restrict__ pooled)
{
  __shared__ __align__(16) float rede[4][128];
  __shared__ __align__(16) float redp[4][128];
  int t = threadIdx.x, wv = t >> 6, lane = t & 63;
  int f = blockIdx.x;
  int o0 = foffs[f], o1 = foffs[f+1];
  float c0 = cf[(size_t)f*128 + lane*2], c1 = cf[(size_t)f*128 + lane*2 + 1];
  float t0 = attc[lane*2], t1 = attc[lane*2 + 1];
  float e0=0, e1=0, p0=0, p1=0;
  for (int i = o0 + wv; i < o1; i += 4){
    const float* xp = X + (size_t)fperm[i]*128 + lane*2;
    float vx = xp[0], vy = xp[1];
    union { double d; float2 f2; } u;
    u.f2.x = vx*c0 + vy*c1;
    u.f2.y = vx*t0 + vy*t1;
    #pragma unroll
    for (int m2=1; m2<64; m2<<=1){
      union { double d; float2 f2; } v;
      v.d = __shfl_xor(u.d, m2, 64);
      u.f2.x += v.f2.x; u.f2.y += v.f2.y;
    }
    float s1 = sigf(u.f2.x), s2 = sigf(u.f2.y);
    e0 += vx*s1; e1 += vy*s1;
    p0 += vx*s2; p1 += vy*s2;
  }
  rede[wv][lane*2] = e0; rede[wv][lane*2+1] = e1;
  redp[wv][lane*2] = p0; redp[wv][lane*2+1] = p1;
  __syncthreads();
  if (t < 128){
    femb[(size_t)f*128 + t] = rede[0][t] + rede[1][t] + rede[2][t] + rede[3][t];
    float pp = redp[0][t] + redp[1][t] + redp[2][t] + redp[3][t];
    atomAddF(&pooled[t], pp);
  }
}

// ---------------- attention-pool context (parallel colsum) ----------------
__global__ __launch_bounds__(1024) void attc2_k(const float* __restrict__ fsum, float Ninv,
                                                const float* __restrict__ Watt,
                                                float* __restrict__ attc)
{
  __shared__ float part[8][128];
  __shared__ float mean[128];
  int t = threadIdx.x;
  int j = t & 127, ch = t >> 7;
  float a = 0;
  for (int f = ch; f < FFUNC; f += 8) a += fsum[(size_t)f*128 + j];
  part[ch][j] = a;
  __syncthreads();
  if (t < 128){
    float m = 0;
    #pragma unroll
    for (int c=0;c<8;c++) m += part[c][t];
    mean[t] = m * Ninv;
  }
  __syncthreads();
  if (t < 128){
    float c = 0;
    for (int k=0;k<128;k++) c += mean[k]*Watt[(size_t)k*128 + t];
    attc[t] = tanhf(c);
  }
}

__global__ void rowmean_k(float* __restrict__ fsum, const float* __restrict__ fcnt){
  int idx = blockIdx.x*256 + threadIdx.x;
  if (idx < FFUNC*128) fsum[idx] /= fmaxf(fcnt[idx>>7], 1.0f);
}

// ---------------- histogram: sc = f1@f2^T, track min/max ----------------
__global__ __launch_bounds__(256) void gemmnt_k(const float* __restrict__ fa,
                                                const float* __restrict__ fb,
                                                float* __restrict__ sc,
                                                unsigned* __restrict__ mmk)
{
  int t = threadIdx.x;
  int tx = t & 15, ty = t >> 4;
  int i = blockIdx.y*16 + ty, j = blockIdx.x*16 + tx;
  float mn = INFINITY, mx = -INFINITY;
  if (i < FFUNC && j < FFUNC){
    float a = 0;
    for (int k=0;k<128;k+=4){
      float4 A = *(const float4*)(fa + (size_t)i*128 + k);
      float4 B = *(const float4*)(fb + (size_t)j*128 + k);
      a += A.x*B.x + A.y*B.y + A.z*B.z + A.w*B.w;
    }
    sc[(size_t)i*FFUNC + j] = a;
    mn = a; mx = a;
  }
  __shared__ float smn[256], smx[256];
  smn[t]=mn; smx[t]=mx; __syncthreads();
  for (int o=128;o>0;o>>=1){
    if (t<o){ smn[t]=fminf(smn[t],smn[t+o]); smx[t]=fmaxf(smx[t],smx[t+o]); }
    __syncthreads();
  }
  if (t==0){ atomicMin(&mmk[0], fkey(smn[0])); atomicMax(&mmk[1], fkey(smx[0])); }
}

__global__ void hist_init_k(unsigned* mmk, unsigned* hist){
  int t = threadIdx.x;
  if (t==0){ mmk[0]=0xFFFFFFFFu; mmk[1]=0u; }
  if (t<16) hist[t]=0u;
}

__global__ void hist_k(const float* __restrict__ sc, const unsigned* __restrict__ mmk,
                       unsigned* __restrict__ hist)
{
  __shared__ unsigned hl[16];
  int t = threadIdx.x;
  if (t < 16) hl[t] = 0;
  __syncthreads();
  float mn = funkey(mmk[0]), mx = funkey(mmk[1]);
  float rng = fmaxf(mx - mn, 1e-12f);
  const long total = (long)FFUNC*FFUNC;
  for (long idx = (long)blockIdx.x*256 + t; idx < total; idx += (long)gridDim.x*256){
    float v = sc[idx];
    int b = (int)floorf((v - mn)/rng * 16.0f);
    b = min(max(b,0),15);
    atomicAdd(&hl[b], 1u);
  }
  __syncthreads();
  if (t < 16) atomicAdd(&hist[t], hl[t]);
}

// ---------------- final head ----------------
__global__ __launch_bounds__(256) void final_k(
    const float* __restrict__ p1, const float* __restrict__ p2,
    const float* __restrict__ Wtn, const float* __restrict__ Vtn,
    const float* __restrict__ btn, const unsigned* __restrict__ hist,
    const float* __restrict__ Wfc1, const float* __restrict__ bfc1,
    const float* __restrict__ Wsc, const float* __restrict__ bsc,
    float* __restrict__ outp)
{
  __shared__ float P1[128], P2[128], part[256], feats[32], hv[16];
  int t = threadIdx.x;
  if (t < 128){ P1[t] = p1[t]; P2[t] = p2[t]; }
  __syncthreads();
  int k = t & 15, pr_ = t >> 4;
  float acc = 0;
  for (int i = pr_*8; i < pr_*8+8; ++i){
    float pi = P1[i];
    const float* wrow = Wtn + ((size_t)i*128)*16 + k;
    float a2 = 0;
    for (int j=0;j<128;++j) a2 += P2[j]*wrow[(size_t)j*16];
    acc += pi*a2;
  }
  part[t] = acc;
  __syncthreads();
  if (t < 16){
    float sc_ = 0;
    for (int p=0;p<16;p++) sc_ += part[p*16 + t];
    float bl = btn[t];
    for (int j=0;j<256;j++) bl += Vtn[(size_t)t*256 + j] * (j<128 ? P1[j] : P2[j-128]);
    float tv = sc_ + bl;
    feats[t] = tv > 0.f ? tv : 0.f;
    feats[16+t] = (float)hist[t] * (1.0f/((float)FFUNC*(float)FFUNC));
  }
  __syncthreads();
  if (t < 16){
    float a2 = bfc1[t];
    for (int q2=0;q2<32;q2++) a2 += feats[q2]*Wfc1[q2*16 + t];
    hv[t] = a2 > 0.f ? a2 : 0.f;
  }
  __syncthreads();
  if (t == 0){
    float z = bsc[0];
    for (int m=0;m<16;m++) z += hv[m]*Wsc[m];
    outp[0] = sigf(z);
  }
}

// ---------------- host ----------------
extern "C" void kernel_launch(void* const* d_in, const int* in_sizes, int n_in,
                              void* d_out, int out_size, void* d_ws, size_t ws_size,
                              hipStream_t stream)
{
  (void)n_in; (void)out_size; (void)ws_size;
  const float* Wk = (const float*)d_in[16];
  const float* bk = (const float*)d_in[17];
  const float* Wq = (const float*)d_in[18];
  const float* bq = (const float*)d_in[19];
  const float* Wv = (const float*)d_in[20];
  const float* bv = (const float*)d_in[21];
  const float* Wa = (const float*)d_in[22];
  const float* ba = (const float*)d_in[23];
  const float* SKp = (const float*)d_in[24];
  const float* AR = (const float*)d_in[25];
  const float* MRm = (const float*)d_in[26];
  const float* PRp = (const float*)d_in[27];
  const float* WATT = (const float*)d_in[28];
  const float* WTN = (const float*)d_in[29];
  const float* VTN = (const float*)d_in[30];
  const float* BTN = (const float*)d_in[31];
  const float* WFC1 = (const float*)d_in[32];
  const float* BFC1 = (const float*)d_in[33];
  const float* WSC = (const float*)d_in[34];
  const float* BSC = (const float*)d_in[35];

  int NdA[2] = { in_sizes[0]/128, in_sizes[8]/128 };
  int NiA[2] = { in_sizes[1]/128, in_sizes[9]/128 };
  int EA[2][4];
  for (int g=0; g<2; g++)
    for (int r=0; r<4; r++) EA[g][r] = in_sizes[g*8+2+r]/2;

  int NdM = NdA[0] > NdA[1] ? NdA[0] : NdA[1];
  int NiM = NiA[0] > NiA[1] ? NiA[0] : NiA[1];
  long EtotM = 0;
  for (int g=0; g<2; g++){
    long et = 0; for (int r=0;r<4;r++) et += EA[g][r];
    if (et > EtotM) EtotM = et;
  }
  int NO = ((NiM + 2 + 63)/64)*64;

  char* wp = (char*)d_ws;
  auto alloc = [&](size_t bytes)->void*{
    void* p = (void*)wp;
    wp += (bytes + 255) & ~(size_t)255;
    return p;
  };
  size_t nrows = (size_t)NdM + (size_t)NiM;
  float*          X    = (float*)alloc(nrows*128*4);
  float*          AGG  = (float*)alloc(nrows*128*4);   // AGG/NMAX/DEN contiguous
  unsigned*       NMAX = (unsigned*)alloc(nrows*4*4);
  float*          DEN  = (float*)alloc(nrows*4*4);
  float*          O1b  = (float*)alloc(nrows*128*4);
  unsigned short* Kb   = (unsigned short*)alloc(nrows*128*2);
  unsigned short* Qb   = (unsigned short*)alloc(nrows*128*2);
  unsigned short* Vb   = (unsigned short*)alloc(nrows*128*2);
  unsigned short* KR   = (unsigned short*)alloc((size_t)NiM*128*2);
  float*          LOGb = (float*)alloc((size_t)EtotM*4*4);
  int*            OFFS = (int*)alloc((size_t)8*NO*4);
  int*            PERM = (int*)alloc((size_t)2*EtotM*4);
  int*            FOFFS= (int*)alloc((size_t)1024*4);
  int*            FCURS= (int*)alloc((size_t)1024*4);
  int*            FPERM= (int*)alloc(nrows*4);
  float*          GS[2];
  GS[0] = (float*)alloc((size_t)385280*4);
  GS[1] = (float*)alloc((size_t)385280*4);
  unsigned*       MM   = (unsigned*)alloc(2*4);
  unsigned*       HIST = (unsigned*)alloc(16*4);
  unsigned short* WKP  = (unsigned short*)alloc((size_t)8*16384*2);
  unsigned short* WQP  = (unsigned short*)alloc((size_t)8*16384*2);
  unsigned short* WVP  = (unsigned short*)alloc((size_t)8*16384*2);
  unsigned short* WAP  = (unsigned short*)alloc((size_t)8*16384*2);
  unsigned short* WATTP= (unsigned short*)alloc((size_t)16384*2);
  unsigned short* ARP  = (unsigned short*)alloc((size_t)16*4096*2);
  unsigned short* MRP  = (unsigned short*)alloc((size_t)16*4096*2);
  size_t uni_bytes = (size_t)FFUNC*FFUNC*4;
  size_t curs_bytes = (size_t)8*NO*4;
  void* UNI = alloc(uni_bytes > curs_bytes ? uni_bytes : curs_bytes);
  int*   CURS = (int*)UNI;
  float* SCb  = (float*)UNI;

  packw_k<<<8,256,0,stream>>>(Wk, WKP);
  packw_k<<<8,256,0,stream>>>(Wq, WQP);
  packw_k<<<8,256,0,stream>>>(Wv, WVP);
  packw_k<<<8,256,0,stream>>>(Wa, WAP);
  packw_k<<<1,256,0,stream>>>(WATT, WATTP);
  packa_k<<<16,256,0,stream>>>(AR, ARP);
  packa_k<<<16,256,0,stream>>>(MRm, MRP);

  const size_t OF_FSUM=0, OF_FCNT=128000, OF_CF=129024, OF_ATTC=257024, OF_FEMB=257152, OF_POOL=385152;
  const int stf[4] = {1,0,1,1};
  const int dtf[4] = {1,1,0,1};

  for (int g=0; g<2; ++g){
    int nd = NdA[g], ni = NiA[g];
    int E[4] = {EA[g][0],EA[g][1],EA[g][2],EA[g][3]};
    int eoff[4]; eoff[0]=0;
    for (int r=1;r<4;r++) eoff[r] = eoff[r-1] + E[r-1];
    const int* ei[4] = {(const int*)d_in[g*8+2], (const int*)d_in[g*8+3],
                        (const int*)d_in[g*8+4], (const int*)d_in[g*8+5]};
    const int* fdp = (const int*)d_in[g*8+6];
    const int* fip = (const int*)d_in[g*8+7];
    const float* x0d = (const float*)d_in[g*8+0];
    const float* x0i = (const float*)d_in[g*8+1];
    int gbd = (nd+63)/64, gbi = (ni+63)/64;
    int nt = nd + ni;
    int ntb = (nt+255)/256; if (ntb > 2048) ntb = 2048;

    // ---- build 8 edge CSRs + function CSR ----
    hipMemsetAsync(OFFS, 0, (size_t)8*NO*4, stream);
    hipMemsetAsync(FOFFS, 0, 1024*4, stream);
    ScanDesc sd;
    for (int c2=0; c2<2; c2++)
      for (int r=0; r<4; r++){
        int ent = c2*4 + r;
        const int* dptr = (c2==0) ? ei[r]+E[r] : ei[r];
        int nds = ((c2==0) ? dtf[r] : stf[r]) ? ni : nd;
        sd.n[ent] = nds;
        int blks = (E[r]+255)/256; if (blks > 1024) blks = 1024;
        csr_hist_k<<<blks,256,0,stream>>>(dptr, E[r], OFFS + (size_t)ent*NO);
      }
    fhist_k<<<ntb,256,0,stream>>>(fdp, fip, nd, ni, FOFFS);
    csr_scan_k<<<8,1024,0,stream>>>(sd, OFFS, CURS, NO);
    ScanDesc fsd; fsd.n[0] = FFUNC;
    csr_scan_k<<<1,1024,0,stream>>>(fsd, FOFFS, FCURS, 1024);
    for (int c2=0; c2<2; c2++)
      for (int r=0; r<4; r++){
        int ent = c2*4 + r;
        const int* dptr = (c2==0) ? ei[r]+E[r] : ei[r];
        const int* sptr = (c2==0) ? ei[r] : ei[r]+E[r];
        int blks = (E[r]+255)/256; if (blks > 1024) blks = 1024;
        csr_fill_k<<<blks,256,0,stream>>>(dptr, sptr, E[r], CURS + (size_t)ent*NO,
                                          PERM + (size_t)c2*EtotM + eoff[r]);
      }
    ffill_k<<<ntb,256,0,stream>>>(fdp, fip, nd, ni, FCURS, FPERM);

    for (int l=0; l<2; ++l){
      const float* xd = (l==0) ? x0d : X;
      const float* xi = (l==0) ? x0i : X + (size_t)nd*128;
      for (int c=0; c<2; ++c){
        int pc = l*2 + c;
        hipMemsetAsync(AGG, 0, nrows*128*4 + nrows*4*4*2, stream);
        gemm_kqv_k<<<gbd+gbi,256,0,stream>>>(
            xd, xi, nd, ni, gbd,
            WKP+(size_t)pc*2*16384, WQP+(size_t)pc*2*16384, WVP+(size_t)pc*2*16384,
            bk+(size_t)pc*2*128, bq+(size_t)pc*2*128, bv+(size_t)pc*2*128,
            Kb, Qb, Vb);
        for (int r=0; r<4; r++){
          int st = (c==0) ? stf[r] : dtf[r];
          int dt = (c==0) ? dtf[r] : stf[r];
          int Ns = st ? ni : nd;
          int Ndst = dt ? ni : nd;
          int ent = c*4 + r;
          xformb_k<<<(Ns+63)/64,256,0,stream>>>(Kb + (st?(size_t)nd*128:0), Ns,
                                                ARP + (size_t)(pc*4+r)*4096, KR);
          e1_csr_k<<<((size_t)Ndst*32+255)/256,256,0,stream>>>(
              KR, Qb + (dt?(size_t)nd*128:0),
              OFFS + (size_t)ent*NO, PERM + (size_t)c*EtotM + eoff[r], Ndst,
              PRp + (size_t)(pc*4+r)*4,
              LOGb + (size_t)eoff[r]*4,
              NMAX + (dt?(size_t)nd*4:0));
        }
        for (int r=0; r<4; r++){
          int st = (c==0) ? stf[r] : dtf[r];
          int dt = (c==0) ? dtf[r] : stf[r];
          int Ns = st ? ni : nd;
          int Ndst = dt ? ni : nd;
          int ent = c*4 + r;
          xformb_k<<<(Ns+63)/64,256,0,stream>>>(Vb + (st?(size_t)nd*128:0), Ns,
                                                MRP + (size_t)(pc*4+r)*4096, KR);
          e2n_k<<<((size_t)Ndst*32+255)/256,256,0,stream>>>(
              KR, LOGb + (size_t)eoff[r]*4,
              NMAX + (dt?(size_t)nd*4:0),
              OFFS + (size_t)ent*NO, PERM + (size_t)c*EtotM + eoff[r], Ndst,
              AGG + (dt?(size_t)nd*128:0), DEN + (dt?(size_t)nd*4:0));
        }
        gemm_epi_k<<<gbd+gbi,256,0,stream>>>(
            AGG, DEN, nd, ni, gbd,
            WAP+(size_t)pc*2*16384, ba+(size_t)pc*2*128,
            xd, xi,
            (c==1) ? O1b : nullptr,
            (c==0) ? O1b : X,
            SKp + (size_t)pc*2, (c==0) ? 2 : 3);
      }
    }
    // pooling for this graph (function-CSR, atomic-free)
    float* fsum = GS[g]+OF_FSUM;  float* fcnt = GS[g]+OF_FCNT;
    float* cf   = GS[g]+OF_CF;    float* attc = GS[g]+OF_ATTC;
    float* femb = GS[g]+OF_FEMB;  float* pool = GS[g]+OF_POOL;
    hipMemsetAsync(GS[g], 0, (size_t)385280*4, stream);
    f1c_k<<<FFUNC,256,0,stream>>>(X, FOFFS, FPERM, fsum, fcnt);
    attc2_k<<<1,1024,0,stream>>>(fsum, 1.0f/(float)nt, WATT, attc);
    rowmean_k<<<(FFUNC*128+255)/256,256,0,stream>>>(fsum, fcnt);
    gemmb_k<<<(FFUNC+63)/64,256,0,stream>>>(fsum, FFUNC, WATTP, nullptr, cf, nullptr, 1,0,nullptr,nullptr,nullptr);
    f23c_k<<<FFUNC,256,0,stream>>>(X, FOFFS, FPERM, cf, attc, femb, pool);
  }
  // similarity histogram + final head
  hist_init_k<<<1,32,0,stream>>>(MM, HIST);
  dim3 gnt((FFUNC+15)/16, (FFUNC+15)/16);
  gemmnt_k<<<gnt,256,0,stream>>>(GS[0]+OF_FEMB, GS[1]+OF_FEMB, SCb, MM);
  hist_k<<<512,256,0,stream>>>(SCb, MM, HIST);
  final_k<<<1,256,0,stream>>>(GS[0]+OF_POOL, GS[1]+OF_POOL, WTN, VTN, BTN, HIST,
                              WFC1, BFC1, WSC, BSC, (float*)d_out);
}

// Round 7
// 2887.509 us; speedup vs baseline: 3.3494x; 1.2195x over previous
//
#include <hip/hip_runtime.h>
#include <math.h>

#define FFUNC 1000

typedef __attribute__((ext_vector_type(8))) short s8v;
typedef __attribute__((ext_vector_type(4))) float f4v;

// ---------------- device helpers ----------------
__device__ __forceinline__ float sigf(float x){ return 1.0f/(1.0f+expf(-x)); }
__device__ __forceinline__ float geluf(float x){
  return 0.5f*x*(1.0f + tanhf(0.7978845608028654f*(x + 0.044715f*x*x*x)));
}
__device__ __forceinline__ unsigned fkey(float f){
  unsigned u = __float_as_uint(f);
  return (u & 0x80000000u) ? ~u : (u | 0x80000000u);
}
__device__ __forceinline__ float funkey(unsigned k){
  unsigned u = (k & 0x80000000u) ? (k ^ 0x80000000u) : ~k;
  return __uint_as_float(u);
}
__device__ __forceinline__ void atomAddF(float* p, float v){ unsafeAtomicAdd(p, v); }
__device__ __forceinline__ unsigned short bfr(float x){   // f32 -> bf16 RNE
  unsigned u = __float_as_uint(x);
  unsigned r = (u + 0x7FFFu + ((u >> 16) & 1u)) >> 16;
  return (unsigned short)r;
}
__device__ __forceinline__ float b2f(unsigned short v){
  return __uint_as_float((unsigned)v << 16);
}

// ---------------- weight prepack ----------------
__global__ void packw_k(const float* __restrict__ W, unsigned short* __restrict__ out){
  int mat = blockIdx.x;
  const float* w = W + (size_t)mat*16384;
  unsigned short* o = out + (size_t)mat*16384;
  for (int u=0; u<64; u++){
    int oi = u*256 + threadIdx.x;
    int j = oi & 7, l = (oi>>3) & 63, nt = (oi>>9) & 7, kt = oi >> 12;
    float v = w[(size_t)(kt*32 + 8*(l>>4) + j)*128 + nt*16 + (l&15)];
    o[oi] = bfr(v);
  }
}

__global__ void packa_k(const float* __restrict__ A, unsigned short* __restrict__ out){
  int ent = blockIdx.x;
  const float* a = A + (size_t)ent*4096;
  unsigned short* o = out + (size_t)ent*4096;
  for (int u=0; u<16; u++){
    int oi = u*256 + threadIdx.x;
    int j = oi & 7, l = (oi>>3) & 63, nt = (oi>>9) & 1, h = oi >> 10;
    float v = a[(size_t)h*1024 + (size_t)(8*(l>>4)+j)*32 + nt*16 + (l&15)];
    o[oi] = bfr(v);
  }
}

// ---------------- fused K/Q/V projection, both node types, f32-or-bf16 A ----------------
__global__ __launch_bounds__(256) void gemm_kqv_k(
    const void* __restrict__ xdv, const void* __restrict__ xiv, int af32,
    int nd, int ni, int gbd,
    const unsigned short* __restrict__ WK, const unsigned short* __restrict__ WQ,
    const unsigned short* __restrict__ WV,
    const float* __restrict__ bK, const float* __restrict__ bQ, const float* __restrict__ bV,
    unsigned short* __restrict__ Kb, unsigned short* __restrict__ Qb,
    unsigned short* __restrict__ Vb)
{
  int blk = blockIdx.x;
  int ty = (blk >= gbd);
  int N = ty ? ni : nd;
  int rbase = (ty ? (blk - gbd) : blk) * 64;
  size_t obase = ty ? (size_t)nd*128 : 0;
  const unsigned short* wk = WK + (ty ? 16384 : 0);
  const unsigned short* wq = WQ + (ty ? 16384 : 0);
  const unsigned short* wv = WV + (ty ? 16384 : 0);
  const float* bk2 = bK + (ty ? 128 : 0);
  const float* bq2 = bQ + (ty ? 128 : 0);
  const float* bv2 = bV + (ty ? 128 : 0);
  const float* Af = (const float*)(ty ? xiv : xdv);
  const unsigned short* Ab = (const unsigned short*)(ty ? xiv : xdv);

  int t = threadIdx.x;
  int l = t & 63, w = t >> 6, b = l >> 4, m = l & 15;
  int arow = rbase + w*16 + m;
  bool rv = arow < N;
  f4v ak[8], aq[8], av[8];
  #pragma unroll
  for (int nt=0; nt<8; nt++){ ak[nt]=(f4v){0,0,0,0}; aq[nt]=(f4v){0,0,0,0}; av[nt]=(f4v){0,0,0,0}; }

  #pragma unroll
  for (int kt=0; kt<4; kt++){
    s8v af = (s8v){0,0,0,0,0,0,0,0};
    if (rv){
      if (af32){
        const float* ap = Af + (size_t)arow*128 + kt*32 + b*8;
        float4 x0 = *(const float4*)ap;
        float4 x1 = *(const float4*)(ap + 4);
        af[0]=(short)bfr(x0.x); af[1]=(short)bfr(x0.y); af[2]=(short)bfr(x0.z); af[3]=(short)bfr(x0.w);
        af[4]=(short)bfr(x1.x); af[5]=(short)bfr(x1.y); af[6]=(short)bfr(x1.z); af[7]=(short)bfr(x1.w);
      } else {
        af = *(const s8v*)(Ab + (size_t)arow*128 + kt*32 + b*8);
      }
    }
    #pragma unroll
    for (int nt=0; nt<8; nt++){
      int fo = ((kt*8 + nt)*64 + l)*8;
      s8v bk_ = *(const s8v*)(wk + fo);
      s8v bq_ = *(const s8v*)(wq + fo);
      s8v bv_ = *(const s8v*)(wv + fo);
      ak[nt] = __builtin_amdgcn_mfma_f32_16x16x32_bf16(af, bk_, ak[nt], 0, 0, 0);
      aq[nt] = __builtin_amdgcn_mfma_f32_16x16x32_bf16(af, bq_, aq[nt], 0, 0, 0);
      av[nt] = __builtin_amdgcn_mfma_f32_16x16x32_bf16(af, bv_, av[nt], 0, 0, 0);
    }
  }
  float bkr[8], bqr[8], bvr[8];
  #pragma unroll
  for (int nt=0; nt<8; nt++){ int col=nt*16+m; bkr[nt]=bk2[col]; bqr[nt]=bq2[col]; bvr[nt]=bv2[col]; }
  #pragma unroll
  for (int r2=0; r2<4; r2++){
    int orow = rbase + w*16 + 4*b + r2;
    if (orow >= N) continue;
    size_t ob = obase + (size_t)orow*128 + m;
    #pragma unroll
    for (int nt=0; nt<8; nt++){
      Kb[ob + nt*16] = bfr(ak[nt][r2] + bkr[nt]);
      Qb[ob + nt*16] = bfr(aq[nt][r2] + bqr[nt]);
      Vb[ob + nt*16] = bfr(av[nt][r2] + bvr[nt]);
    }
  }
}

// ---------------- fused epilogue GEMM; bf16 outputs ----------------
__global__ __launch_bounds__(256) void gemm_epi_k(
    const float* __restrict__ AGG, const float* __restrict__ DENb,
    int nd, int ni, int gbd,
    const unsigned short* __restrict__ WA, const float* __restrict__ bA,
    const void* __restrict__ xin_dv, const void* __restrict__ xin_iv, int xf32,
    const unsigned short* __restrict__ o1p, unsigned short* __restrict__ out,
    const float* __restrict__ skp, int mode)
{
  int blk = blockIdx.x;
  int ty = (blk >= gbd);
  int N = ty ? ni : nd;
  int rbase = (ty ? (blk - gbd) : blk) * 64;
  int goff = ty ? nd : 0;
  const unsigned short* wa = WA + (ty ? 16384 : 0);
  const float* ba2 = bA + (ty ? 128 : 0);
  const float* xinF = (const float*)(ty ? xin_iv : xin_dv);
  const unsigned short* xinB = (const unsigned short*)(ty ? xin_iv : xin_dv);
  float s = sigf(skp[ty]), s1 = 1.0f - s;

  int t = threadIdx.x;
  int l = t & 63, w = t >> 6, b = l >> 4, m = l & 15;
  int arow = rbase + w*16 + m;
  bool rv = arow < N;
  f4v acc[8];
  #pragma unroll
  for (int nt=0; nt<8; nt++) acc[nt] = (f4v){0,0,0,0};

  #pragma unroll
  for (int kt=0; kt<4; kt++){
    s8v af = (s8v){0,0,0,0,0,0,0,0};
    if (rv){
      size_t grow = (size_t)(goff + arow);
      float dv = 1.0f / fmaxf(DENb[grow*4 + kt], 1e-16f);
      const float* ap = AGG + grow*128 + kt*32 + b*8;
      float4 x0 = *(const float4*)ap;
      float4 x1 = *(const float4*)(ap + 4);
      x0.x=geluf(x0.x*dv); x0.y=geluf(x0.y*dv); x0.z=geluf(x0.z*dv); x0.w=geluf(x0.w*dv);
      x1.x=geluf(x1.x*dv); x1.y=geluf(x1.y*dv); x1.z=geluf(x1.z*dv); x1.w=geluf(x1.w*dv);
      af[0]=(short)bfr(x0.x); af[1]=(short)bfr(x0.y); af[2]=(short)bfr(x0.z); af[3]=(short)bfr(x0.w);
      af[4]=(short)bfr(x1.x); af[5]=(short)bfr(x1.y); af[6]=(short)bfr(x1.z); af[7]=(short)bfr(x1.w);
    }
    #pragma unroll
    for (int nt=0; nt<8; nt++){
      s8v bf = *(const s8v*)(wa + ((kt*8 + nt)*64 + l)*8);
      acc[nt] = __builtin_amdgcn_mfma_f32_16x16x32_bf16(af, bf, acc[nt], 0, 0, 0);
    }
  }
  #pragma unroll
  for (int r2=0; r2<4; r2++){
    int orow = rbase + w*16 + 4*b + r2;
    if (orow >= N) continue;
    size_t grow = (size_t)(goff + orow);
    #pragma unroll
    for (int nt=0; nt<8; nt++){
      int col = nt*16 + m;
      float v = acc[nt][r2] + ba2[col];
      float xv = xf32 ? xinF[(size_t)orow*128 + col] : b2f(xinB[(size_t)orow*128 + col]);
      v = s*v + s1*xv;
      if (mode == 3){
        float o1 = b2f(o1p[grow*128 + col]);
        v = fmaxf(0.5f*o1 + 0.5f*v, 0.f);
      }
      out[grow*128 + col] = bfr(v);
    }
  }
}

// ---------------- batched per-head transform over 4 relations ----------------
struct XfD {
  int blk0[5];
  int N[4];
  int inoff[4];
  int outoff[4];
  int matoff[4];
};
__global__ __launch_bounds__(256) void xform_all_k(
    const unsigned short* __restrict__ Xb,
    const unsigned short* __restrict__ Apb,
    unsigned short* __restrict__ outb, XfD d)
{
  int bq = blockIdx.x;
  int r = (bq >= d.blk0[1]) + (bq >= d.blk0[2]) + (bq >= d.blk0[3]);
  int lb = bq - d.blk0[r];
  int N = d.N[r];
  const unsigned short* X = Xb + (size_t)d.inoff[r]*128;
  const unsigned short* Ap = Apb + d.matoff[r];
  unsigned short* out = outb + (size_t)d.outoff[r]*128;

  int t = threadIdx.x;
  int l = t & 63, w = t >> 6, b = l >> 4, m = l & 15;
  int arow = lb*64 + w*16 + m;
  bool rv = arow < N;
  f4v acc[8];
  #pragma unroll
  for (int i=0;i<8;i++) acc[i] = (f4v){0,0,0,0};
  #pragma unroll
  for (int h=0; h<4; h++){
    s8v af = (s8v){0,0,0,0,0,0,0,0};
    if (rv) af = *(const s8v*)(X + (size_t)arow*128 + h*32 + b*8);
    #pragma unroll
    for (int nt=0; nt<2; nt++){
      s8v bf = *(const s8v*)(Ap + ((h*2 + nt)*64 + l)*8);
      acc[h*2+nt] = __builtin_amdgcn_mfma_f32_16x16x32_bf16(af, bf, acc[h*2+nt], 0, 0, 0);
    }
  }
  #pragma unroll
  for (int r2=0; r2<4; r2++){
    int orow = lb*64 + w*16 + 4*b + r2;
    if (orow >= N) continue;
    #pragma unroll
    for (int h=0; h<4; h++)
      #pragma unroll
      for (int nt=0; nt<2; nt++)
        out[(size_t)orow*128 + h*32 + nt*16 + m] = bfr(acc[h*2+nt][r2]);
  }
}

// ---------------- CSR build (batched) ----------------
struct ScanDesc { int n[8]; };

struct HD {
  int blk0[9];
  const int* dst[8];
  const int* src[8];
  int E[8];
  int cnto[8];
  int permo[8];
};
__global__ void csr_hist_all_k(HD d, int* __restrict__ cnt){
  int b = blockIdx.x;
  int r = 0;
  while (r < 7 && b >= d.blk0[r+1]) r++;
  int e = (b - d.blk0[r])*256 + threadIdx.x;
  if (e < d.E[r]) atomicAdd(&cnt[d.cnto[r] + d.dst[r][e]], 1);
}
__global__ void csr_fill_all_k(HD d, int* __restrict__ curs, int* __restrict__ perm){
  int b = blockIdx.x;
  int r = 0;
  while (r < 7 && b >= d.blk0[r+1]) r++;
  int e = (b - d.blk0[r])*256 + threadIdx.x;
  if (e < d.E[r]){
    int pos = atomicAdd(&curs[d.cnto[r] + d.dst[r][e]], 1);
    perm[d.permo[r] + pos] = d.src[r][e];
  }
}

// wave-level scan: 3 barriers per 1024-chunk
__global__ __launch_bounds__(1024) void csr_scan_k(ScanDesc sd, int* __restrict__ offs,
                                                   int* __restrict__ curs, int NO){
  int ent = blockIdx.x;
  int n = sd.n[ent];
  int* o  = offs + (size_t)ent*NO;
  int* cu = curs + (size_t)ent*NO;
  __shared__ int wsum[16];
  __shared__ int woff[17];
  int tid = threadIdx.x, lane = tid & 63, wv = tid >> 6;
  int run = 0;
  for (int base=0; base<n; base+=1024){
    int i = base + tid;
    int v = (i<n) ? o[i] : 0;
    int s = v;
    #pragma unroll
    for (int d2=1; d2<64; d2<<=1){
      int t2 = __shfl_up(s, d2, 64);
      if (lane >= d2) s += t2;
    }
    if (lane == 63) wsum[wv] = s;
    __syncthreads();
    if (wv == 0 && lane < 16){
      int x = wsum[lane];
      #pragma unroll
      for (int d2=1; d2<16; d2<<=1){
        int t2 = __shfl_up(x, d2, 64);
        if (lane >= d2) x += t2;
      }
      woff[lane+1] = x;
      if (lane == 0) woff[0] = 0;
    }
    __syncthreads();
    int excl = run + woff[wv] + s - v;
    if (i < n){ o[i] = excl; cu[i] = excl; }
    run += woff[16];
    __syncthreads();
  }
  if (tid == 0) o[n] = run;
}

// ---------------- function-CSR build ----------------
__global__ void fhist_k(const int* __restrict__ fd, const int* __restrict__ fi,
                        int Nd, int Ni, int* __restrict__ cnt){
  int nt = Nd + Ni;
  for (int n = blockIdx.x*256 + threadIdx.x; n < nt; n += gridDim.x*256){
    int f = (n < Nd) ? fd[n] : fi[n-Nd];
    atomicAdd(&cnt[f], 1);
  }
}
__global__ void ffill_k(const int* __restrict__ fd, const int* __restrict__ fi,
                        int Nd, int Ni, int* __restrict__ curs, int* __restrict__ perm){
  int nt = Nd + Ni;
  for (int n = blockIdx.x*256 + threadIdx.x; n < nt; n += gridDim.x*256){
    int f = (n < Nd) ? fd[n] : fi[n-Nd];
    int pos = atomicAdd(&curs[f], 1);
    perm[pos] = n;
  }
}

// ---------------- E1 batched over 4 relations ----------------
struct E1D {
  int blk0[5];
  int ndst[4];
  int offso[4];
  int permo[4];
  int kro[4];
  int qo[4];
  int nmo[4];
  int logo[4];
  int pro[4];
};
__global__ __launch_bounds__(256) void e1_all_k(
    const unsigned short* __restrict__ KR4, const unsigned short* __restrict__ Qb,
    const int* __restrict__ OFFS, const int* __restrict__ PERM,
    const float* __restrict__ PRp, float* __restrict__ LOGb,
    unsigned* __restrict__ NMAX, E1D dd)
{
  int bq = blockIdx.x;
  int r = (bq >= dd.blk0[1]) + (bq >= dd.blk0[2]) + (bq >= dd.blk0[3]);
  int gidx = (bq - dd.blk0[r])*256 + threadIdx.x;
  int d = gidx >> 5; if (d >= dd.ndst[r]) return;
  int sub = gidx & 31, h = sub >> 3, j = sub & 7;
  const int* offs = OFFS + dd.offso[r];
  int o0 = offs[d], o1 = offs[d+1];
  if (o0 == o1) return;
  const int* psrc = PERM + dd.permo[r];
  const unsigned short* kr = KR4 + (size_t)dd.kro[r]*128;
  const unsigned short* q  = Qb  + (size_t)dd.qo[r]*128;
  float* lg = LOGb + dd.logo[r];
  unsigned* nm = NMAX + dd.nmo[r];
  ushort4 qa = *(const ushort4*)(q + (size_t)d*128 + h*32 + j*4);
  float q0=b2f(qa.x), q1=b2f(qa.y), q2=b2f(qa.z), q3=b2f(qa.w);
  float scale = PRp[dd.pro[r] + h] * 0.17677669529663687f;  // 1/sqrt(32)
  float mx = -INFINITY;
  for (int i=o0; i<o1; ++i){
    int s = psrc[i];
    ushort4 aa = *(const ushort4*)(kr + (size_t)s*128 + h*32 + j*4);
    float p = b2f(aa.x)*q0 + b2f(aa.y)*q1 + b2f(aa.z)*q2 + b2f(aa.w)*q3;
    p += __shfl_xor(p, 1, 8);
    p += __shfl_xor(p, 2, 8);
    p += __shfl_xor(p, 4, 8);
    float lv = p * scale;
    if (j == 0) lg[(size_t)i*4 + h] = lv;
    mx = fmaxf(mx, lv);
  }
  if (j == 0) atomicMax(&nm[(size_t)d*4 + h], fkey(mx));
}

// ---------------- E2 batched over 4 relations ----------------
struct E2D {
  int blk0[5];
  int ndst[4];
  int offso[4];
  int permo[4];
  int vro[4];
  int nmo[4];
  int logo[4];
  int aggo[4];
  int deno[4];
};
__global__ __launch_bounds__(256) void e2_all_k(
    const unsigned short* __restrict__ KR4, const float* __restrict__ LOGb,
    const unsigned* __restrict__ NMAX, const int* __restrict__ OFFS,
    const int* __restrict__ PERM, float* __restrict__ AGG, float* __restrict__ DEN, E2D dd)
{
  int bq = blockIdx.x;
  int r = (bq >= dd.blk0[1]) + (bq >= dd.blk0[2]) + (bq >= dd.blk0[3]);
  int gidx = (bq - dd.blk0[r])*256 + threadIdx.x;
  int d = gidx >> 5; if (d >= dd.ndst[r]) return;
  int sub = gidx & 31, h = sub >> 3, j = sub & 7;
  const int* offs = OFFS + dd.offso[r];
  int o0 = offs[d], o1 = offs[d+1];
  if (o0 == o1) return;
  const int* psrc = PERM + dd.permo[r];
  const unsigned short* vr = KR4 + (size_t)dd.vro[r]*128;
  const float* lg = LOGb + dd.logo[r];
  float mx = funkey(NMAX[dd.nmo[r] + (size_t)d*4 + h]);
  float4 acc = make_float4(0.f,0.f,0.f,0.f);
  float ds = 0.f;
  for (int i=o0; i<o1; ++i){
    int s = psrc[i];
    float ev = __expf(lg[(size_t)i*4 + h] - mx);
    ushort4 v = *(const ushort4*)(vr + (size_t)s*128 + h*32 + j*4);
    acc.x += ev*b2f(v.x); acc.y += ev*b2f(v.y); acc.z += ev*b2f(v.z); acc.w += ev*b2f(v.w);
    ds += ev;
  }
  float* ap = AGG + dd.aggo[r] + (size_t)d*128 + h*32 + j*4;
  float4 old = *(const float4*)ap;
  old.x += acc.x; old.y += acc.y; old.z += acc.z; old.w += acc.w;
  *(float4*)ap = old;
  if (j == 0) DEN[dd.deno[r] + (size_t)d*4 + h] += ds;
}

// ---------------- plain MFMA GEMM (cf only; optional per-row divide) ----------------
__global__ __launch_bounds__(256) void gemmb_k(
    const float* __restrict__ A, int N,
    const unsigned short* __restrict__ Wp, const float* __restrict__ bias,
    float* __restrict__ outf, int mode, const float* __restrict__ rdiv)
{
  int t = threadIdx.x;
  int l = t & 63, w = t >> 6, b = l >> 4, m = l & 15;
  int arow = blockIdx.x*64 + w*16 + m;
  bool rv = arow < N;
  float dv = 1.0f;
  if (rv && rdiv) dv = 1.0f / fmaxf(rdiv[arow], 1.0f);
  f4v acc[8];
  #pragma unroll
  for (int nt=0; nt<8; nt++) acc[nt] = (f4v){0,0,0,0};
  #pragma unroll
  for (int kt=0; kt<4; kt++){
    s8v af = (s8v){0,0,0,0,0,0,0,0};
    if (rv){
      const float* ap = A + (size_t)arow*128 + kt*32 + b*8;
      float4 x0 = *(const float4*)ap;
      float4 x1 = *(const float4*)(ap + 4);
      af[0]=(short)bfr(x0.x*dv); af[1]=(short)bfr(x0.y*dv); af[2]=(short)bfr(x0.z*dv); af[3]=(short)bfr(x0.w*dv);
      af[4]=(short)bfr(x1.x*dv); af[5]=(short)bfr(x1.y*dv); af[6]=(short)bfr(x1.z*dv); af[7]=(short)bfr(x1.w*dv);
    }
    #pragma unroll
    for (int nt=0; nt<8; nt++){
      s8v bf = *(const s8v*)(Wp + ((kt*8 + nt)*64 + l)*8);
      acc[nt] = __builtin_amdgcn_mfma_f32_16x16x32_bf16(af, bf, acc[nt], 0, 0, 0);
    }
  }
  #pragma unroll
  for (int r2=0; r2<4; r2++){
    int orow = blockIdx.x*64 + w*16 + 4*b + r2;
    if (orow >= N) continue;
    #pragma unroll
    for (int nt=0; nt<8; nt++){
      int col = nt*16 + m;
      float v = acc[nt][r2];
      if (bias) v += bias[col];
      if (mode == 1) v = tanhf(v);
      outf[(size_t)orow*128 + col] = v;
    }
  }
}

// ---------------- func pool (CSR, bf16 X): sums + counts ----------------
__global__ __launch_bounds__(256) void f1c_k(const unsigned short* __restrict__ X,
    const int* __restrict__ foffs, const int* __restrict__ fperm,
    float* __restrict__ fsum, float* __restrict__ fcnt)
{
  __shared__ __align__(16) float red[4][128];
  int t = threadIdx.x, wv = t >> 6, lane = t & 63;
  int f = blockIdx.x;
  int o0 = foffs[f], o1 = foffs[f+1];
  float a0 = 0, a1 = 0;
  for (int i = o0 + wv; i < o1; i += 4){
    ushort2 x = *(const ushort2*)(X + (size_t)fperm[i]*128 + lane*2);
    a0 += b2f(x.x); a1 += b2f(x.y);
  }
  red[wv][lane*2] = a0; red[wv][lane*2+1] = a1;
  __syncthreads();
  if (t < 128)
    fsum[(size_t)f*128 + t] = red[0][t] + red[1][t] + red[2][t] + red[3][t];
  if (t == 0) fcnt[f] = (float)(o1 - o0);
}

// ---------------- func pool (CSR, bf16 X): femb + global attention pool ----------------
__global__ __launch_bounds__(256) void f23c_k(const unsigned short* __restrict__ X,
    const int* __restrict__ foffs, const int* __restrict__ fperm,
    const float* __restrict__ cf, const float* __restrict__ attc,
    float* __restrict__ femb, float* __restrict__ pooled)
{
  __shared__ __align__(16) float rede[4][128];
  __shared__ __align__(16) float redp[4][128];
  int t = threadIdx.x, wv = t >> 6, lane = t & 63;
  int f = blockIdx.x;
  int o0 = foffs[f], o1 = foffs[f+1];
  float c0 = cf[(size_t)f*128 + lane*2], c1 = cf[(size_t)f*128 + lane*2 + 1];
  float t0 = attc[lane*2], t1 = attc[lane*2 + 1];
  float e0=0, e1=0, p0=0, p1=0;
  for (int i = o0 + wv; i < o1; i += 4){
    ushort2 xr = *(const ushort2*)(X + (size_t)fperm[i]*128 + lane*2);
    float vx = b2f(xr.x), vy = b2f(xr.y);
    union { double d; float2 f2; } u;
    u.f2.x = vx*c0 + vy*c1;
    u.f2.y = vx*t0 + vy*t1;
    #pragma unroll
    for (int m2=1; m2<64; m2<<=1){
      union { double d; float2 f2; } v;
      v.d = __shfl_xor(u.d, m2, 64);
      u.f2.x += v.f2.x; u.f2.y += v.f2.y;
    }
    float s1 = sigf(u.f2.x), s2 = sigf(u.f2.y);
    e0 += vx*s1; e1 += vy*s1;
    p0 += vx*s2; p1 += vy*s2;
  }
  rede[wv][lane*2] = e0; rede[wv][lane*2+1] = e1;
  redp[wv][lane*2] = p0; redp[wv][lane*2+1] = p1;
  __syncthreads();
  if (t < 128){
    femb[(size_t)f*128 + t] = rede[0][t] + rede[1][t] + rede[2][t] + rede[3][t];
    float pp = redp[0][t] + redp[1][t] + redp[2][t] + redp[3][t];
    atomAddF(&pooled[t], pp);
  }
}

// ---------------- attention-pool context (parallel colsum) ----------------
__global__ __launch_bounds__(1024) void attc2_k(const float* __restrict__ fsum, float Ninv,
                                                const float* __restrict__ Watt,
                                                float* __restrict__ attc)
{
  __shared__ float part[8][128];
  __shared__ float mean[128];
  int t = threadIdx.x;
  int j = t & 127, ch = t >> 7;
  float a = 0;
  for (int f = ch; f < FFUNC; f += 8) a += fsum[(size_t)f*128 + j];
  part[ch][j] = a;
  __syncthreads();
  if (t < 128){
    float m = 0;
    #pragma unroll
    for (int c=0;c<8;c++) m += part[c][t];
    mean[t] = m * Ninv;
  }
  __syncthreads();
  if (t < 128){
    float c = 0;
    for (int k=0;k<128;k++) c += mean[k]*Watt[(size_t)k*128 + t];
    attc[t] = tanhf(c);
  }
}

// ---------------- histogram: sc = f1@f2^T, track min/max ----------------
__global__ __launch_bounds__(256) void gemmnt_k(const float* __restrict__ fa,
                                                const float* __restrict__ fb,
                                                float* __restrict__ sc,
                                                unsigned* __restrict__ mmk)
{
  int t = threadIdx.x;
  int tx = t & 15, ty = t >> 4;
  int i = blockIdx.y*16 + ty, j = blockIdx.x*16 + tx;
  float mn = INFINITY, mx = -INFINITY;
  if (i < FFUNC && j < FFUNC){
    float a = 0;
    for (int k=0;k<128;k+=4){
      float4 A = *(const float4*)(fa + (size_t)i*128 + k);
      float4 B = *(const float4*)(fb + (size_t)j*128 + k);
      a += A.x*B.x + A.y*B.y + A.z*B.z + A.w*B.w;
    }
    sc[(size_t)i*FFUNC + j] = a;
    mn = a; mx = a;
  }
  __shared__ float smn[256], smx[256];
  smn[t]=mn; smx[t]=mx; __syncthreads();
  for (int o=128;o>0;o>>=1){
    if (t<o){ smn[t]=fminf(smn[t],smn[t+o]); smx[t]=fmaxf(smx[t],smx[t+o]); }
    __syncthreads();
  }
  if (t==0){ atomicMin(&mmk[0], fkey(smn[0])); atomicMax(&mmk[1], fkey(smx[0])); }
}

__global__ void hist_init_k(unsigned* mmk, unsigned* hist){
  int t = threadIdx.x;
  if (t==0){ mmk[0]=0xFFFFFFFFu; mmk[1]=0u; }
  if (t<16) hist[t]=0u;
}

__global__ void hist_k(const float* __restrict__ sc, const unsigned* __restrict__ mmk,
                       unsigned* __restrict__ hist)
{
  __shared__ unsigned hl[16];
  int t = threadIdx.x;
  if (t < 16) hl[t] = 0;
  __syncthreads();
  float mn = funkey(mmk[0]), mx = funkey(mmk[1]);
  float rng = fmaxf(mx - mn, 1e-12f);
  const long total = (long)FFUNC*FFUNC;
  for (long idx = (long)blockIdx.x*256 + t; idx < total; idx += (long)gridDim.x*256){
    float v = sc[idx];
    int b = (int)floorf((v - mn)/rng * 16.0f);
    b = min(max(b,0),15);
    atomicAdd(&hl[b], 1u);
  }
  __syncthreads();
  if (t < 16) atomicAdd(&hist[t], hl[t]);
}

// ---------------- final head ----------------
__global__ __launch_bounds__(256) void final_k(
    const float* __restrict__ p1, const float* __restrict__ p2,
    const float* __restrict__ Wtn, const float* __restrict__ Vtn,
    const float* __restrict__ btn, const unsigned* __restrict__ hist,
    const float* __restrict__ Wfc1, const float* __restrict__ bfc1,
    const float* __restrict__ Wsc, const float* __restrict__ bsc,
    float* __restrict__ outp)
{
  __shared__ float P1[128], P2[128], part[256], feats[32], hv[16];
  int t = threadIdx.x;
  if (t < 128){ P1[t] = p1[t]; P2[t] = p2[t]; }
  __syncthreads();
  int k = t & 15, pr_ = t >> 4;
  float acc = 0;
  for (int i = pr_*8; i < pr_*8+8; ++i){
    float pi = P1[i];
    const float* wrow = Wtn + ((size_t)i*128)*16 + k;
    float a2 = 0;
    for (int j=0;j<128;++j) a2 += P2[j]*wrow[(size_t)j*16];
    acc += pi*a2;
  }
  part[t] = acc;
  __syncthreads();
  if (t < 16){
    float sc_ = 0;
    for (int p=0;p<16;p++) sc_ += part[p*16 + t];
    float bl = btn[t];
    for (int j=0;j<256;j++) bl += Vtn[(size_t)t*256 + j] * (j<128 ? P1[j] : P2[j-128]);
    float tv = sc_ + bl;
    feats[t] = tv > 0.f ? tv : 0.f;
    feats[16+t] = (float)hist[t] * (1.0f/((float)FFUNC*(float)FFUNC));
  }
  __syncthreads();
  if (t < 16){
    float a2 = bfc1[t];
    for (int q2=0;q2<32;q2++) a2 += feats[q2]*Wfc1[q2*16 + t];
    hv[t] = a2 > 0.f ? a2 : 0.f;
  }
  __syncthreads();
  if (t == 0){
    float z = bsc[0];
    for (int m=0;m<16;m++) z += hv[m]*Wsc[m];
    outp[0] = sigf(z);
  }
}

// ---------------- host ----------------
extern "C" void kernel_launch(void* const* d_in, const int* in_sizes, int n_in,
                              void* d_out, int out_size, void* d_ws, size_t ws_size,
                              hipStream_t stream)
{
  (void)n_in; (void)out_size; (void)ws_size;
  const float* Wk = (const float*)d_in[16];
  const float* bk = (const float*)d_in[17];
  const float* Wq = (const float*)d_in[18];
  const float* bq = (const float*)d_in[19];
  const float* Wv = (const float*)d_in[20];
  const float* bv = (const float*)d_in[21];
  const float* Wa = (const float*)d_in[22];
  const float* ba = (const float*)d_in[23];
  const float* SKp = (const float*)d_in[24];
  const float* AR = (const float*)d_in[25];
  const float* MRm = (const float*)d_in[26];
  const float* PRp = (const float*)d_in[27];
  const float* WATT = (const float*)d_in[28];
  const float* WTN = (const float*)d_in[29];
  const float* VTN = (const float*)d_in[30];
  const float* BTN = (const float*)d_in[31];
  const float* WFC1 = (const float*)d_in[32];
  const float* BFC1 = (const float*)d_in[33];
  const float* WSC = (const float*)d_in[34];
  const float* BSC = (const float*)d_in[35];

  int NdA[2] = { in_sizes[0]/128, in_sizes[8]/128 };
  int NiA[2] = { in_sizes[1]/128, in_sizes[9]/128 };
  int EA[2][4];
  for (int g=0; g<2; g++)
    for (int r=0; r<4; r++) EA[g][r] = in_sizes[g*8+2+r]/2;

  int NdM = NdA[0] > NdA[1] ? NdA[0] : NdA[1];
  int NiM = NiA[0] > NiA[1] ? NiA[0] : NiA[1];
  long EtotM = 0;
  for (int g=0; g<2; g++){
    long et = 0; for (int r=0;r<4;r++) et += EA[g][r];
    if (et > EtotM) EtotM = et;
  }
  int NO = ((NiM + 2 + 63)/64)*64;
  long KR4rows = 3L*NiM + NdM;

  char* wp = (char*)d_ws;
  auto alloc = [&](size_t bytes)->void*{
    void* p = (void*)wp;
    wp += (bytes + 255) & ~(size_t)255;
    return p;
  };
  size_t nrows = (size_t)NdM + (size_t)NiM;
  // budget ~237 MB (X,O1b bf16; KR4 batched)
  unsigned short* Xb   = (unsigned short*)alloc(nrows*128*2);
  float*          AGG  = (float*)alloc(nrows*128*4);   // AGG/NMAX/DEN contiguous
  unsigned*       NMAX = (unsigned*)alloc(nrows*4*4);
  float*          DEN  = (float*)alloc(nrows*4*4);
  unsigned short* O1b  = (unsigned short*)alloc(nrows*128*2);
  unsigned short* Kb   = (unsigned short*)alloc(nrows*128*2);
  unsigned short* Qb   = (unsigned short*)alloc(nrows*128*2);
  unsigned short* Vb   = (unsigned short*)alloc(nrows*128*2);
  unsigned short* KR4  = (unsigned short*)alloc((size_t)KR4rows*128*2);
  float*          LOGb = (float*)alloc((size_t)EtotM*4*4);
  int*            OFFS = (int*)alloc((size_t)8*NO*4);   // OFFS/FOFFS contiguous (one memset)
  int*            FOFFS= (int*)alloc((size_t)1024*4);
  int*            FCURS= (int*)alloc((size_t)1024*4);
  int*            PERM = (int*)alloc((size_t)2*EtotM*4);
  int*            FPERM= (int*)alloc(nrows*4);
  float*          GS[2];
  GS[0] = (float*)alloc((size_t)385280*4);
  GS[1] = (float*)alloc((size_t)385280*4);
  unsigned*       MM   = (unsigned*)alloc(2*4);
  unsigned*       HIST = (unsigned*)alloc(16*4);
  unsigned short* WKP  = (unsigned short*)alloc((size_t)8*16384*2);
  unsigned short* WQP  = (unsigned short*)alloc((size_t)8*16384*2);
  unsigned short* WVP  = (unsigned short*)alloc((size_t)8*16384*2);
  unsigned short* WAP  = (unsigned short*)alloc((size_t)8*16384*2);
  unsigned short* WATTP= (unsigned short*)alloc((size_t)16384*2);
  unsigned short* ARP  = (unsigned short*)alloc((size_t)16*4096*2);
  unsigned short* MRP  = (unsigned short*)alloc((size_t)16*4096*2);
  size_t uni_bytes = (size_t)FFUNC*FFUNC*4;
  size_t curs_bytes = (size_t)8*NO*4;
  void* UNI = alloc(uni_bytes > curs_bytes ? uni_bytes : curs_bytes);
  int*   CURS = (int*)UNI;
  float* SCb  = (float*)UNI;

  packw_k<<<8,256,0,stream>>>(Wk, WKP);
  packw_k<<<8,256,0,stream>>>(Wq, WQP);
  packw_k<<<8,256,0,stream>>>(Wv, WVP);
  packw_k<<<8,256,0,stream>>>(Wa, WAP);
  packw_k<<<1,256,0,stream>>>(WATT, WATTP);
  packa_k<<<16,256,0,stream>>>(AR, ARP);
  packa_k<<<16,256,0,stream>>>(MRm, MRP);

  const size_t OF_FSUM=0, OF_FCNT=128000, OF_CF=129024, OF_ATTC=257024, OF_FEMB=257152, OF_POOL=385152;
  const int stf[4] = {1,0,1,1};
  const int dtf[4] = {1,1,0,1};

  for (int g=0; g<2; ++g){
    int nd = NdA[g], ni = NiA[g];
    int E[4] = {EA[g][0],EA[g][1],EA[g][2],EA[g][3]};
    int eoff[4]; eoff[0]=0;
    for (int r=1;r<4;r++) eoff[r] = eoff[r-1] + E[r-1];
    const int* ei[4] = {(const int*)d_in[g*8+2], (const int*)d_in[g*8+3],
                        (const int*)d_in[g*8+4], (const int*)d_in[g*8+5]};
    const int* fdp = (const int*)d_in[g*8+6];
    const int* fip = (const int*)d_in[g*8+7];
    const float* x0d = (const float*)d_in[g*8+0];
    const float* x0i = (const float*)d_in[g*8+1];
    int gbd = (nd+63)/64, gbi = (ni+63)/64;
    int nt = nd + ni;
    int ntb = (nt+255)/256; if (ntb > 2048) ntb = 2048;

    // per-direction KR4 row offsets + src/dst type info
    int koff[2][4], stA[2][4], dtA[2][4];
    for (int c=0;c<2;c++){
      int run = 0;
      for (int r=0;r<4;r++){
        stA[c][r] = (c==0) ? stf[r] : dtf[r];
        dtA[c][r] = (c==0) ? dtf[r] : stf[r];
        koff[c][r] = run;
        run += stA[c][r] ? ni : nd;
      }
    }

    // ---- build 8 edge CSRs + function CSR (batched) ----
    hipMemsetAsync(OFFS, 0, (size_t)8*NO*4 + 1024*4, stream);
    HD hd; int hb = 0;
    ScanDesc sd;
    for (int c2=0; c2<2; c2++)
      for (int r=0; r<4; r++){
        int ent = c2*4 + r;
        hd.blk0[ent] = hb;
        hd.dst[ent] = (c2==0) ? ei[r]+E[r] : ei[r];
        hd.src[ent] = (c2==0) ? ei[r] : ei[r]+E[r];
        hd.E[ent] = E[r];
        hd.cnto[ent] = ent*NO;
        hd.permo[ent] = c2*(int)EtotM + eoff[r];
        sd.n[ent] = (dtA[c2][r]) ? ni : nd;
        hb += (E[r]+255)/256;
      }
    hd.blk0[8] = hb;
    csr_hist_all_k<<<hb,256,0,stream>>>(hd, OFFS);
    fhist_k<<<ntb,256,0,stream>>>(fdp, fip, nd, ni, FOFFS);
    csr_scan_k<<<8,1024,0,stream>>>(sd, OFFS, CURS, NO);
    ScanDesc fsd; fsd.n[0] = FFUNC;
    csr_scan_k<<<1,1024,0,stream>>>(fsd, FOFFS, FCURS, 1024);
    csr_fill_all_k<<<hb,256,0,stream>>>(hd, CURS, PERM);
    ffill_k<<<ntb,256,0,stream>>>(fdp, fip, nd, ni, FCURS, FPERM);

    for (int l=0; l<2; ++l){
      const void* xd = (l==0) ? (const void*)x0d : (const void*)Xb;
      const void* xi = (l==0) ? (const void*)x0i : (const void*)(Xb + (size_t)nd*128);
      int af32 = (l==0);
      for (int c=0; c<2; ++c){
        int pc = l*2 + c;
        hipMemsetAsync(AGG, 0, nrows*128*4 + nrows*4*4*2, stream);
        gemm_kqv_k<<<gbd+gbi,256,0,stream>>>(
            xd, xi, af32, nd, ni, gbd,
            WKP+(size_t)pc*2*16384, WQP+(size_t)pc*2*16384, WVP+(size_t)pc*2*16384,
            bk+(size_t)pc*2*128, bq+(size_t)pc*2*128, bv+(size_t)pc*2*128,
            Kb, Qb, Vb);
        // batched K-transform
        XfD xf; int xb = 0;
        for (int r=0;r<4;r++){
          xf.blk0[r] = xb;
          xf.N[r] = stA[c][r] ? ni : nd;
          xf.inoff[r] = stA[c][r] ? nd : 0;
          xf.outoff[r] = koff[c][r];
          xf.matoff[r] = (pc*4+r)*4096;
          xb += (xf.N[r]+63)/64;
        }
        xf.blk0[4] = xb;
        xform_all_k<<<xb,256,0,stream>>>(Kb, ARP, KR4, xf);
        // batched e1
        E1D e1; int eb = 0;
        for (int r=0;r<4;r++){
          int Ndst = dtA[c][r] ? ni : nd;
          e1.blk0[r] = eb;
          e1.ndst[r] = Ndst;
          e1.offso[r] = (c*4+r)*NO;
          e1.permo[r] = c*(int)EtotM + eoff[r];
          e1.kro[r]   = koff[c][r];
          e1.qo[r]    = dtA[c][r] ? nd : 0;
          e1.nmo[r]   = dtA[c][r] ? nd*4 : 0;
          e1.logo[r]  = eoff[r]*4;
          e1.pro[r]   = (pc*4+r)*4;
          eb += (Ndst*32 + 255)/256;
        }
        e1.blk0[4] = eb;
        e1_all_k<<<eb,256,0,stream>>>(KR4, Qb, OFFS, PERM, PRp, LOGb, NMAX, e1);
        // batched V-transform (same geometry; overwrites KR4 after e1 consumed it)
        xform_all_k<<<xb,256,0,stream>>>(Vb, MRP, KR4, xf);
        // batched e2
        E2D e2;
        for (int r=0;r<4;r++){
          e2.blk0[r] = e1.blk0[r];
          e2.ndst[r] = e1.ndst[r];
          e2.offso[r] = e1.offso[r];
          e2.permo[r] = e1.permo[r];
          e2.vro[r]   = koff[c][r];
          e2.nmo[r]   = e1.nmo[r];
          e2.logo[r]  = e1.logo[r];
          e2.aggo[r]  = dtA[c][r] ? nd*128 : 0;
          e2.deno[r]  = dtA[c][r] ? nd*4 : 0;
        }
        e2.blk0[4] = e1.blk0[4];
        e2_all_k<<<eb,256,0,stream>>>(KR4, LOGb, NMAX, OFFS, PERM, AGG, DEN, e2);
        // fused epilogue (bf16 out)
        gemm_epi_k<<<gbd+gbi,256,0,stream>>>(
            AGG, DEN, nd, ni, gbd,
            WAP+(size_t)pc*2*16384, ba+(size_t)pc*2*128,
            xd, xi, af32,
            (c==1) ? O1b : (const unsigned short*)nullptr,
            (c==0) ? O1b : Xb,
            SKp + (size_t)pc*2, (c==0) ? 2 : 3);
      }
    }
    // pooling (function-CSR, atomic-light, bf16 X)
    float* fsum = GS[g]+OF_FSUM;  float* fcnt = GS[g]+OF_FCNT;
    float* cf   = GS[g]+OF_CF;    float* attc = GS[g]+OF_ATTC;
    float* femb = GS[g]+OF_FEMB;  float* pool = GS[g]+OF_POOL;
    hipMemsetAsync(GS[g], 0, (size_t)385280*4, stream);
    f1c_k<<<FFUNC,256,0,stream>>>(Xb, FOFFS, FPERM, fsum, fcnt);
    attc2_k<<<1,1024,0,stream>>>(fsum, 1.0f/(float)nt, WATT, attc);
    gemmb_k<<<(FFUNC+63)/64,256,0,stream>>>(fsum, FFUNC, WATTP, nullptr, cf, 1, fcnt);
    f23c_k<<<FFUNC,256,0,stream>>>(Xb, FOFFS, FPERM, cf, attc, femb, pool);
  }
  // similarity histogram + final head
  hist_init_k<<<1,32,0,stream>>>(MM, HIST);
  dim3 gnt((FFUNC+15)/16, (FFUNC+15)/16);
  gemmnt_k<<<gnt,256,0,stream>>>(GS[0]+OF_FEMB, GS[1]+OF_FEMB, SCb, MM);
  hist_k<<<512,256,0,stream>>>(SCb, MM, HIST);
  final_k<<<1,256,0,stream>>>(GS[0]+OF_POOL, GS[1]+OF_POOL, WTN, VTN, BTN, HIST,
                              WFC1, BFC1, WSC, BSC, (float*)d_out);
}

// Round 8
// 2637.352 us; speedup vs baseline: 3.6671x; 1.0949x over previous
//
#include <hip/hip_runtime.h>
#include <math.h>

#define FFUNC 1000

typedef __attribute__((ext_vector_type(8))) short s8v;
typedef __attribute__((ext_vector_type(4))) float f4v;

// ---------------- device helpers ----------------
__device__ __forceinline__ float sigf(float x){ return 1.0f/(1.0f+expf(-x)); }
__device__ __forceinline__ float geluf(float x){
  return 0.5f*x*(1.0f + tanhf(0.7978845608028654f*(x + 0.044715f*x*x*x)));
}
__device__ __forceinline__ unsigned fkey(float f){
  unsigned u = __float_as_uint(f);
  return (u & 0x80000000u) ? ~u : (u | 0x80000000u);
}
__device__ __forceinline__ float funkey(unsigned k){
  unsigned u = (k & 0x80000000u) ? (k ^ 0x80000000u) : ~k;
  return __uint_as_float(u);
}
__device__ __forceinline__ void atomAddF(float* p, float v){ unsafeAtomicAdd(p, v); }
__device__ __forceinline__ unsigned short bfr(float x){   // f32 -> bf16 RNE
  unsigned u = __float_as_uint(x);
  unsigned r = (u + 0x7FFFu + ((u >> 16) & 1u)) >> 16;
  return (unsigned short)r;
}
__device__ __forceinline__ float b2f(unsigned short v){
  return __uint_as_float((unsigned)v << 16);
}

// ---------------- weight prepack ----------------
__global__ void packw_k(const float* __restrict__ W, unsigned short* __restrict__ out){
  int mat = blockIdx.x;
  const float* w = W + (size_t)mat*16384;
  unsigned short* o = out + (size_t)mat*16384;
  for (int u=0; u<64; u++){
    int oi = u*256 + threadIdx.x;
    int j = oi & 7, l = (oi>>3) & 63, nt = (oi>>9) & 7, kt = oi >> 12;
    float v = w[(size_t)(kt*32 + 8*(l>>4) + j)*128 + nt*16 + (l&15)];
    o[oi] = bfr(v);
  }
}

__global__ void packa_k(const float* __restrict__ A, unsigned short* __restrict__ out){
  int ent = blockIdx.x;
  const float* a = A + (size_t)ent*4096;
  unsigned short* o = out + (size_t)ent*4096;
  for (int u=0; u<16; u++){
    int oi = u*256 + threadIdx.x;
    int j = oi & 7, l = (oi>>3) & 63, nt = (oi>>9) & 1, h = oi >> 10;
    float v = a[(size_t)h*1024 + (size_t)(8*(l>>4)+j)*32 + nt*16 + (l&15)];
    o[oi] = bfr(v);
  }
}

// ---------------- fused K/Q/V projection, both node types, f32-or-bf16 A ----------------
__global__ __launch_bounds__(256) void gemm_kqv_k(
    const void* __restrict__ xdv, const void* __restrict__ xiv, int af32,
    int nd, int ni, int gbd,
    const unsigned short* __restrict__ WK, const unsigned short* __restrict__ WQ,
    const unsigned short* __restrict__ WV,
    const float* __restrict__ bK, const float* __restrict__ bQ, const float* __restrict__ bV,
    unsigned short* __restrict__ Kb, unsigned short* __restrict__ Qb,
    unsigned short* __restrict__ Vb)
{
  int blk = blockIdx.x;
  int ty = (blk >= gbd);
  int N = ty ? ni : nd;
  int rbase = (ty ? (blk - gbd) : blk) * 64;
  size_t obase = ty ? (size_t)nd*128 : 0;
  const unsigned short* wk = WK + (ty ? 16384 : 0);
  const unsigned short* wq = WQ + (ty ? 16384 : 0);
  const unsigned short* wv = WV + (ty ? 16384 : 0);
  const float* bk2 = bK + (ty ? 128 : 0);
  const float* bq2 = bQ + (ty ? 128 : 0);
  const float* bv2 = bV + (ty ? 128 : 0);
  const float* Af = (const float*)(ty ? xiv : xdv);
  const unsigned short* Ab = (const unsigned short*)(ty ? xiv : xdv);

  int t = threadIdx.x;
  int l = t & 63, w = t >> 6, b = l >> 4, m = l & 15;
  int arow = rbase + w*16 + m;
  bool rv = arow < N;
  f4v ak[8], aq[8], av[8];
  #pragma unroll
  for (int nt=0; nt<8; nt++){ ak[nt]=(f4v){0,0,0,0}; aq[nt]=(f4v){0,0,0,0}; av[nt]=(f4v){0,0,0,0}; }

  #pragma unroll
  for (int kt=0; kt<4; kt++){
    s8v af = (s8v){0,0,0,0,0,0,0,0};
    if (rv){
      if (af32){
        const float* ap = Af + (size_t)arow*128 + kt*32 + b*8;
        float4 x0 = *(const float4*)ap;
        float4 x1 = *(const float4*)(ap + 4);
        af[0]=(short)bfr(x0.x); af[1]=(short)bfr(x0.y); af[2]=(short)bfr(x0.z); af[3]=(short)bfr(x0.w);
        af[4]=(short)bfr(x1.x); af[5]=(short)bfr(x1.y); af[6]=(short)bfr(x1.z); af[7]=(short)bfr(x1.w);
      } else {
        af = *(const s8v*)(Ab + (size_t)arow*128 + kt*32 + b*8);
      }
    }
    #pragma unroll
    for (int nt=0; nt<8; nt++){
      int fo = ((kt*8 + nt)*64 + l)*8;
      s8v bk_ = *(const s8v*)(wk + fo);
      s8v bq_ = *(const s8v*)(wq + fo);
      s8v bv_ = *(const s8v*)(wv + fo);
      ak[nt] = __builtin_amdgcn_mfma_f32_16x16x32_bf16(af, bk_, ak[nt], 0, 0, 0);
      aq[nt] = __builtin_amdgcn_mfma_f32_16x16x32_bf16(af, bq_, aq[nt], 0, 0, 0);
      av[nt] = __builtin_amdgcn_mfma_f32_16x16x32_bf16(af, bv_, av[nt], 0, 0, 0);
    }
  }
  float bkr[8], bqr[8], bvr[8];
  #pragma unroll
  for (int nt=0; nt<8; nt++){ int col=nt*16+m; bkr[nt]=bk2[col]; bqr[nt]=bq2[col]; bvr[nt]=bv2[col]; }
  #pragma unroll
  for (int r2=0; r2<4; r2++){
    int orow = rbase + w*16 + 4*b + r2;
    if (orow >= N) continue;
    size_t ob = obase + (size_t)orow*128 + m;
    #pragma unroll
    for (int nt=0; nt<8; nt++){
      Kb[ob + nt*16] = bfr(ak[nt][r2] + bkr[nt]);
      Qb[ob + nt*16] = bfr(aq[nt][r2] + bqr[nt]);
      Vb[ob + nt*16] = bfr(av[nt][r2] + bvr[nt]);
    }
  }
}

// ---------------- fused epilogue GEMM (AGG bf16) ----------------
__global__ __launch_bounds__(256) void gemm_epi_k(
    const unsigned short* __restrict__ AGGb, const float* __restrict__ DENb,
    int nd, int ni, int gbd,
    const unsigned short* __restrict__ WA, const float* __restrict__ bA,
    const void* __restrict__ xin_dv, const void* __restrict__ xin_iv, int xf32,
    const unsigned short* __restrict__ o1p, unsigned short* __restrict__ out,
    const float* __restrict__ skp, int mode)
{
  int blk = blockIdx.x;
  int ty = (blk >= gbd);
  int N = ty ? ni : nd;
  int rbase = (ty ? (blk - gbd) : blk) * 64;
  int goff = ty ? nd : 0;
  const unsigned short* wa = WA + (ty ? 16384 : 0);
  const float* ba2 = bA + (ty ? 128 : 0);
  const float* xinF = (const float*)(ty ? xin_iv : xin_dv);
  const unsigned short* xinB = (const unsigned short*)(ty ? xin_iv : xin_dv);
  float s = sigf(skp[ty]), s1 = 1.0f - s;

  int t = threadIdx.x;
  int l = t & 63, w = t >> 6, b = l >> 4, m = l & 15;
  int arow = rbase + w*16 + m;
  bool rv = arow < N;
  f4v acc[8];
  #pragma unroll
  for (int nt=0; nt<8; nt++) acc[nt] = (f4v){0,0,0,0};

  #pragma unroll
  for (int kt=0; kt<4; kt++){
    s8v af = (s8v){0,0,0,0,0,0,0,0};
    if (rv){
      size_t grow = (size_t)(goff + arow);
      float dv = 1.0f / fmaxf(DENb[grow*4 + kt], 1e-16f);
      s8v ag = *(const s8v*)(AGGb + grow*128 + kt*32 + b*8);
      #pragma unroll
      for (int jj=0; jj<8; jj++)
        af[jj] = (short)bfr(geluf(b2f((unsigned short)ag[jj]) * dv));
    }
    #pragma unroll
    for (int nt=0; nt<8; nt++){
      s8v bf = *(const s8v*)(wa + ((kt*8 + nt)*64 + l)*8);
      acc[nt] = __builtin_amdgcn_mfma_f32_16x16x32_bf16(af, bf, acc[nt], 0, 0, 0);
    }
  }
  #pragma unroll
  for (int r2=0; r2<4; r2++){
    int orow = rbase + w*16 + 4*b + r2;
    if (orow >= N) continue;
    size_t grow = (size_t)(goff + orow);
    #pragma unroll
    for (int nt=0; nt<8; nt++){
      int col = nt*16 + m;
      float v = acc[nt][r2] + ba2[col];
      float xv = xf32 ? xinF[(size_t)orow*128 + col] : b2f(xinB[(size_t)orow*128 + col]);
      v = s*v + s1*xv;
      if (mode == 3){
        float o1 = b2f(o1p[grow*128 + col]);
        v = fmaxf(0.5f*o1 + 0.5f*v, 0.f);
      }
      out[grow*128 + col] = bfr(v);
    }
  }
}

// ---------------- batched per-head transform over 4 relations ----------------
struct XfD {
  int blk0[5];
  int N[4];
  int inoff[4];
  int outoff[4];
  int matoff[4];
};
__global__ __launch_bounds__(256) void xform_all_k(
    const unsigned short* __restrict__ Xb,
    const unsigned short* __restrict__ Apb,
    unsigned short* __restrict__ outb, XfD d)
{
  int bq = blockIdx.x;
  int r = (bq >= d.blk0[1]) + (bq >= d.blk0[2]) + (bq >= d.blk0[3]);
  int lb = bq - d.blk0[r];
  int N = d.N[r];
  const unsigned short* X = Xb + (size_t)d.inoff[r]*128;
  const unsigned short* Ap = Apb + d.matoff[r];
  unsigned short* out = outb + (size_t)d.outoff[r]*128;

  int t = threadIdx.x;
  int l = t & 63, w = t >> 6, b = l >> 4, m = l & 15;
  int arow = lb*64 + w*16 + m;
  bool rv = arow < N;
  f4v acc[8];
  #pragma unroll
  for (int i=0;i<8;i++) acc[i] = (f4v){0,0,0,0};
  #pragma unroll
  for (int h=0; h<4; h++){
    s8v af = (s8v){0,0,0,0,0,0,0,0};
    if (rv) af = *(const s8v*)(X + (size_t)arow*128 + h*32 + b*8);
    #pragma unroll
    for (int nt=0; nt<2; nt++){
      s8v bf = *(const s8v*)(Ap + ((h*2 + nt)*64 + l)*8);
      acc[h*2+nt] = __builtin_amdgcn_mfma_f32_16x16x32_bf16(af, bf, acc[h*2+nt], 0, 0, 0);
    }
  }
  #pragma unroll
  for (int r2=0; r2<4; r2++){
    int orow = lb*64 + w*16 + 4*b + r2;
    if (orow >= N) continue;
    #pragma unroll
    for (int h=0; h<4; h++)
      #pragma unroll
      for (int nt=0; nt<2; nt++)
        out[(size_t)orow*128 + h*32 + nt*16 + m] = bfr(acc[h*2+nt][r2]);
  }
}

// ---------------- merged CSR build ----------------
struct ScanDesc { int n[8]; };

struct HD {
  int blk0[9];
  const int* dst[8];
  const int* src[8];
  int E[8];
  int cnto[8];    // dir*NOR + dst type base
  int permo[8];   // dir*EtotM
};
__global__ void csr_hist_all_k(HD d, int* __restrict__ cnt){
  int b = blockIdx.x;
  int r = 0;
  while (r < 7 && b >= d.blk0[r+1]) r++;
  int e = (b - d.blk0[r])*256 + threadIdx.x;
  if (e < d.E[r]) atomicAdd(&cnt[d.cnto[r] + d.dst[r][e]], 1);
}
__global__ void csr_fill_all_k(HD d, int* __restrict__ curs, int* __restrict__ perm){
  int b = blockIdx.x;
  int r = 0;
  while (r < 7 && b >= d.blk0[r+1]) r++;
  int e = (b - d.blk0[r])*256 + threadIdx.x;
  if (e < d.E[r]){
    int pos = atomicAdd(&curs[d.cnto[r] + d.dst[r][e]], 1);
    perm[d.permo[r] + pos] = d.src[r][e] | ((r & 3) << 24);
  }
}

// wave-level scan: 3 barriers per 1024-chunk
__global__ __launch_bounds__(1024) void csr_scan_k(ScanDesc sd, int* __restrict__ offs,
                                                   int* __restrict__ curs, int NO){
  int ent = blockIdx.x;
  int n = sd.n[ent];
  int* o  = offs + (size_t)ent*NO;
  int* cu = curs + (size_t)ent*NO;
  __shared__ int wsum[16];
  __shared__ int woff[17];
  int tid = threadIdx.x, lane = tid & 63, wv = tid >> 6;
  int run = 0;
  for (int base=0; base<n; base+=1024){
    int i = base + tid;
    int v = (i<n) ? o[i] : 0;
    int s = v;
    #pragma unroll
    for (int d2=1; d2<64; d2<<=1){
      int t2 = __shfl_up(s, d2, 64);
      if (lane >= d2) s += t2;
    }
    if (lane == 63) wsum[wv] = s;
    __syncthreads();
    if (wv == 0 && lane < 16){
      int x = wsum[lane];
      #pragma unroll
      for (int d2=1; d2<16; d2<<=1){
        int t2 = __shfl_up(x, d2, 64);
        if (lane >= d2) x += t2;
      }
      woff[lane+1] = x;
      if (lane == 0) woff[0] = 0;
    }
    __syncthreads();
    int excl = run + woff[wv] + s - v;
    if (i < n){ o[i] = excl; cu[i] = excl; }
    run += woff[16];
    __syncthreads();
  }
  if (tid == 0) o[n] = run;
}

// ---------------- function-CSR build ----------------
__global__ void fhist_k(const int* __restrict__ fd, const int* __restrict__ fi,
                        int Nd, int Ni, int* __restrict__ cnt){
  int nt = Nd + Ni;
  for (int n = blockIdx.x*256 + threadIdx.x; n < nt; n += gridDim.x*256){
    int f = (n < Nd) ? fd[n] : fi[n-Nd];
    atomicAdd(&cnt[f], 1);
  }
}
__global__ void ffill_k(const int* __restrict__ fd, const int* __restrict__ fi,
                        int Nd, int Ni, int* __restrict__ curs, int* __restrict__ perm){
  int nt = Nd + Ni;
  for (int n = blockIdx.x*256 + threadIdx.x; n < nt; n += gridDim.x*256){
    int f = (n < Nd) ? fd[n] : fi[n-Nd];
    int pos = atomicAdd(&curs[f], 1);
    perm[pos] = n;
  }
}

// ---------------- E1 merged: logits only ----------------
struct MD { int koff[4]; };
__global__ __launch_bounds__(256) void e1m_k(
    const unsigned short* __restrict__ KR4, const unsigned short* __restrict__ Qb,
    const int* __restrict__ offs, const int* __restrict__ perm, int nrows,
    const float* __restrict__ pr, float* __restrict__ logits, MD md)
{
  int gidx = blockIdx.x*256 + threadIdx.x;
  int node = gidx >> 5; if (node >= nrows) return;
  int sub = gidx & 31, h = sub >> 3, j = sub & 7;
  int o0 = offs[node], o1 = offs[node+1];
  if (o0 == o1) return;
  ushort4 qa = *(const ushort4*)(Qb + (size_t)node*128 + h*32 + j*4);
  float q0=b2f(qa.x), q1=b2f(qa.y), q2=b2f(qa.z), q3=b2f(qa.w);
  for (int i=o0; i<o1; ++i){
    int pk = perm[i];
    int src = pk & 0xFFFFFF, rel = pk >> 24;
    const unsigned short* kr = KR4 + (size_t)(md.koff[rel] + src)*128 + h*32 + j*4;
    ushort4 aa = *(const ushort4*)kr;
    float p = b2f(aa.x)*q0 + b2f(aa.y)*q1 + b2f(aa.z)*q2 + b2f(aa.w)*q3;
    p += __shfl_xor(p, 1, 8);
    p += __shfl_xor(p, 2, 8);
    p += __shfl_xor(p, 4, 8);
    if (j == 0)
      logits[(size_t)i*4 + h] = p * (pr[rel*4 + h] * 0.17677669529663687f);
  }
}

// ---------------- E2 merged: max + exp + aggregate + den, single owner ----------------
__global__ __launch_bounds__(256) void e2m_k(
    const unsigned short* __restrict__ VR4, const float* __restrict__ logits,
    const int* __restrict__ offs, const int* __restrict__ perm, int nrows,
    unsigned short* __restrict__ aggb, float* __restrict__ den, MD md)
{
  int gidx = blockIdx.x*256 + threadIdx.x;
  int node = gidx >> 5; if (node >= nrows) return;
  int sub = gidx & 31, h = sub >> 3, j = sub & 7;
  int o0 = offs[node], o1 = offs[node+1];
  unsigned short* ap = aggb + (size_t)node*128 + h*32 + j*4;
  if (o0 == o1){
    *(ushort4*)ap = make_ushort4(0,0,0,0);
    if (j == 0) den[(size_t)node*4 + h] = 0.f;
    return;
  }
  float mx = -INFINITY;
  for (int i=o0; i<o1; ++i) mx = fmaxf(mx, logits[(size_t)i*4 + h]);
  float4 acc = make_float4(0.f,0.f,0.f,0.f);
  float ds = 0.f;
  for (int i=o0; i<o1; ++i){
    float ev = __expf(logits[(size_t)i*4 + h] - mx);
    int pk = perm[i];
    int src = pk & 0xFFFFFF, rel = pk >> 24;
    ushort4 v = *(const ushort4*)(VR4 + (size_t)(md.koff[rel] + src)*128 + h*32 + j*4);
    acc.x += ev*b2f(v.x); acc.y += ev*b2f(v.y); acc.z += ev*b2f(v.z); acc.w += ev*b2f(v.w);
    ds += ev;
  }
  *(ushort4*)ap = make_ushort4(bfr(acc.x), bfr(acc.y), bfr(acc.z), bfr(acc.w));
  if (j == 0) den[(size_t)node*4 + h] = ds;
}

// ---------------- plain MFMA GEMM (cf only; optional per-row divide) ----------------
__global__ __launch_bounds__(256) void gemmb_k(
    const float* __restrict__ A, int N,
    const unsigned short* __restrict__ Wp, const float* __restrict__ bias,
    float* __restrict__ outf, int mode, const float* __restrict__ rdiv)
{
  int t = threadIdx.x;
  int l = t & 63, w = t >> 6, b = l >> 4, m = l & 15;
  int arow = blockIdx.x*64 + w*16 + m;
  bool rv = arow < N;
  float dv = 1.0f;
  if (rv && rdiv) dv = 1.0f / fmaxf(rdiv[arow], 1.0f);
  f4v acc[8];
  #pragma unroll
  for (int nt=0; nt<8; nt++) acc[nt] = (f4v){0,0,0,0};
  #pragma unroll
  for (int kt=0; kt<4; kt++){
    s8v af = (s8v){0,0,0,0,0,0,0,0};
    if (rv){
      const float* ap = A + (size_t)arow*128 + kt*32 + b*8;
      float4 x0 = *(const float4*)ap;
      float4 x1 = *(const float4*)(ap + 4);
      af[0]=(short)bfr(x0.x*dv); af[1]=(short)bfr(x0.y*dv); af[2]=(short)bfr(x0.z*dv); af[3]=(short)bfr(x0.w*dv);
      af[4]=(short)bfr(x1.x*dv); af[5]=(short)bfr(x1.y*dv); af[6]=(short)bfr(x1.z*dv); af[7]=(short)bfr(x1.w*dv);
    }
    #pragma unroll
    for (int nt=0; nt<8; nt++){
      s8v bf = *(const s8v*)(Wp + ((kt*8 + nt)*64 + l)*8);
      acc[nt] = __builtin_amdgcn_mfma_f32_16x16x32_bf16(af, bf, acc[nt], 0, 0, 0);
    }
  }
  #pragma unroll
  for (int r2=0; r2<4; r2++){
    int orow = blockIdx.x*64 + w*16 + 4*b + r2;
    if (orow >= N) continue;
    #pragma unroll
    for (int nt=0; nt<8; nt++){
      int col = nt*16 + m;
      float v = acc[nt][r2];
      if (bias) v += bias[col];
      if (mode == 1) v = tanhf(v);
      outf[(size_t)orow*128 + col] = v;
    }
  }
}

// ---------------- func pool (CSR, bf16 X): sums + counts ----------------
__global__ __launch_bounds__(256) void f1c_k(const unsigned short* __restrict__ X,
    const int* __restrict__ foffs, const int* __restrict__ fperm,
    float* __restrict__ fsum, float* __restrict__ fcnt)
{
  __shared__ __align__(16) float red[4][128];
  int t = threadIdx.x, wv = t >> 6, lane = t & 63;
  int f = blockIdx.x;
  int o0 = foffs[f], o1 = foffs[f+1];
  float a0 = 0, a1 = 0;
  for (int i = o0 + wv; i < o1; i += 4){
    ushort2 x = *(const ushort2*)(X + (size_t)fperm[i]*128 + lane*2);
    a0 += b2f(x.x); a1 += b2f(x.y);
  }
  red[wv][lane*2] = a0; red[wv][lane*2+1] = a1;
  __syncthreads();
  if (t < 128)
    fsum[(size_t)f*128 + t] = red[0][t] + red[1][t] + red[2][t] + red[3][t];
  if (t == 0) fcnt[f] = (float)(o1 - o0);
}

// ---------------- func pool (CSR, bf16 X): femb(bf16) + global attention pool ----------------
__global__ __launch_bounds__(256) void f23c_k(const unsigned short* __restrict__ X,
    const int* __restrict__ foffs, const int* __restrict__ fperm,
    const float* __restrict__ cf, const float* __restrict__ attc,
    unsigned short* __restrict__ fembb, float* __restrict__ pooled)
{
  __shared__ __align__(16) float rede[4][128];
  __shared__ __align__(16) float redp[4][128];
  int t = threadIdx.x, wv = t >> 6, lane = t & 63;
  int f = blockIdx.x;
  int o0 = foffs[f], o1 = foffs[f+1];
  float c0 = cf[(size_t)f*128 + lane*2], c1 = cf[(size_t)f*128 + lane*2 + 1];
  float t0 = attc[lane*2], t1 = attc[lane*2 + 1];
  float e0=0, e1=0, p0=0, p1=0;
  for (int i = o0 + wv; i < o1; i += 4){
    ushort2 xr = *(const ushort2*)(X + (size_t)fperm[i]*128 + lane*2);
    float vx = b2f(xr.x), vy = b2f(xr.y);
    union { double d; float2 f2; } u;
    u.f2.x = vx*c0 + vy*c1;
    u.f2.y = vx*t0 + vy*t1;
    #pragma unroll
    for (int m2=1; m2<64; m2<<=1){
      union { double d; float2 f2; } v;
      v.d = __shfl_xor(u.d, m2, 64);
      u.f2.x += v.f2.x; u.f2.y += v.f2.y;
    }
    float s1 = sigf(u.f2.x), s2 = sigf(u.f2.y);
    e0 += vx*s1; e1 += vy*s1;
    p0 += vx*s2; p1 += vy*s2;
  }
  rede[wv][lane*2] = e0; rede[wv][lane*2+1] = e1;
  redp[wv][lane*2] = p0; redp[wv][lane*2+1] = p1;
  __syncthreads();
  if (t < 128){
    fembb[(size_t)f*128 + t] = bfr(rede[0][t] + rede[1][t] + rede[2][t] + rede[3][t]);
    float pp = redp[0][t] + redp[1][t] + redp[2][t] + redp[3][t];
    atomAddF(&pooled[t], pp);
  }
}

// ---------------- attention-pool context (parallel colsum) ----------------
__global__ __launch_bounds__(1024) void attc2_k(const float* __restrict__ fsum, float Ninv,
                                                const float* __restrict__ Watt,
                                                float* __restrict__ attc)
{
  __shared__ float part[8][128];
  __shared__ float mean[128];
  int t = threadIdx.x;
  int j = t & 127, ch = t >> 7;
  float a = 0;
  for (int f = ch; f < FFUNC; f += 8) a += fsum[(size_t)f*128 + j];
  part[ch][j] = a;
  __syncthreads();
  if (t < 128){
    float m = 0;
    #pragma unroll
    for (int c=0;c<8;c++) m += part[c][t];
    mean[t] = m * Ninv;
  }
  __syncthreads();
  if (t < 128){
    float c = 0;
    for (int k=0;k<128;k++) c += mean[k]*Watt[(size_t)k*128 + t];
    attc[t] = tanhf(c);
  }
}

// ---------------- MFMA similarity GEMM (NT, bf16) + min/max ----------------
__global__ __launch_bounds__(256) void gemmnt_b(const unsigned short* __restrict__ fa,
                                                const unsigned short* __restrict__ fb,
                                                float* __restrict__ sc,
                                                unsigned* __restrict__ mmk)
{
  int t = threadIdx.x;
  int l = t & 63, w = t >> 6, b = l >> 4, m = l & 15;
  int rowbase = blockIdx.y*64 + w*16;
  int colbase = blockIdx.x*64;
  f4v acc[4];
  #pragma unroll
  for (int nt=0; nt<4; nt++) acc[nt] = (f4v){0,0,0,0};
  #pragma unroll
  for (int kt=0; kt<4; kt++){
    int arow = rowbase + m;
    s8v af = (s8v){0,0,0,0,0,0,0,0};
    if (arow < FFUNC) af = *(const s8v*)(fa + (size_t)arow*128 + kt*32 + b*8);
    #pragma unroll
    for (int nt=0; nt<4; nt++){
      int brow = colbase + nt*16 + m;
      s8v bf = (s8v){0,0,0,0,0,0,0,0};
      if (brow < FFUNC) bf = *(const s8v*)(fb + (size_t)brow*128 + kt*32 + b*8);
      acc[nt] = __builtin_amdgcn_mfma_f32_16x16x32_bf16(af, bf, acc[nt], 0, 0, 0);
    }
  }
  float mn = INFINITY, mx = -INFINITY;
  #pragma unroll
  for (int nt=0; nt<4; nt++){
    #pragma unroll
    for (int r2=0; r2<4; r2++){
      int row = rowbase + 4*b + r2;
      int col = colbase + nt*16 + m;
      if (row < FFUNC && col < FFUNC){
        float v = acc[nt][r2];
        sc[(size_t)row*FFUNC + col] = v;
        mn = fminf(mn, v); mx = fmaxf(mx, v);
      }
    }
  }
  __shared__ float smn[256], smx[256];
  smn[t]=mn; smx[t]=mx; __syncthreads();
  for (int o=128;o>0;o>>=1){
    if (t<o){ smn[t]=fminf(smn[t],smn[t+o]); smx[t]=fmaxf(smx[t],smx[t+o]); }
    __syncthreads();
  }
  if (t==0){ atomicMin(&mmk[0], fkey(smn[0])); atomicMax(&mmk[1], fkey(smx[0])); }
}

__global__ void hist_init_k(unsigned* mmk, unsigned* hist){
  int t = threadIdx.x;
  if (t==0){ mmk[0]=0xFFFFFFFFu; mmk[1]=0u; }
  if (t<16) hist[t]=0u;
}

__global__ void hist_k(const float* __restrict__ sc, const unsigned* __restrict__ mmk,
                       unsigned* __restrict__ hist)
{
  __shared__ unsigned hl[16];
  int t = threadIdx.x;
  if (t < 16) hl[t] = 0;
  __syncthreads();
  float mn = funkey(mmk[0]), mx = funkey(mmk[1]);
  float rng = fmaxf(mx - mn, 1e-12f);
  const long total = (long)FFUNC*FFUNC;
  for (long idx = (long)blockIdx.x*256 + t; idx < total; idx += (long)gridDim.x*256){
    float v = sc[idx];
    int b = (int)floorf((v - mn)/rng * 16.0f);
    b = min(max(b,0),15);
    atomicAdd(&hl[b], 1u);
  }
  __syncthreads();
  if (t < 16) atomicAdd(&hist[t], hl[t]);
}

// ---------------- final head ----------------
__global__ __launch_bounds__(256) void final_k(
    const float* __restrict__ p1, const float* __restrict__ p2,
    const float* __restrict__ Wtn, const float* __restrict__ Vtn,
    const float* __restrict__ btn, const unsigned* __restrict__ hist,
    const float* __restrict__ Wfc1, const float* __restrict__ bfc1,
    const float* __restrict__ Wsc, const float* __restrict__ bsc,
    float* __restrict__ outp)
{
  __shared__ float P1[128], P2[128], part[256], feats[32], hv[16];
  int t = threadIdx.x;
  if (t < 128){ P1[t] = p1[t]; P2[t] = p2[t]; }
  __syncthreads();
  int k = t & 15, pr_ = t >> 4;
  float acc = 0;
  for (int i = pr_*8; i < pr_*8+8; ++i){
    float pi = P1[i];
    const float* wrow = Wtn + ((size_t)i*128)*16 + k;
    float a2 = 0;
    for (int j=0;j<128;++j) a2 += P2[j]*wrow[(size_t)j*16];
    acc += pi*a2;
  }
  part[t] = acc;
  __syncthreads();
  if (t < 16){
    float sc_ = 0;
    for (int p=0;p<16;p++) sc_ += part[p*16 + t];
    float bl = btn[t];
    for (int j=0;j<256;j++) bl += Vtn[(size_t)t*256 + j] * (j<128 ? P1[j] : P2[j-128]);
    float tv = sc_ + bl;
    feats[t] = tv > 0.f ? tv : 0.f;
    feats[16+t] = (float)hist[t] * (1.0f/((float)FFUNC*(float)FFUNC));
  }
  __syncthreads();
  if (t < 16){
    float a2 = bfc1[t];
    for (int q2=0;q2<32;q2++) a2 += feats[q2]*Wfc1[q2*16 + t];
    hv[t] = a2 > 0.f ? a2 : 0.f;
  }
  __syncthreads();
  if (t == 0){
    float z = bsc[0];
    for (int m=0;m<16;m++) z += hv[m]*Wsc[m];
    outp[0] = sigf(z);
  }
}

// ---------------- host ----------------
extern "C" void kernel_launch(void* const* d_in, const int* in_sizes, int n_in,
                              void* d_out, int out_size, void* d_ws, size_t ws_size,
                              hipStream_t stream)
{
  (void)n_in; (void)out_size; (void)ws_size;
  const float* Wk = (const float*)d_in[16];
  const float* bk = (const float*)d_in[17];
  const float* Wq = (const float*)d_in[18];
  const float* bq = (const float*)d_in[19];
  const float* Wv = (const float*)d_in[20];
  const float* bv = (const float*)d_in[21];
  const float* Wa = (const float*)d_in[22];
  const float* ba = (const float*)d_in[23];
  const float* SKp = (const float*)d_in[24];
  const float* AR = (const float*)d_in[25];
  const float* MRm = (const float*)d_in[26];
  const float* PRp = (const float*)d_in[27];
  const float* WATT = (const float*)d_in[28];
  const float* WTN = (const float*)d_in[29];
  const float* VTN = (const float*)d_in[30];
  const float* BTN = (const float*)d_in[31];
  const float* WFC1 = (const float*)d_in[32];
  const float* BFC1 = (const float*)d_in[33];
  const float* WSC = (const float*)d_in[34];
  const float* BSC = (const float*)d_in[35];

  int NdA[2] = { in_sizes[0]/128, in_sizes[8]/128 };
  int NiA[2] = { in_sizes[1]/128, in_sizes[9]/128 };
  int EA[2][4];
  for (int g=0; g<2; g++)
    for (int r=0; r<4; r++) EA[g][r] = in_sizes[g*8+2+r]/2;

  int NdM = NdA[0] > NdA[1] ? NdA[0] : NdA[1];
  int NiM = NiA[0] > NiA[1] ? NiA[0] : NiA[1];
  long EtotM = 0;
  for (int g=0; g<2; g++){
    long et = 0; for (int r=0;r<4;r++) et += EA[g][r];
    if (et > EtotM) EtotM = et;
  }
  size_t nrowsM = (size_t)NdM + (size_t)NiM;
  int NOR = (int)(((nrowsM + 2 + 63)/64)*64);
  long KR4rows = 3L*NiM + NdM;

  char* wp = (char*)d_ws;
  auto alloc = [&](size_t bytes)->void*{
    void* p = (void*)wp;
    wp += (bytes + 255) & ~(size_t)255;
    return p;
  };
  unsigned short* Xb   = (unsigned short*)alloc(nrowsM*128*2);
  unsigned short* AGGb = (unsigned short*)alloc(nrowsM*128*2);
  float*          DEN  = (float*)alloc(nrowsM*4*4);
  unsigned short* O1b  = (unsigned short*)alloc(nrowsM*128*2);
  unsigned short* Kb   = (unsigned short*)alloc(nrowsM*128*2);
  unsigned short* Qb   = (unsigned short*)alloc(nrowsM*128*2);
  unsigned short* Vb   = (unsigned short*)alloc(nrowsM*128*2);
  unsigned short* KR4  = (unsigned short*)alloc((size_t)KR4rows*128*2);
  float*          LOGb = (float*)alloc((size_t)EtotM*4*4);
  int*            OFFS3= (int*)alloc((size_t)3*NOR*4);   // dir0, dir1, func
  int*            PERM = (int*)alloc((size_t)2*EtotM*4);
  int*            FPERM= (int*)alloc(nrowsM*4);
  float*          GS[2];
  GS[0] = (float*)alloc((size_t)257280*4);
  GS[1] = (float*)alloc((size_t)257280*4);
  unsigned short* FB[2];
  FB[0] = (unsigned short*)alloc((size_t)FFUNC*128*2);
  FB[1] = (unsigned short*)alloc((size_t)FFUNC*128*2);
  unsigned*       MM   = (unsigned*)alloc(2*4);
  unsigned*       HIST = (unsigned*)alloc(16*4);
  unsigned short* WKP  = (unsigned short*)alloc((size_t)8*16384*2);
  unsigned short* WQP  = (unsigned short*)alloc((size_t)8*16384*2);
  unsigned short* WVP  = (unsigned short*)alloc((size_t)8*16384*2);
  unsigned short* WAP  = (unsigned short*)alloc((size_t)8*16384*2);
  unsigned short* WATTP= (unsigned short*)alloc((size_t)16384*2);
  unsigned short* ARP  = (unsigned short*)alloc((size_t)16*4096*2);
  unsigned short* MRP  = (unsigned short*)alloc((size_t)16*4096*2);
  size_t uni_bytes = (size_t)FFUNC*FFUNC*4;
  size_t curs_bytes = (size_t)3*NOR*4;
  void* UNI = alloc(uni_bytes > curs_bytes ? uni_bytes : curs_bytes);
  int*   CURS3 = (int*)UNI;
  float* SCb   = (float*)UNI;

  packw_k<<<8,256,0,stream>>>(Wk, WKP);
  packw_k<<<8,256,0,stream>>>(Wq, WQP);
  packw_k<<<8,256,0,stream>>>(Wv, WVP);
  packw_k<<<8,256,0,stream>>>(Wa, WAP);
  packw_k<<<1,256,0,stream>>>(WATT, WATTP);
  packa_k<<<16,256,0,stream>>>(AR, ARP);
  packa_k<<<16,256,0,stream>>>(MRm, MRP);

  const size_t OF_FSUM=0, OF_FCNT=128000, OF_CF=129024, OF_ATTC=257024, OF_POOL=257152;
  const int stf[4] = {1,0,1,1};
  const int dtf[4] = {1,1,0,1};

  for (int g=0; g<2; ++g){
    int nd = NdA[g], ni = NiA[g];
    int nrows = nd + ni;
    int E[4] = {EA[g][0],EA[g][1],EA[g][2],EA[g][3]};
    const int* ei[4] = {(const int*)d_in[g*8+2], (const int*)d_in[g*8+3],
                        (const int*)d_in[g*8+4], (const int*)d_in[g*8+5]};
    const int* fdp = (const int*)d_in[g*8+6];
    const int* fip = (const int*)d_in[g*8+7];
    const float* x0d = (const float*)d_in[g*8+0];
    const float* x0i = (const float*)d_in[g*8+1];
    int gbd = (nd+63)/64, gbi = (ni+63)/64;
    int ntb = (nrows+255)/256; if (ntb > 2048) ntb = 2048;

    int koff[2][4], stA[2][4], dtA[2][4];
    for (int c=0;c<2;c++){
      int run = 0;
      for (int r=0;r<4;r++){
        stA[c][r] = (c==0) ? stf[r] : dtf[r];
        dtA[c][r] = (c==0) ? dtf[r] : stf[r];
        koff[c][r] = run;
        run += stA[c][r] ? ni : nd;
      }
    }

    // ---- build 2 merged edge CSRs + function CSR ----
    hipMemsetAsync(OFFS3, 0, (size_t)3*NOR*4, stream);
    HD hd; int hb = 0;
    for (int c2=0; c2<2; c2++)
      for (int r=0; r<4; r++){
        int ent = c2*4 + r;
        hd.blk0[ent] = hb;
        hd.dst[ent] = (c2==0) ? ei[r]+E[r] : ei[r];
        hd.src[ent] = (c2==0) ? ei[r] : ei[r]+E[r];
        hd.E[ent] = E[r];
        hd.cnto[ent] = c2*NOR + (dtA[c2][r] ? nd : 0);
        hd.permo[ent] = c2*(int)EtotM;
        hb += (E[r]+255)/256;
      }
    hd.blk0[8] = hb;
    csr_hist_all_k<<<hb,256,0,stream>>>(hd, OFFS3);
    fhist_k<<<ntb,256,0,stream>>>(fdp, fip, nd, ni, OFFS3 + (size_t)2*NOR);
    ScanDesc sd; sd.n[0] = nrows; sd.n[1] = nrows; sd.n[2] = FFUNC;
    csr_scan_k<<<3,1024,0,stream>>>(sd, OFFS3, CURS3, NOR);
    csr_fill_all_k<<<hb,256,0,stream>>>(hd, CURS3, PERM);
    ffill_k<<<ntb,256,0,stream>>>(fdp, fip, nd, ni, CURS3 + (size_t)2*NOR, FPERM);

    for (int l=0; l<2; ++l){
      const void* xd = (l==0) ? (const void*)x0d : (const void*)Xb;
      const void* xi = (l==0) ? (const void*)x0i : (const void*)(Xb + (size_t)nd*128);
      int af32 = (l==0);
      for (int c=0; c<2; ++c){
        int pc = l*2 + c;
        gemm_kqv_k<<<gbd+gbi,256,0,stream>>>(
            xd, xi, af32, nd, ni, gbd,
            WKP+(size_t)pc*2*16384, WQP+(size_t)pc*2*16384, WVP+(size_t)pc*2*16384,
            bk+(size_t)pc*2*128, bq+(size_t)pc*2*128, bv+(size_t)pc*2*128,
            Kb, Qb, Vb);
        // batched K-transform into KR4
        XfD xf; int xb = 0;
        for (int r=0;r<4;r++){
          xf.blk0[r] = xb;
          xf.N[r] = stA[c][r] ? ni : nd;
          xf.inoff[r] = stA[c][r] ? nd : 0;
          xf.outoff[r] = koff[c][r];
          xf.matoff[r] = (pc*4+r)*4096;
          xb += (xf.N[r]+63)/64;
        }
        xf.blk0[4] = xb;
        xform_all_k<<<xb,256,0,stream>>>(Kb, ARP, KR4, xf);
        MD md;
        for (int r=0;r<4;r++) md.koff[r] = koff[c][r];
        int eblk = (nrows*32 + 255)/256;
        e1m_k<<<eblk,256,0,stream>>>(KR4, Qb, OFFS3 + (size_t)c*NOR,
                                     PERM + (size_t)c*EtotM, nrows,
                                     PRp + (size_t)pc*16, LOGb, md);
        // V-transform overwrites KR4 (e1m consumed it)
        xform_all_k<<<xb,256,0,stream>>>(Vb, MRP, KR4, xf);
        e2m_k<<<eblk,256,0,stream>>>(KR4, LOGb, OFFS3 + (size_t)c*NOR,
                                     PERM + (size_t)c*EtotM, nrows,
                                     AGGb, DEN, md);
        gemm_epi_k<<<gbd+gbi,256,0,stream>>>(
            AGGb, DEN, nd, ni, gbd,
            WAP+(size_t)pc*2*16384, ba+(size_t)pc*2*128,
            xd, xi, af32,
            (c==1) ? O1b : (const unsigned short*)nullptr,
            (c==0) ? O1b : Xb,
            SKp + (size_t)pc*2, (c==0) ? 2 : 3);
      }
    }
    // pooling (function-CSR, bf16 X)
    float* fsum = GS[g]+OF_FSUM;  float* fcnt = GS[g]+OF_FCNT;
    float* cf   = GS[g]+OF_CF;    float* attc = GS[g]+OF_ATTC;
    float* pool = GS[g]+OF_POOL;
    hipMemsetAsync(pool, 0, 128*4, stream);
    f1c_k<<<FFUNC,256,0,stream>>>(Xb, OFFS3 + (size_t)2*NOR, FPERM, fsum, fcnt);
    attc2_k<<<1,1024,0,stream>>>(fsum, 1.0f/(float)nrows, WATT, attc);
    gemmb_k<<<(FFUNC+63)/64,256,0,stream>>>(fsum, FFUNC, WATTP, nullptr, cf, 1, fcnt);
    f23c_k<<<FFUNC,256,0,stream>>>(Xb, OFFS3 + (size_t)2*NOR, FPERM, cf, attc, FB[g], pool);
  }
  // similarity histogram + final head
  hist_init_k<<<1,32,0,stream>>>(MM, HIST);
  dim3 gnt((FFUNC+63)/64, (FFUNC+63)/64);
  gemmnt_b<<<gnt,256,0,stream>>>(FB[0], FB[1], SCb, MM);
  hist_k<<<512,256,0,stream>>>(SCb, MM, HIST);
  final_k<<<1,256,0,stream>>>(GS[0]+OF_POOL, GS[1]+OF_POOL, WTN, VTN, BTN, HIST,
                              WFC1, BFC1, WSC, BSC, (float*)d_out);
}

// Round 9
// 2385.936 us; speedup vs baseline: 4.0535x; 1.1054x over previous
//
#include <hip/hip_runtime.h>
#include <math.h>

#define FFUNC 1000

typedef __attribute__((ext_vector_type(8))) short s8v;
typedef __attribute__((ext_vector_type(4))) float f4v;

// ---------------- device helpers ----------------
__device__ __forceinline__ float sigf(float x){ return 1.0f/(1.0f+expf(-x)); }
__device__ __forceinline__ float geluf(float x){
  return 0.5f*x*(1.0f + tanhf(0.7978845608028654f*(x + 0.044715f*x*x*x)));
}
__device__ __forceinline__ unsigned fkey(float f){
  unsigned u = __float_as_uint(f);
  return (u & 0x80000000u) ? ~u : (u | 0x80000000u);
}
__device__ __forceinline__ float funkey(unsigned k){
  unsigned u = (k & 0x80000000u) ? (k ^ 0x80000000u) : ~k;
  return __uint_as_float(u);
}
__device__ __forceinline__ void atomAddF(float* p, float v){ unsafeAtomicAdd(p, v); }
__device__ __forceinline__ unsigned short bfr(float x){   // f32 -> bf16 RNE
  unsigned u = __float_as_uint(x);
  unsigned r = (u + 0x7FFFu + ((u >> 16) & 1u)) >> 16;
  return (unsigned short)r;
}
__device__ __forceinline__ float b2f(unsigned short v){
  return __uint_as_float((unsigned)v << 16);
}

// ---------------- weight prepack ----------------
__global__ void packw_k(const float* __restrict__ W, unsigned short* __restrict__ out){
  int mat = blockIdx.x;
  const float* w = W + (size_t)mat*16384;
  unsigned short* o = out + (size_t)mat*16384;
  for (int u=0; u<64; u++){
    int oi = u*256 + threadIdx.x;
    int j = oi & 7, l = (oi>>3) & 63, nt = (oi>>9) & 7, kt = oi >> 12;
    float v = w[(size_t)(kt*32 + 8*(l>>4) + j)*128 + nt*16 + (l&15)];
    o[oi] = bfr(v);
  }
}

__global__ void packa_k(const float* __restrict__ A, unsigned short* __restrict__ out){
  int ent = blockIdx.x;
  const float* a = A + (size_t)ent*4096;
  unsigned short* o = out + (size_t)ent*4096;
  for (int u=0; u<16; u++){
    int oi = u*256 + threadIdx.x;
    int j = oi & 7, l = (oi>>3) & 63, nt = (oi>>9) & 1, h = oi >> 10;
    float v = a[(size_t)h*1024 + (size_t)(8*(l>>4)+j)*32 + nt*16 + (l&15)];
    o[oi] = bfr(v);
  }
}

// ---------------- K/Q/V projection, split by matrix (occupancy) ----------------
__global__ __launch_bounds__(256) void gemm_kqv_k(
    const void* __restrict__ xdv, const void* __restrict__ xiv, int af32,
    int nd, int ni, int gbd, int nb,
    const unsigned short* __restrict__ WK, const unsigned short* __restrict__ WQ,
    const unsigned short* __restrict__ WV,
    const float* __restrict__ bK, const float* __restrict__ bQ, const float* __restrict__ bV,
    unsigned short* __restrict__ Kb, unsigned short* __restrict__ Qb,
    unsigned short* __restrict__ Vb)
{
  int blk = blockIdx.x;
  int mat = blk / nb;
  int bb  = blk - mat*nb;
  int ty = (bb >= gbd);
  int N = ty ? ni : nd;
  int rbase = (ty ? (bb - gbd) : bb) * 64;
  size_t obase = ty ? (size_t)nd*128 : 0;
  const unsigned short* w0 = (mat==0) ? WK : (mat==1) ? WQ : WV;
  const float* bi0 = (mat==0) ? bK : (mat==1) ? bQ : bV;
  unsigned short* outp = (mat==0) ? Kb : (mat==1) ? Qb : Vb;
  const unsigned short* w = w0 + (ty ? 16384 : 0);
  const float* bi = bi0 + (ty ? 128 : 0);
  const float* Af = (const float*)(ty ? xiv : xdv);
  const unsigned short* Ab = (const unsigned short*)(ty ? xiv : xdv);

  int t = threadIdx.x;
  int l = t & 63, wv = t >> 6, b = l >> 4, m = l & 15;
  int arow = rbase + wv*16 + m;
  bool rv = arow < N;
  f4v acc[8];
  #pragma unroll
  for (int nt=0; nt<8; nt++) acc[nt] = (f4v){0,0,0,0};

  #pragma unroll
  for (int kt=0; kt<4; kt++){
    s8v af = (s8v){0,0,0,0,0,0,0,0};
    if (rv){
      if (af32){
        const float* ap = Af + (size_t)arow*128 + kt*32 + b*8;
        float4 x0 = *(const float4*)ap;
        float4 x1 = *(const float4*)(ap + 4);
        af[0]=(short)bfr(x0.x); af[1]=(short)bfr(x0.y); af[2]=(short)bfr(x0.z); af[3]=(short)bfr(x0.w);
        af[4]=(short)bfr(x1.x); af[5]=(short)bfr(x1.y); af[6]=(short)bfr(x1.z); af[7]=(short)bfr(x1.w);
      } else {
        af = *(const s8v*)(Ab + (size_t)arow*128 + kt*32 + b*8);
      }
    }
    #pragma unroll
    for (int nt=0; nt<8; nt++){
      s8v bf = *(const s8v*)(w + ((kt*8 + nt)*64 + l)*8);
      acc[nt] = __builtin_amdgcn_mfma_f32_16x16x32_bf16(af, bf, acc[nt], 0, 0, 0);
    }
  }
  float br[8];
  #pragma unroll
  for (int nt=0; nt<8; nt++) br[nt] = bi[nt*16 + m];
  #pragma unroll
  for (int r2=0; r2<4; r2++){
    int orow = rbase + wv*16 + 4*b + r2;
    if (orow >= N) continue;
    size_t ob = obase + (size_t)orow*128 + m;
    #pragma unroll
    for (int nt=0; nt<8; nt++)
      outp[ob + nt*16] = bfr(acc[nt][r2] + br[nt]);
  }
}

// ---------------- fused epilogue GEMM (AGG bf16) ----------------
__global__ __launch_bounds__(256) void gemm_epi_k(
    const unsigned short* __restrict__ AGGb, const float* __restrict__ DENb,
    int nd, int ni, int gbd,
    const unsigned short* __restrict__ WA, const float* __restrict__ bA,
    const void* __restrict__ xin_dv, const void* __restrict__ xin_iv, int xf32,
    const unsigned short* __restrict__ o1p, unsigned short* __restrict__ out,
    const float* __restrict__ skp, int mode)
{
  int blk = blockIdx.x;
  int ty = (blk >= gbd);
  int N = ty ? ni : nd;
  int rbase = (ty ? (blk - gbd) : blk) * 64;
  int goff = ty ? nd : 0;
  const unsigned short* wa = WA + (ty ? 16384 : 0);
  const float* ba2 = bA + (ty ? 128 : 0);
  const float* xinF = (const float*)(ty ? xin_iv : xin_dv);
  const unsigned short* xinB = (const unsigned short*)(ty ? xin_iv : xin_dv);
  float s = sigf(skp[ty]), s1 = 1.0f - s;

  int t = threadIdx.x;
  int l = t & 63, w = t >> 6, b = l >> 4, m = l & 15;
  int arow = rbase + w*16 + m;
  bool rv = arow < N;
  f4v acc[8];
  #pragma unroll
  for (int nt=0; nt<8; nt++) acc[nt] = (f4v){0,0,0,0};

  #pragma unroll
  for (int kt=0; kt<4; kt++){
    s8v af = (s8v){0,0,0,0,0,0,0,0};
    if (rv){
      size_t grow = (size_t)(goff + arow);
      float dv = 1.0f / fmaxf(DENb[grow*4 + kt], 1e-16f);
      s8v ag = *(const s8v*)(AGGb + grow*128 + kt*32 + b*8);
      #pragma unroll
      for (int jj=0; jj<8; jj++)
        af[jj] = (short)bfr(geluf(b2f((unsigned short)ag[jj]) * dv));
    }
    #pragma unroll
    for (int nt=0; nt<8; nt++){
      s8v bf = *(const s8v*)(wa + ((kt*8 + nt)*64 + l)*8);
      acc[nt] = __builtin_amdgcn_mfma_f32_16x16x32_bf16(af, bf, acc[nt], 0, 0, 0);
    }
  }
  #pragma unroll
  for (int r2=0; r2<4; r2++){
    int orow = rbase + w*16 + 4*b + r2;
    if (orow >= N) continue;
    size_t grow = (size_t)(goff + orow);
    #pragma unroll
    for (int nt=0; nt<8; nt++){
      int col = nt*16 + m;
      float v = acc[nt][r2] + ba2[col];
      float xv = xf32 ? xinF[(size_t)orow*128 + col] : b2f(xinB[(size_t)orow*128 + col]);
      v = s*v + s1*xv;
      if (mode == 3){
        float o1 = b2f(o1p[grow*128 + col]);
        v = fmaxf(0.5f*o1 + 0.5f*v, 0.f);
      }
      out[grow*128 + col] = bfr(v);
    }
  }
}

// ---------------- batched per-head transform over 4 relations ----------------
struct XfD {
  int blk0[5];
  int N[4];
  int inoff[4];
  int outoff[4];
  int matoff[4];
};
__global__ __launch_bounds__(256) void xform_all_k(
    const unsigned short* __restrict__ Xb,
    const unsigned short* __restrict__ Apb,
    unsigned short* __restrict__ outb, XfD d)
{
  int bq = blockIdx.x;
  int r = (bq >= d.blk0[1]) + (bq >= d.blk0[2]) + (bq >= d.blk0[3]);
  int lb = bq - d.blk0[r];
  int N = d.N[r];
  const unsigned short* X = Xb + (size_t)d.inoff[r]*128;
  const unsigned short* Ap = Apb + d.matoff[r];
  unsigned short* out = outb + (size_t)d.outoff[r]*128;

  int t = threadIdx.x;
  int l = t & 63, w = t >> 6, b = l >> 4, m = l & 15;
  int arow = lb*64 + w*16 + m;
  bool rv = arow < N;
  f4v acc[8];
  #pragma unroll
  for (int i=0;i<8;i++) acc[i] = (f4v){0,0,0,0};
  #pragma unroll
  for (int h=0; h<4; h++){
    s8v af = (s8v){0,0,0,0,0,0,0,0};
    if (rv) af = *(const s8v*)(X + (size_t)arow*128 + h*32 + b*8);
    #pragma unroll
    for (int nt=0; nt<2; nt++){
      s8v bf = *(const s8v*)(Ap + ((h*2 + nt)*64 + l)*8);
      acc[h*2+nt] = __builtin_amdgcn_mfma_f32_16x16x32_bf16(af, bf, acc[h*2+nt], 0, 0, 0);
    }
  }
  #pragma unroll
  for (int r2=0; r2<4; r2++){
    int orow = lb*64 + w*16 + 4*b + r2;
    if (orow >= N) continue;
    #pragma unroll
    for (int h=0; h<4; h++)
      #pragma unroll
      for (int nt=0; nt<2; nt++)
        out[(size_t)orow*128 + h*32 + nt*16 + m] = bfr(acc[h*2+nt][r2]);
  }
}

// ---------------- merged CSR build ----------------
struct ScanDesc { int n[8]; };

struct HD {
  int blk0[9];
  const int* dst[8];
  const int* src[8];
  int E[8];
  int cnto[8];    // dir*NOR + dst type base
  int permo[8];   // dir*EtotM
};
__global__ void csr_hist_all_k(HD d, int* __restrict__ cnt){
  int b = blockIdx.x;
  int r = 0;
  while (r < 7 && b >= d.blk0[r+1]) r++;
  int e = (b - d.blk0[r])*256 + threadIdx.x;
  if (e < d.E[r]) atomicAdd(&cnt[d.cnto[r] + d.dst[r][e]], 1);
}
__global__ void csr_fill_all_k(HD d, int* __restrict__ curs, int* __restrict__ perm){
  int b = blockIdx.x;
  int r = 0;
  while (r < 7 && b >= d.blk0[r+1]) r++;
  int e = (b - d.blk0[r])*256 + threadIdx.x;
  if (e < d.E[r]){
    int pos = atomicAdd(&curs[d.cnto[r] + d.dst[r][e]], 1);
    perm[d.permo[r] + pos] = d.src[r][e] | ((r & 3) << 24);
  }
}

// ---------------- parallel 3-phase scan ----------------
__global__ __launch_bounds__(1024) void scan_p1(ScanDesc sd, const int* __restrict__ offs,
                                                int* __restrict__ part, int NO, int MAXT){
  int ent = blockIdx.y, tile = blockIdx.x;
  int n = sd.n[ent];
  int i = tile*1024 + threadIdx.x;
  int v = (i < n) ? offs[(size_t)ent*NO + i] : 0;
  #pragma unroll
  for (int d2=1; d2<64; d2<<=1) v += __shfl_xor(v, d2, 64);
  __shared__ int ws_[16];
  int lane = threadIdx.x & 63, wv = threadIdx.x >> 6;
  if (lane == 0) ws_[wv] = v;
  __syncthreads();
  if (threadIdx.x == 0){
    int s = 0;
    #pragma unroll
    for (int k=0;k<16;k++) s += ws_[k];
    part[ent*MAXT + tile] = s;
  }
}

__global__ __launch_bounds__(1024) void scan_p2(int* __restrict__ part, int MAXT, int nent){
  int tid = threadIdx.x, lane = tid & 63, wv = tid >> 6;
  __shared__ int wsum[16];
  __shared__ int woff[17];
  for (int ent=0; ent<nent; ent++){
    int v = (tid < MAXT) ? part[ent*MAXT + tid] : 0;
    int s = v;
    #pragma unroll
    for (int d2=1; d2<64; d2<<=1){
      int t2 = __shfl_up(s, d2, 64);
      if (lane >= d2) s += t2;
    }
    if (lane == 63) wsum[wv] = s;
    __syncthreads();
    if (wv == 0 && lane < 16){
      int x = wsum[lane];
      #pragma unroll
      for (int d2=1; d2<16; d2<<=1){
        int t2 = __shfl_up(x, d2, 64);
        if (lane >= d2) x += t2;
      }
      woff[lane+1] = x;
      if (lane == 0) woff[0] = 0;
    }
    __syncthreads();
    if (tid < MAXT) part[ent*MAXT + tid] = woff[wv] + s - v;  // exclusive
    __syncthreads();
  }
}

__global__ __launch_bounds__(1024) void scan_p3(ScanDesc sd, int* __restrict__ offs,
                                                int* __restrict__ curs,
                                                const int* __restrict__ part, int NO, int MAXT){
  int ent = blockIdx.y, tile = blockIdx.x;
  int n = sd.n[ent];
  int i = tile*1024 + threadIdx.x;
  int v = (i < n) ? offs[(size_t)ent*NO + i] : 0;
  int lane = threadIdx.x & 63, wv = threadIdx.x >> 6;
  int s = v;
  #pragma unroll
  for (int d2=1; d2<64; d2<<=1){
    int t2 = __shfl_up(s, d2, 64);
    if (lane >= d2) s += t2;
  }
  __shared__ int wsum[16];
  __shared__ int woff[17];
  if (lane == 63) wsum[wv] = s;
  __syncthreads();
  if (wv == 0 && lane < 16){
    int x = wsum[lane];
    #pragma unroll
    for (int d2=1; d2<16; d2<<=1){
      int t2 = __shfl_up(x, d2, 64);
      if (lane >= d2) x += t2;
    }
    woff[lane+1] = x;
    if (lane == 0) woff[0] = 0;
  }
  __syncthreads();
  int excl = part[ent*MAXT + tile] + woff[wv] + s - v;
  if (i < n){
    offs[(size_t)ent*NO + i] = excl;
    curs[(size_t)ent*NO + i] = excl;
  }
  if (i == n-1) offs[(size_t)ent*NO + n] = excl + v;
}

// ---------------- function-CSR build ----------------
__global__ void fhist_k(const int* __restrict__ fd, const int* __restrict__ fi,
                        int Nd, int Ni, int* __restrict__ cnt){
  int nt = Nd + Ni;
  for (int n = blockIdx.x*256 + threadIdx.x; n < nt; n += gridDim.x*256){
    int f = (n < Nd) ? fd[n] : fi[n-Nd];
    atomicAdd(&cnt[f], 1);
  }
}
__global__ void ffill_k(const int* __restrict__ fd, const int* __restrict__ fi,
                        int Nd, int Ni, int* __restrict__ curs, int* __restrict__ perm){
  int nt = Nd + Ni;
  for (int n = blockIdx.x*256 + threadIdx.x; n < nt; n += gridDim.x*256){
    int f = (n < Nd) ? fd[n] : fi[n-Nd];
    int pos = atomicAdd(&curs[f], 1);
    perm[pos] = n;
  }
}

// ---------------- E1 merged: logits only ----------------
struct MD { int koff[4]; };
__global__ __launch_bounds__(256) void e1m_k(
    const unsigned short* __restrict__ KR4, const unsigned short* __restrict__ Qb,
    const int* __restrict__ offs, const int* __restrict__ perm, int nrows,
    const float* __restrict__ pr, float* __restrict__ logits, MD md)
{
  int gidx = blockIdx.x*256 + threadIdx.x;
  int node = gidx >> 5; if (node >= nrows) return;
  int sub = gidx & 31, h = sub >> 3, j = sub & 7;
  int o0 = offs[node], o1 = offs[node+1];
  if (o0 == o1) return;
  ushort4 qa = *(const ushort4*)(Qb + (size_t)node*128 + h*32 + j*4);
  float q0=b2f(qa.x), q1=b2f(qa.y), q2=b2f(qa.z), q3=b2f(qa.w);
  for (int i=o0; i<o1; ++i){
    int pk = perm[i];
    int src = pk & 0xFFFFFF, rel = pk >> 24;
    const unsigned short* kr = KR4 + (size_t)(md.koff[rel] + src)*128 + h*32 + j*4;
    ushort4 aa = *(const ushort4*)kr;
    float p = b2f(aa.x)*q0 + b2f(aa.y)*q1 + b2f(aa.z)*q2 + b2f(aa.w)*q3;
    p += __shfl_xor(p, 1, 8);
    p += __shfl_xor(p, 2, 8);
    p += __shfl_xor(p, 4, 8);
    if (j == 0)
      logits[(size_t)i*4 + h] = p * (pr[rel*4 + h] * 0.17677669529663687f);
  }
}

// ---------------- E2 merged: max + exp + aggregate + den, single owner ----------------
__global__ __launch_bounds__(256) void e2m_k(
    const unsigned short* __restrict__ VR4, const float* __restrict__ logits,
    const int* __restrict__ offs, const int* __restrict__ perm, int nrows,
    unsigned short* __restrict__ aggb, float* __restrict__ den, MD md)
{
  int gidx = blockIdx.x*256 + threadIdx.x;
  int node = gidx >> 5; if (node >= nrows) return;
  int sub = gidx & 31, h = sub >> 3, j = sub & 7;
  int o0 = offs[node], o1 = offs[node+1];
  unsigned short* ap = aggb + (size_t)node*128 + h*32 + j*4;
  if (o0 == o1){
    *(ushort4*)ap = make_ushort4(0,0,0,0);
    if (j == 0) den[(size_t)node*4 + h] = 0.f;
    return;
  }
  float mx = -INFINITY;
  for (int i=o0; i<o1; ++i) mx = fmaxf(mx, logits[(size_t)i*4 + h]);
  float4 acc = make_float4(0.f,0.f,0.f,0.f);
  float ds = 0.f;
  for (int i=o0; i<o1; ++i){
    float ev = __expf(logits[(size_t)i*4 + h] - mx);
    int pk = perm[i];
    int src = pk & 0xFFFFFF, rel = pk >> 24;
    ushort4 v = *(const ushort4*)(VR4 + (size_t)(md.koff[rel] + src)*128 + h*32 + j*4);
    acc.x += ev*b2f(v.x); acc.y += ev*b2f(v.y); acc.z += ev*b2f(v.z); acc.w += ev*b2f(v.w);
    ds += ev;
  }
  *(ushort4*)ap = make_ushort4(bfr(acc.x), bfr(acc.y), bfr(acc.z), bfr(acc.w));
  if (j == 0) den[(size_t)node*4 + h] = ds;
}

// ---------------- plain MFMA GEMM (cf only; optional per-row divide) ----------------
__global__ __launch_bounds__(256) void gemmb_k(
    const float* __restrict__ A, int N,
    const unsigned short* __restrict__ Wp, const float* __restrict__ bias,
    float* __restrict__ outf, int mode, const float* __restrict__ rdiv)
{
  int t = threadIdx.x;
  int l = t & 63, w = t >> 6, b = l >> 4, m = l & 15;
  int arow = blockIdx.x*64 + w*16 + m;
  bool rv = arow < N;
  float dv = 1.0f;
  if (rv && rdiv) dv = 1.0f / fmaxf(rdiv[arow], 1.0f);
  f4v acc[8];
  #pragma unroll
  for (int nt=0; nt<8; nt++) acc[nt] = (f4v){0,0,0,0};
  #pragma unroll
  for (int kt=0; kt<4; kt++){
    s8v af = (s8v){0,0,0,0,0,0,0,0};
    if (rv){
      const float* ap = A + (size_t)arow*128 + kt*32 + b*8;
      float4 x0 = *(const float4*)ap;
      float4 x1 = *(const float4*)(ap + 4);
      af[0]=(short)bfr(x0.x*dv); af[1]=(short)bfr(x0.y*dv); af[2]=(short)bfr(x0.z*dv); af[3]=(short)bfr(x0.w*dv);
      af[4]=(short)bfr(x1.x*dv); af[5]=(short)bfr(x1.y*dv); af[6]=(short)bfr(x1.z*dv); af[7]=(short)bfr(x1.w*dv);
    }
    #pragma unroll
    for (int nt=0; nt<8; nt++){
      s8v bf = *(const s8v*)(Wp + ((kt*8 + nt)*64 + l)*8);
      acc[nt] = __builtin_amdgcn_mfma_f32_16x16x32_bf16(af, bf, acc[nt], 0, 0, 0);
    }
  }
  #pragma unroll
  for (int r2=0; r2<4; r2++){
    int orow = blockIdx.x*64 + w*16 + 4*b + r2;
    if (orow >= N) continue;
    #pragma unroll
    for (int nt=0; nt<8; nt++){
      int col = nt*16 + m;
      float v = acc[nt][r2];
      if (bias) v += bias[col];
      if (mode == 1) v = tanhf(v);
      outf[(size_t)orow*128 + col] = v;
    }
  }
}

// ---------------- func pool (CSR, bf16 X): sums + counts ----------------
__global__ __launch_bounds__(256) void f1c_k(const unsigned short* __restrict__ X,
    const int* __restrict__ foffs, const int* __restrict__ fperm,
    float* __restrict__ fsum, float* __restrict__ fcnt)
{
  __shared__ __align__(16) float red[4][128];
  int t = threadIdx.x, wv = t >> 6, lane = t & 63;
  int f = blockIdx.x;
  int o0 = foffs[f], o1 = foffs[f+1];
  float a0 = 0, a1 = 0;
  for (int i = o0 + wv; i < o1; i += 4){
    ushort2 x = *(const ushort2*)(X + (size_t)fperm[i]*128 + lane*2);
    a0 += b2f(x.x); a1 += b2f(x.y);
  }
  red[wv][lane*2] = a0; red[wv][lane*2+1] = a1;
  __syncthreads();
  if (t < 128)
    fsum[(size_t)f*128 + t] = red[0][t] + red[1][t] + red[2][t] + red[3][t];
  if (t == 0) fcnt[f] = (float)(o1 - o0);
}

// ---------------- func pool (CSR, bf16 X): femb(bf16) + global attention pool ----------------
__global__ __launch_bounds__(256) void f23c_k(const unsigned short* __restrict__ X,
    const int* __restrict__ foffs, const int* __restrict__ fperm,
    const float* __restrict__ cf, const float* __restrict__ attc,
    unsigned short* __restrict__ fembb, float* __restrict__ pooled)
{
  __shared__ __align__(16) float rede[4][128];
  __shared__ __align__(16) float redp[4][128];
  int t = threadIdx.x, wv = t >> 6, lane = t & 63;
  int f = blockIdx.x;
  int o0 = foffs[f], o1 = foffs[f+1];
  float c0 = cf[(size_t)f*128 + lane*2], c1 = cf[(size_t)f*128 + lane*2 + 1];
  float t0 = attc[lane*2], t1 = attc[lane*2 + 1];
  float e0=0, e1=0, p0=0, p1=0;
  for (int i = o0 + wv; i < o1; i += 4){
    ushort2 xr = *(const ushort2*)(X + (size_t)fperm[i]*128 + lane*2);
    float vx = b2f(xr.x), vy = b2f(xr.y);
    union { double d; float2 f2; } u;
    u.f2.x = vx*c0 + vy*c1;
    u.f2.y = vx*t0 + vy*t1;
    #pragma unroll
    for (int m2=1; m2<64; m2<<=1){
      union { double d; float2 f2; } v;
      v.d = __shfl_xor(u.d, m2, 64);
      u.f2.x += v.f2.x; u.f2.y += v.f2.y;
    }
    float s1 = sigf(u.f2.x), s2 = sigf(u.f2.y);
    e0 += vx*s1; e1 += vy*s1;
    p0 += vx*s2; p1 += vy*s2;
  }
  rede[wv][lane*2] = e0; rede[wv][lane*2+1] = e1;
  redp[wv][lane*2] = p0; redp[wv][lane*2+1] = p1;
  __syncthreads();
  if (t < 128){
    fembb[(size_t)f*128 + t] = bfr(rede[0][t] + rede[1][t] + rede[2][t] + rede[3][t]);
    float pp = redp[0][t] + redp[1][t] + redp[2][t] + redp[3][t];
    atomAddF(&pooled[t], pp);
  }
}

// ---------------- attention-pool context (parallel colsum) ----------------
__global__ __launch_bounds__(1024) void attc2_k(const float* __restrict__ fsum, float Ninv,
                                                const float* __restrict__ Watt,
                                                float* __restrict__ attc)
{
  __shared__ float part[8][128];
  __shared__ float mean[128];
  int t = threadIdx.x;
  int j = t & 127, ch = t >> 7;
  float a = 0;
  for (int f = ch; f < FFUNC; f += 8) a += fsum[(size_t)f*128 + j];
  part[ch][j] = a;
  __syncthreads();
  if (t < 128){
    float m = 0;
    #pragma unroll
    for (int c=0;c<8;c++) m += part[c][t];
    mean[t] = m * Ninv;
  }
  __syncthreads();
  if (t < 128){
    float c = 0;
    for (int k=0;k<128;k++) c += mean[k]*Watt[(size_t)k*128 + t];
    attc[t] = tanhf(c);
  }
}

// ---------------- MFMA similarity GEMM (NT, bf16) + min/max ----------------
__global__ __launch_bounds__(256) void gemmnt_b(const unsigned short* __restrict__ fa,
                                                const unsigned short* __restrict__ fb,
                                                float* __restrict__ sc,
                                                unsigned* __restrict__ mmk)
{
  int t = threadIdx.x;
  int l = t & 63, w = t >> 6, b = l >> 4, m = l & 15;
  int rowbase = blockIdx.y*64 + w*16;
  int colbase = blockIdx.x*64;
  f4v acc[4];
  #pragma unroll
  for (int nt=0; nt<4; nt++) acc[nt] = (f4v){0,0,0,0};
  #pragma unroll
  for (int kt=0; kt<4; kt++){
    int arow = rowbase + m;
    s8v af = (s8v){0,0,0,0,0,0,0,0};
    if (arow < FFUNC) af = *(const s8v*)(fa + (size_t)arow*128 + kt*32 + b*8);
    #pragma unroll
    for (int nt=0; nt<4; nt++){
      int brow = colbase + nt*16 + m;
      s8v bf = (s8v){0,0,0,0,0,0,0,0};
      if (brow < FFUNC) bf = *(const s8v*)(fb + (size_t)brow*128 + kt*32 + b*8);
      acc[nt] = __builtin_amdgcn_mfma_f32_16x16x32_bf16(af, bf, acc[nt], 0, 0, 0);
    }
  }
  float mn = INFINITY, mx = -INFINITY;
  #pragma unroll
  for (int nt=0; nt<4; nt++){
    #pragma unroll
    for (int r2=0; r2<4; r2++){
      int row = rowbase + 4*b + r2;
      int col = colbase + nt*16 + m;
      if (row < FFUNC && col < FFUNC){
        float v = acc[nt][r2];
        sc[(size_t)row*FFUNC + col] = v;
        mn = fminf(mn, v); mx = fmaxf(mx, v);
      }
    }
  }
  __shared__ float smn[256], smx[256];
  smn[t]=mn; smx[t]=mx; __syncthreads();
  for (int o=128;o>0;o>>=1){
    if (t<o){ smn[t]=fminf(smn[t],smn[t+o]); smx[t]=fmaxf(smx[t],smx[t+o]); }
    __syncthreads();
  }
  if (t==0){ atomicMin(&mmk[0], fkey(smn[0])); atomicMax(&mmk[1], fkey(smx[0])); }
}

__global__ void hist_init_k(unsigned* mmk, unsigned* hist){
  int t = threadIdx.x;
  if (t==0){ mmk[0]=0xFFFFFFFFu; mmk[1]=0u; }
  if (t<16) hist[t]=0u;
}

__global__ void hist_k(const float* __restrict__ sc, const unsigned* __restrict__ mmk,
                       unsigned* __restrict__ hist)
{
  __shared__ unsigned hl[16];
  int t = threadIdx.x;
  if (t < 16) hl[t] = 0;
  __syncthreads();
  float mn = funkey(mmk[0]), mx = funkey(mmk[1]);
  float rng = fmaxf(mx - mn, 1e-12f);
  const long total = (long)FFUNC*FFUNC;
  for (long idx = (long)blockIdx.x*256 + t; idx < total; idx += (long)gridDim.x*256){
    float v = sc[idx];
    int b = (int)floorf((v - mn)/rng * 16.0f);
    b = min(max(b,0),15);
    atomicAdd(&hl[b], 1u);
  }
  __syncthreads();
  if (t < 16) atomicAdd(&hist[t], hl[t]);
}

// ---------------- final head ----------------
__global__ __launch_bounds__(256) void final_k(
    const float* __restrict__ p1, const float* __restrict__ p2,
    const float* __restrict__ Wtn, const float* __restrict__ Vtn,
    const float* __restrict__ btn, const unsigned* __restrict__ hist,
    const float* __restrict__ Wfc1, const float* __restrict__ bfc1,
    const float* __restrict__ Wsc, const float* __restrict__ bsc,
    float* __restrict__ outp)
{
  __shared__ float P1[128], P2[128], part[256], feats[32], hv[16];
  int t = threadIdx.x;
  if (t < 128){ P1[t] = p1[t]; P2[t] = p2[t]; }
  __syncthreads();
  int k = t & 15, pr_ = t >> 4;
  float acc = 0;
  for (int i = pr_*8; i < pr_*8+8; ++i){
    float pi = P1[i];
    const float* wrow = Wtn + ((size_t)i*128)*16 + k;
    float a2 = 0;
    for (int j=0;j<128;++j) a2 += P2[j]*wrow[(size_t)j*16];
    acc += pi*a2;
  }
  part[t] = acc;
  __syncthreads();
  if (t < 16){
    float sc_ = 0;
    for (int p=0;p<16;p++) sc_ += part[p*16 + t];
    float bl = btn[t];
    for (int j=0;j<256;j++) bl += Vtn[(size_t)t*256 + j] * (j<128 ? P1[j] : P2[j-128]);
    float tv = sc_ + bl;
    feats[t] = tv > 0.f ? tv : 0.f;
    feats[16+t] = (float)hist[t] * (1.0f/((float)FFUNC*(float)FFUNC));
  }
  __syncthreads();
  if (t < 16){
    float a2 = bfc1[t];
    for (int q2=0;q2<32;q2++) a2 += feats[q2]*Wfc1[q2*16 + t];
    hv[t] = a2 > 0.f ? a2 : 0.f;
  }
  __syncthreads();
  if (t == 0){
    float z = bsc[0];
    for (int m=0;m<16;m++) z += hv[m]*Wsc[m];
    outp[0] = sigf(z);
  }
}

// ---------------- host ----------------
extern "C" void kernel_launch(void* const* d_in, const int* in_sizes, int n_in,
                              void* d_out, int out_size, void* d_ws, size_t ws_size,
                              hipStream_t stream)
{
  (void)n_in; (void)out_size; (void)ws_size;
  const float* Wk = (const float*)d_in[16];
  const float* bk = (const float*)d_in[17];
  const float* Wq = (const float*)d_in[18];
  const float* bq = (const float*)d_in[19];
  const float* Wv = (const float*)d_in[20];
  const float* bv = (const float*)d_in[21];
  const float* Wa = (const float*)d_in[22];
  const float* ba = (const float*)d_in[23];
  const float* SKp = (const float*)d_in[24];
  const float* AR = (const float*)d_in[25];
  const float* MRm = (const float*)d_in[26];
  const float* PRp = (const float*)d_in[27];
  const float* WATT = (const float*)d_in[28];
  const float* WTN = (const float*)d_in[29];
  const float* VTN = (const float*)d_in[30];
  const float* BTN = (const float*)d_in[31];
  const float* WFC1 = (const float*)d_in[32];
  const float* BFC1 = (const float*)d_in[33];
  const float* WSC = (const float*)d_in[34];
  const float* BSC = (const float*)d_in[35];

  int NdA[2] = { in_sizes[0]/128, in_sizes[8]/128 };
  int NiA[2] = { in_sizes[1]/128, in_sizes[9]/128 };
  int EA[2][4];
  for (int g=0; g<2; g++)
    for (int r=0; r<4; r++) EA[g][r] = in_sizes[g*8+2+r]/2;

  int NdM = NdA[0] > NdA[1] ? NdA[0] : NdA[1];
  int NiM = NiA[0] > NiA[1] ? NiA[0] : NiA[1];
  long EtotM = 0;
  for (int g=0; g<2; g++){
    long et = 0; for (int r=0;r<4;r++) et += EA[g][r];
    if (et > EtotM) EtotM = et;
  }
  size_t nrowsM = (size_t)NdM + (size_t)NiM;
  int NOR = (int)(((nrowsM + 2 + 63)/64)*64);
  long KR4rows = 3L*NiM + NdM;

  char* wp = (char*)d_ws;
  auto alloc = [&](size_t bytes)->void*{
    void* p = (void*)wp;
    wp += (bytes + 255) & ~(size_t)255;
    return p;
  };
  unsigned short* Xb   = (unsigned short*)alloc(nrowsM*128*2);
  unsigned short* AGGb = (unsigned short*)alloc(nrowsM*128*2);
  float*          DEN  = (float*)alloc(nrowsM*4*4);
  unsigned short* O1b  = (unsigned short*)alloc(nrowsM*128*2);
  unsigned short* Kb   = (unsigned short*)alloc(nrowsM*128*2);
  unsigned short* Qb   = (unsigned short*)alloc(nrowsM*128*2);
  unsigned short* Vb   = (unsigned short*)alloc(nrowsM*128*2);
  unsigned short* KR4  = (unsigned short*)alloc((size_t)KR4rows*128*2);
  float*          LOGb = (float*)alloc((size_t)EtotM*4*4);
  int*            OFFS3= (int*)alloc((size_t)3*NOR*4);   // dir0, dir1, func
  int*            PERM = (int*)alloc((size_t)2*EtotM*4);
  int*            FPERM= (int*)alloc(nrowsM*4);
  int*            PART = (int*)alloc((size_t)3*1024*4);
  float*          GS[2];
  GS[0] = (float*)alloc((size_t)257280*4);
  GS[1] = (float*)alloc((size_t)257280*4);
  unsigned short* FB[2];
  FB[0] = (unsigned short*)alloc((size_t)FFUNC*128*2);
  FB[1] = (unsigned short*)alloc((size_t)FFUNC*128*2);
  unsigned*       MM   = (unsigned*)alloc(2*4);
  unsigned*       HIST = (unsigned*)alloc(16*4);
  unsigned short* WKP  = (unsigned short*)alloc((size_t)8*16384*2);
  unsigned short* WQP  = (unsigned short*)alloc((size_t)8*16384*2);
  unsigned short* WVP  = (unsigned short*)alloc((size_t)8*16384*2);
  unsigned short* WAP  = (unsigned short*)alloc((size_t)8*16384*2);
  unsigned short* WATTP= (unsigned short*)alloc((size_t)16384*2);
  unsigned short* ARP  = (unsigned short*)alloc((size_t)16*4096*2);
  unsigned short* MRP  = (unsigned short*)alloc((size_t)16*4096*2);
  size_t uni_bytes = (size_t)FFUNC*FFUNC*4;
  size_t curs_bytes = (size_t)3*NOR*4;
  void* UNI = alloc(uni_bytes > curs_bytes ? uni_bytes : curs_bytes);
  int*   CURS3 = (int*)UNI;
  float* SCb   = (float*)UNI;

  packw_k<<<8,256,0,stream>>>(Wk, WKP);
  packw_k<<<8,256,0,stream>>>(Wq, WQP);
  packw_k<<<8,256,0,stream>>>(Wv, WVP);
  packw_k<<<8,256,0,stream>>>(Wa, WAP);
  packw_k<<<1,256,0,stream>>>(WATT, WATTP);
  packa_k<<<16,256,0,stream>>>(AR, ARP);
  packa_k<<<16,256,0,stream>>>(MRm, MRP);

  const size_t OF_FSUM=0, OF_FCNT=128000, OF_CF=129024, OF_ATTC=257024, OF_POOL=257152;
  const int stf[4] = {1,0,1,1};
  const int dtf[4] = {1,1,0,1};

  for (int g=0; g<2; ++g){
    int nd = NdA[g], ni = NiA[g];
    int nrows = nd + ni;
    int E[4] = {EA[g][0],EA[g][1],EA[g][2],EA[g][3]};
    const int* ei[4] = {(const int*)d_in[g*8+2], (const int*)d_in[g*8+3],
                        (const int*)d_in[g*8+4], (const int*)d_in[g*8+5]};
    const int* fdp = (const int*)d_in[g*8+6];
    const int* fip = (const int*)d_in[g*8+7];
    const float* x0d = (const float*)d_in[g*8+0];
    const float* x0i = (const float*)d_in[g*8+1];
    int gbd = (nd+63)/64, gbi = (ni+63)/64;
    int nb = gbd + gbi;
    int ntb = (nrows+255)/256; if (ntb > 2048) ntb = 2048;

    int koff[2][4], stA[2][4], dtA[2][4];
    for (int c=0;c<2;c++){
      int run = 0;
      for (int r=0;r<4;r++){
        stA[c][r] = (c==0) ? stf[r] : dtf[r];
        dtA[c][r] = (c==0) ? dtf[r] : stf[r];
        koff[c][r] = run;
        run += stA[c][r] ? ni : nd;
      }
    }

    // ---- build 2 merged edge CSRs + function CSR ----
    hipMemsetAsync(OFFS3, 0, (size_t)3*NOR*4, stream);
    HD hd; int hb = 0;
    for (int c2=0; c2<2; c2++)
      for (int r=0; r<4; r++){
        int ent = c2*4 + r;
        hd.blk0[ent] = hb;
        hd.dst[ent] = (c2==0) ? ei[r]+E[r] : ei[r];
        hd.src[ent] = (c2==0) ? ei[r] : ei[r]+E[r];
        hd.E[ent] = E[r];
        hd.cnto[ent] = c2*NOR + (dtA[c2][r] ? nd : 0);
        hd.permo[ent] = c2*(int)EtotM;
        hb += (E[r]+255)/256;
      }
    hd.blk0[8] = hb;
    csr_hist_all_k<<<hb,256,0,stream>>>(hd, OFFS3);
    fhist_k<<<ntb,256,0,stream>>>(fdp, fip, nd, ni, OFFS3 + (size_t)2*NOR);
    ScanDesc sd; sd.n[0] = nrows; sd.n[1] = nrows; sd.n[2] = FFUNC;
    int maxtiles = (nrows + 1023)/1024; if (maxtiles < 1) maxtiles = 1;
    dim3 sgrid(maxtiles, 3);
    scan_p1<<<sgrid,1024,0,stream>>>(sd, OFFS3, PART, NOR, maxtiles);
    scan_p2<<<1,1024,0,stream>>>(PART, maxtiles, 3);
    scan_p3<<<sgrid,1024,0,stream>>>(sd, OFFS3, CURS3, PART, NOR, maxtiles);
    csr_fill_all_k<<<hb,256,0,stream>>>(hd, CURS3, PERM);
    ffill_k<<<ntb,256,0,stream>>>(fdp, fip, nd, ni, CURS3 + (size_t)2*NOR, FPERM);

    for (int l=0; l<2; ++l){
      const void* xd = (l==0) ? (const void*)x0d : (const void*)Xb;
      const void* xi = (l==0) ? (const void*)x0i : (const void*)(Xb + (size_t)nd*128);
      int af32 = (l==0);
      for (int c=0; c<2; ++c){
        int pc = l*2 + c;
        gemm_kqv_k<<<3*nb,256,0,stream>>>(
            xd, xi, af32, nd, ni, gbd, nb,
            WKP+(size_t)pc*2*16384, WQP+(size_t)pc*2*16384, WVP+(size_t)pc*2*16384,
            bk+(size_t)pc*2*128, bq+(size_t)pc*2*128, bv+(size_t)pc*2*128,
            Kb, Qb, Vb);
        // batched K-transform into KR4
        XfD xf; int xb = 0;
        for (int r=0;r<4;r++){
          xf.blk0[r] = xb;
          xf.N[r] = stA[c][r] ? ni : nd;
          xf.inoff[r] = stA[c][r] ? nd : 0;
          xf.outoff[r] = koff[c][r];
          xf.matoff[r] = (pc*4+r)*4096;
          xb += (xf.N[r]+63)/64;
        }
        xf.blk0[4] = xb;
        xform_all_k<<<xb,256,0,stream>>>(Kb, ARP, KR4, xf);
        MD md;
        for (int r=0;r<4;r++) md.koff[r] = koff[c][r];
        int eblk = (nrows*32 + 255)/256;
        e1m_k<<<eblk,256,0,stream>>>(KR4, Qb, OFFS3 + (size_t)c*NOR,
                                     PERM + (size_t)c*EtotM, nrows,
                                     PRp + (size_t)pc*16, LOGb, md);
        // V-transform overwrites KR4 (e1m consumed it)
        xform_all_k<<<xb,256,0,stream>>>(Vb, MRP, KR4, xf);
        e2m_k<<<eblk,256,0,stream>>>(KR4, LOGb, OFFS3 + (size_t)c*NOR,
                                     PERM + (size_t)c*EtotM, nrows,
                                     AGGb, DEN, md);
        gemm_epi_k<<<nb,256,0,stream>>>(
            AGGb, DEN, nd, ni, gbd,
            WAP+(size_t)pc*2*16384, ba+(size_t)pc*2*128,
            xd, xi, af32,
            (c==1) ? O1b : (const unsigned short*)nullptr,
            (c==0) ? O1b : Xb,
            SKp + (size_t)pc*2, (c==0) ? 2 : 3);
      }
    }
    // pooling (function-CSR, bf16 X)
    float* fsum = GS[g]+OF_FSUM;  float* fcnt = GS[g]+OF_FCNT;
    float* cf   = GS[g]+OF_CF;    float* attc = GS[g]+OF_ATTC;
    float* pool = GS[g]+OF_POOL;
    hipMemsetAsync(pool, 0, 128*4, stream);
    f1c_k<<<FFUNC,256,0,stream>>>(Xb, OFFS3 + (size_t)2*NOR, FPERM, fsum, fcnt);
    attc2_k<<<1,1024,0,stream>>>(fsum, 1.0f/(float)nrows, WATT, attc);
    gemmb_k<<<(FFUNC+63)/64,256,0,stream>>>(fsum, FFUNC, WATTP, nullptr, cf, 1, fcnt);
    f23c_k<<<FFUNC,256,0,stream>>>(Xb, OFFS3 + (size_t)2*NOR, FPERM, cf, attc, FB[g], pool);
  }
  // similarity histogram + final head
  hist_init_k<<<1,32,0,stream>>>(MM, HIST);
  dim3 gnt((FFUNC+63)/64, (FFUNC+63)/64);
  gemmnt_b<<<gnt,256,0,stream>>>(FB[0], FB[1], SCb, MM);
  hist_k<<<512,256,0,stream>>>(SCb, MM, HIST);
  final_k<<<1,256,0,stream>>>(GS[0]+OF_POOL, GS[1]+OF_POOL, WTN, VTN, BTN, HIST,
                              WFC1, BFC1, WSC, BSC, (float*)d_out);
}